// Round 2
// baseline (4895.268 us; speedup 1.0000x reference)
//
#include <hip/hip_runtime.h>
#include <hip/hip_bf16.h>

using bf16 = __hip_bfloat16;

constexpr int NE  = 50000;   // entities
constexpr int H   = 200;     // hidden dim
constexpr int R2C = 500;     // 2*num_rels
constexpr int TS  = 4;       // timesteps
constexpr int EC  = 400000;  // edges per step
constexpr float SLOPE = 0.22916666666666666f;  // rrelu eval slope
constexpr int NSCAN = (NE + 255) / 256;        // 196

#define DEVINL __device__ __forceinline__

DEVINL float b2f(bf16 v) { return __bfloat162float(v); }
DEVINL bf16  f2b(float v) { return __float2bfloat16(v); }

DEVINL float wave_sum(float v) {
  #pragma unroll
  for (int o = 32; o > 0; o >>= 1) v += __shfl_xor(v, o, 64);
  return v;
}

DEVINL float sigmoidf(float x) { return 1.0f / (1.0f + expf(-x)); }

// ---------------- init ----------------
__global__ __launch_bounds__(256) void k_init_h(const float* de, float* h) {
  int wid = threadIdx.x >> 6, lane = threadIdx.x & 63;
  int row = blockIdx.x * 4 + wid;
  if (row >= NE) return;
  float v[4]; float ss = 0.f;
  #pragma unroll
  for (int q = 0; q < 4; q++) {
    int d = lane + q * 64;
    v[q] = (d < H) ? de[(size_t)row * H + d] : 0.f;
    ss += v[q] * v[q];
  }
  ss = wave_sum(ss);
  float sc = 1.0f / fmaxf(sqrtf(ss), 1e-12f);
  #pragma unroll
  for (int q = 0; q < 4; q++) {
    int d = lane + q * 64;
    if (d < H) h[(size_t)row * H + d] = v[q] * sc;
  }
}

__global__ __launch_bounds__(256) void k_init_h0(const float* er, float* h0) {
  int i = blockIdx.x * 256 + threadIdx.x;
  if (i < R2C * H) h0[i] = er[i];
}

// relW = emb_rel @ W_n   [R2C, H]
__global__ __launch_bounds__(256) void k_relw(const float* er, const float* wn, float* relW) {
  __shared__ float a[H];
  int r = blockIdx.x;
  for (int d = threadIdx.x; d < H; d += 256) a[d] = er[r * H + d];
  __syncthreads();
  for (int c = threadIdx.x; c < H; c += 256) {
    float s = 0.f;
    for (int k = 0; k < H; k++) s += a[k] * wn[k * H + c];
    relW[r * H + c] = s;
  }
}

// ---------------- generic zero ----------------
__global__ void k_zero_f(float* p, int n) {
  int i = blockIdx.x * 256 + threadIdx.x;
  if (i < n) p[i] = 0.f;
}
__global__ void k_zero_i(int* p, int n) {
  int i = blockIdx.x * 256 + threadIdx.x;
  if (i < n) p[i] = 0;
}

// ---------------- per-step: relation segment bounds (sorted rseg) ----------------
__global__ __launch_bounds__(512) void k_segbounds(const int* rseg, int* segstart) {
  for (int r = threadIdx.x; r <= R2C; r += 512) {
    int lo = 0, hi = EC;
    while (lo < hi) { int m = (lo + hi) >> 1; if (rseg[m] < r) lo = m + 1; else hi = m; }
    segstart[r] = lo;
  }
}

// chunked segment-sum over sorted rseg; atomic flush on boundaries only
__global__ __launch_bounds__(256) void k_relsums(const int* rseg, const int* rte,
                                                 const float* h, float* sums) {
  int base = blockIdx.x * 256;
  int d = threadIdx.x;
  int cnt = min(256, EC - base);
  float acc = 0.f;
  int prev = rseg[base];
  for (int i = 0; i < cnt; i++) {
    int e = base + i;
    int s = rseg[e];
    if (s != prev) {
      if (d < H) atomicAdd(&sums[prev * H + d], acc);
      acc = 0.f; prev = s;
    }
    if (d < H) acc += h[(size_t)rte[e] * H + d];
  }
  if (d < H) atomicAdd(&sums[prev * H + d], acc);
}

// ---------------- per-step: GRU on relations ----------------
__global__ __launch_bounds__(256) void k_gru(const float* er, const float* sums, const int* segstart,
                                             const float* W_ih, const float* W_hh,
                                             const float* b_ih, const float* b_hh,
                                             float* h0, float* h0_out) {
  __shared__ float xc[2 * H];
  __shared__ float h0r[H];
  __shared__ float gi[3 * H], gh[3 * H];
  __shared__ float red[4];
  int r = blockIdx.x;
  int tid = threadIdx.x, wid = tid >> 6, lane = tid & 63;
  int cnt = segstart[r + 1] - segstart[r];
  float inv = cnt > 0 ? 1.0f / (float)cnt : 0.0f;
  for (int d = tid; d < H; d += 256) {
    xc[d]     = er[r * H + d];
    xc[H + d] = sums[r * H + d] * inv;
    h0r[d]    = h0[r * H + d];
  }
  __syncthreads();
  for (int j = wid; j < 3 * H; j += 4) {
    float si = 0.f;
    for (int k = lane; k < 2 * H; k += 64) si += xc[k] * W_ih[j * (2 * H) + k];
    si = wave_sum(si);
    float sh = 0.f;
    for (int k = lane; k < H; k += 64) sh += h0r[k] * W_hh[j * H + k];
    sh = wave_sum(sh);
    if (lane == 0) { gi[j] = si + b_ih[j]; gh[j] = sh + b_hh[j]; }
  }
  __syncthreads();
  float ssp = 0.f;
  for (int d = tid; d < H; d += 256) {
    float rg = sigmoidf(gi[d] + gh[d]);
    float z  = sigmoidf(gi[H + d] + gh[H + d]);
    float n  = tanhf(gi[2 * H + d] + rg * gh[2 * H + d]);
    float o  = (1.0f - z) * n + z * h0r[d];
    xc[d] = o;                       // reuse xc for output row
    ssp += o * o;
  }
  ssp = wave_sum(ssp);
  if (lane == 0) red[wid] = ssp;
  __syncthreads();
  float ss = red[0] + red[1] + red[2] + red[3];
  float sc = 1.0f / fmaxf(sqrtf(ss), 1e-12f);
  for (int d = tid; d < H; d += 256) {
    float o = xc[d] * sc;
    h0[r * H + d] = o;
    if (h0_out) h0_out[r * H + d] = o;
  }
}

// ---------------- per-step: fused node GEMMs (hW = h@Wn, tw = sigmoid(h@Tg+b)) ----------------
__global__ __launch_bounds__(256) void k_nodegemm(const float* __restrict__ h,
                                                  const float* __restrict__ wn,
                                                  const float* __restrict__ tg,
                                                  const float* __restrict__ tgb,
                                                  bf16* __restrict__ hWb,
                                                  bf16* __restrict__ twb) {
  int c = threadIdx.x;
  int row0 = blockIdx.x * 32;
  if (c >= H) return;
  float acc1[32] = {}, acc2[32] = {};
  for (int k = 0; k < H; k += 4) {
    float b1[4], b2[4];
    #pragma unroll
    for (int kk = 0; kk < 4; kk++) {
      b1[kk] = wn[(k + kk) * H + c];
      b2[kk] = tg[(k + kk) * H + c];
    }
    #pragma unroll
    for (int r = 0; r < 32; r++) {
      int rowc = min(row0 + r, NE - 1);
      const float4 a = *reinterpret_cast<const float4*>(h + (size_t)rowc * H + k);
      acc1[r] = fmaf(a.x, b1[0], fmaf(a.y, b1[1], fmaf(a.z, b1[2], fmaf(a.w, b1[3], acc1[r]))));
      acc2[r] = fmaf(a.x, b2[0], fmaf(a.y, b2[1], fmaf(a.z, b2[2], fmaf(a.w, b2[3], acc2[r]))));
    }
  }
  float bias = tgb[c];
  #pragma unroll
  for (int r = 0; r < 32; r++) {
    int row = row0 + r;
    if (row < NE) {
      hWb[(size_t)row * H + c] = f2b(acc1[r]);
      twb[(size_t)row * H + c] = f2b(sigmoidf(acc2[r] + bias));
    }
  }
}

// ---------------- per-step: CSR build by dst ----------------
__global__ void k_hist(const int* dst, int* deg) {
  int e = blockIdx.x * 256 + threadIdx.x;
  if (e < EC) atomicAdd(&deg[dst[e]], 1);
}

__global__ __launch_bounds__(256) void k_scan1(const int* deg, int* offs, int* bsums) {
  __shared__ int s[256];
  int i = blockIdx.x * 256 + threadIdx.x;
  int v = (i < NE) ? deg[i] : 0;
  s[threadIdx.x] = v;
  __syncthreads();
  for (int o = 1; o < 256; o <<= 1) {
    int add = (threadIdx.x >= o) ? s[threadIdx.x - o] : 0;
    __syncthreads();
    s[threadIdx.x] += add;
    __syncthreads();
  }
  if (i < NE) offs[i] = s[threadIdx.x] - v;  // exclusive
  if (threadIdx.x == 255) bsums[blockIdx.x] = s[255];
}

__global__ __launch_bounds__(256) void k_scan2(int* bsums) {
  __shared__ int s[256];
  int v = (threadIdx.x < NSCAN) ? bsums[threadIdx.x] : 0;
  s[threadIdx.x] = v;
  __syncthreads();
  for (int o = 1; o < 256; o <<= 1) {
    int add = (threadIdx.x >= o) ? s[threadIdx.x - o] : 0;
    __syncthreads();
    s[threadIdx.x] += add;
    __syncthreads();
  }
  if (threadIdx.x < NSCAN) bsums[threadIdx.x] = s[threadIdx.x] - v;  // exclusive
}

__global__ void k_scan3(int* offs, const int* bsums, int* cursor) {
  int i = blockIdx.x * 256 + threadIdx.x;
  if (i < NE) {
    int o = offs[i] + bsums[blockIdx.x];
    offs[i] = o;
    cursor[i] = o;
  }
  if (blockIdx.x == 0 && threadIdx.x == 0) offs[NE] = EC;
}

__global__ void k_scatter(const int* dst, int* cursor, int* eids) {
  int e = blockIdx.x * 256 + threadIdx.x;
  if (e < EC) {
    int pos = atomicAdd(&cursor[dst[e]], 1);
    eids[pos] = e;
  }
}

// ---------------- per-step: aggregate + rrelu + l2norm -> cur (stored in evolve[t] slot) ----------------
__global__ __launch_bounds__(256) void k_aggcur(const int* __restrict__ offs,
                                                const int* __restrict__ eids,
                                                const int* __restrict__ src,
                                                const int* __restrict__ et,
                                                const bf16* __restrict__ hWb,
                                                const float* __restrict__ relW,
                                                float* __restrict__ cur) {
  int wid = threadIdx.x >> 6, lane = threadIdx.x & 63;
  int i = blockIdx.x * 4 + wid;
  if (i >= NE) return;
  int s0 = offs[i], s1 = offs[i + 1];
  float acc[4] = {0.f, 0.f, 0.f, 0.f};
  for (int p = s0; p < s1; p++) {
    int e = eids[p];
    int s = src[e];
    int r = et[e];
    #pragma unroll
    for (int q = 0; q < 4; q++) {
      int d = lane + q * 64;
      if (d < H) acc[q] += b2f(hWb[(size_t)s * H + d]) + relW[r * H + d];
    }
  }
  int deg = s1 - s0;
  float nrm = deg > 0 ? 1.0f / (float)deg : 0.0f;
  float ss = 0.f;
  #pragma unroll
  for (int q = 0; q < 4; q++) {
    float v = acc[q] * nrm;
    v = v >= 0.f ? v : SLOPE * v;
    acc[q] = v;
    ss += v * v;
  }
  ss = wave_sum(ss);
  float sc = 1.0f / fmaxf(sqrtf(ss), 1e-12f);
  #pragma unroll
  for (int q = 0; q < 4; q++) {
    int d = lane + q * 64;
    if (d < H) cur[(size_t)i * H + d] = acc[q] * sc;
  }
}

// ---------------- per-step: time gate + combine + l2norm -> h, evolve (in-place over cur) ----------------
__global__ __launch_bounds__(256) void k_final(const bf16* __restrict__ twb,
                                               float* __restrict__ h,
                                               float* __restrict__ evolve) {
  int wid = threadIdx.x >> 6, lane = threadIdx.x & 63;
  int i = blockIdx.x * 4 + wid;
  if (i >= NE) return;
  float v[4]; float ss = 0.f;
  #pragma unroll
  for (int q = 0; q < 4; q++) {
    int d = lane + q * 64;
    if (d < H) {
      float cur = evolve[(size_t)i * H + d];
      float tw  = b2f(twb[(size_t)i * H + d]);
      float hv  = h[(size_t)i * H + d];
      float val = tw * cur + (1.0f - tw) * hv;
      v[q] = val; ss += val * val;
    } else v[q] = 0.f;
  }
  ss = wave_sum(ss);
  float sc = 1.0f / fmaxf(sqrtf(ss), 1e-12f);
  #pragma unroll
  for (int q = 0; q < 4; q++) {
    int d = lane + q * 64;
    if (d < H) {
      float o = v[q] * sc;
      h[(size_t)i * H + d] = o;
      evolve[(size_t)i * H + d] = o;
    }
  }
}

extern "C" void kernel_launch(void* const* d_in, const int* in_sizes, int n_in,
                              void* d_out, int out_size, void* d_ws, size_t ws_size,
                              hipStream_t stream) {
  const float* de  = (const float*)d_in[0];
  const float* er  = (const float*)d_in[1];
  const float* wih = (const float*)d_in[2];
  const float* whh = (const float*)d_in[3];
  const float* bih = (const float*)d_in[4];
  const float* bhh = (const float*)d_in[5];
  const float* wn  = (const float*)d_in[6];
  const float* tg  = (const float*)d_in[7];
  const float* tgb = (const float*)d_in[8];
  const int* src  = (const int*)d_in[9];
  const int* dst  = (const int*)d_in[10];
  const int* et   = (const int*)d_in[11];
  const int* rte  = (const int*)d_in[12];
  const int* rseg = (const int*)d_in[13];

  char* w = (char*)d_ws;
  auto alloc = [&](size_t bytes) -> char* {
    char* p = w;
    w += (bytes + 255) / 256 * 256;
    return p;
  };
  float* h     = (float*)alloc(sizeof(float) * (size_t)NE * H);   // 40 MB
  bf16*  hWb   = (bf16*) alloc(sizeof(bf16)  * (size_t)NE * H);   // 20 MB
  bf16*  twb   = (bf16*) alloc(sizeof(bf16)  * (size_t)NE * H);   // 20 MB
  float* relW  = (float*)alloc(sizeof(float) * R2C * H);
  float* h0    = (float*)alloc(sizeof(float) * R2C * H);
  float* sums  = (float*)alloc(sizeof(float) * R2C * H);
  int* segstart= (int*)  alloc(sizeof(int) * (R2C + 1));
  int* deg     = (int*)  alloc(sizeof(int) * NE);
  int* offs    = (int*)  alloc(sizeof(int) * (NE + 1));
  int* cursor  = (int*)  alloc(sizeof(int) * NE);
  int* eids    = (int*)  alloc(sizeof(int) * EC);
  int* bsums   = (int*)  alloc(sizeof(int) * 256);
  (void)ws_size; (void)in_sizes; (void)n_in; (void)out_size;

  float* out    = (float*)d_out;
  float* evolve = out;                       // [TS, NE, H]
  float* h0out  = out + (size_t)TS * NE * H; // [R2C, H]

  const int gRow4  = (NE + 3) / 4;          // 12500
  const int gE     = (EC + 255) / 256;      // 1563
  const int gRel   = (R2C * H + 255) / 256; // 391
  const int gGemm  = (NE + 31) / 32;        // 1563

  k_init_h<<<gRow4, 256, 0, stream>>>(de, h);
  k_init_h0<<<gRel, 256, 0, stream>>>(er, h0);
  k_relw<<<R2C, 256, 0, stream>>>(er, wn, relW);

  for (int t = 0; t < TS; t++) {
    const int* src_t  = src  + (size_t)t * EC;
    const int* dst_t  = dst  + (size_t)t * EC;
    const int* et_t   = et   + (size_t)t * EC;
    const int* rte_t  = rte  + (size_t)t * EC;
    const int* rseg_t = rseg + (size_t)t * EC;
    float* evo_t = evolve + (size_t)t * NE * H;

    // relation-segment means + GRU (uses pre-step h, h0)
    k_segbounds<<<1, 512, 0, stream>>>(rseg_t, segstart);
    k_zero_f<<<gRel, 256, 0, stream>>>(sums, R2C * H);
    k_relsums<<<gE, 256, 0, stream>>>(rseg_t, rte_t, h, sums);
    k_gru<<<R2C, 256, 0, stream>>>(er, sums, segstart, wih, whh, bih, bhh,
                                   h0, (t == TS - 1) ? h0out : (float*)nullptr);

    // node GEMMs (pre-step h)
    k_nodegemm<<<gGemm, 256, 0, stream>>>(h, wn, tg, tgb, hWb, twb);

    // CSR build by dst
    k_zero_i<<<NSCAN, 256, 0, stream>>>(deg, NE);
    k_hist<<<gE, 256, 0, stream>>>(dst_t, deg);
    k_scan1<<<NSCAN, 256, 0, stream>>>(deg, offs, bsums);
    k_scan2<<<1, 256, 0, stream>>>(bsums);
    k_scan3<<<NSCAN, 256, 0, stream>>>(offs, bsums, cursor);
    k_scatter<<<gE, 256, 0, stream>>>(dst_t, cursor, eids);

    // aggregate + rrelu + l2norm -> cur (stored in evolve[t] slot of d_out)
    k_aggcur<<<gRow4, 256, 0, stream>>>(offs, eids, src_t, et_t, hWb, relW, evo_t);

    // time gate + combine + l2norm; updates h in place, rewrites evolve[t] with h_new
    k_final<<<gRow4, 256, 0, stream>>>(twb, h, evo_t);
  }
}

// Round 3
// 3541.569 us; speedup vs baseline: 1.3822x; 1.3822x over previous
//
#include <hip/hip_runtime.h>
#include <hip/hip_bf16.h>

using bf16 = __hip_bfloat16;

constexpr int NE  = 50000;   // entities
constexpr int H   = 200;     // hidden dim
constexpr int R2C = 500;     // 2*num_rels
constexpr int TS  = 4;       // timesteps
constexpr int EC  = 400000;  // edges per step
constexpr float SLOPE = 0.22916666666666666f;  // rrelu eval slope
constexpr int NSCAN = (NE + 255) / 256;        // 196

#define DEVINL __device__ __forceinline__

DEVINL float b2f(bf16 v) { return __bfloat162float(v); }
DEVINL bf16  f2b(float v) { return __float2bfloat16(v); }

DEVINL float wave_sum(float v) {
  #pragma unroll
  for (int o = 32; o > 0; o >>= 1) v += __shfl_xor(v, o, 64);
  return v;
}

DEVINL float sigmoidf(float x) { return 1.0f / (1.0f + expf(-x)); }

// ---------------- init ----------------
__global__ __launch_bounds__(256) void k_init_h(const float* de, float* h) {
  int wid = threadIdx.x >> 6, lane = threadIdx.x & 63;
  int row = blockIdx.x * 4 + wid;
  if (row >= NE) return;
  float v[4]; float ss = 0.f;
  #pragma unroll
  for (int q = 0; q < 4; q++) {
    int d = lane + q * 64;
    v[q] = (d < H) ? de[(size_t)row * H + d] : 0.f;
    ss += v[q] * v[q];
  }
  ss = wave_sum(ss);
  float sc = 1.0f / fmaxf(sqrtf(ss), 1e-12f);
  #pragma unroll
  for (int q = 0; q < 4; q++) {
    int d = lane + q * 64;
    if (d < H) h[(size_t)row * H + d] = v[q] * sc;
  }
}

__global__ __launch_bounds__(256) void k_init_h0(const float* er, float* h0) {
  int i = blockIdx.x * 256 + threadIdx.x;
  if (i < R2C * H) h0[i] = er[i];
}

// relW = emb_rel @ W_n   [R2C, H]
__global__ __launch_bounds__(256) void k_relw(const float* er, const float* wn, float* relW) {
  __shared__ float a[H];
  int r = blockIdx.x;
  for (int d = threadIdx.x; d < H; d += 256) a[d] = er[r * H + d];
  __syncthreads();
  for (int c = threadIdx.x; c < H; c += 256) {
    float s = 0.f;
    for (int k = 0; k < H; k++) s += a[k] * wn[k * H + c];
    relW[r * H + c] = s;
  }
}

// transpose GRU weights once: WihT[k][j] = wih[j][k] (400x600), WhhT[k][j] = whh[j][k] (200x600)
__global__ __launch_bounds__(256) void k_wtrans(const float* wih, const float* whh,
                                                float* WihT, float* WhhT) {
  int i = blockIdx.x * 256 + threadIdx.x;
  if (i < 2 * H * 3 * H) {
    int k = i / (3 * H), j = i % (3 * H);
    WihT[i] = wih[j * (2 * H) + k];
  }
  if (i < H * 3 * H) {
    int k = i / (3 * H), j = i % (3 * H);
    WhhT[i] = whh[j * H + k];
  }
}

// ---------------- generic zero ----------------
__global__ void k_zero_f(float* p, int n) {
  int i = blockIdx.x * 256 + threadIdx.x;
  if (i < n) p[i] = 0.f;
}
__global__ void k_zero_i(int* p, int n) {
  int i = blockIdx.x * 256 + threadIdx.x;
  if (i < n) p[i] = 0;
}

// ---------------- per-step: relation segment bounds (sorted rseg) ----------------
__global__ __launch_bounds__(512) void k_segbounds(const int* rseg, int* segstart) {
  for (int r = threadIdx.x; r <= R2C; r += 512) {
    int lo = 0, hi = EC;
    while (lo < hi) { int m = (lo + hi) >> 1; if (rseg[m] < r) lo = m + 1; else hi = m; }
    segstart[r] = lo;
  }
}

// chunked segment-sum over sorted rseg; atomic flush on boundaries only
__global__ __launch_bounds__(256) void k_relsums(const int* rseg, const int* rte,
                                                 const float* h, float* sums) {
  int base = blockIdx.x * 256;
  int d = threadIdx.x;
  int cnt = min(256, EC - base);
  float acc = 0.f;
  int prev = rseg[base];
  for (int i = 0; i < cnt; i++) {
    int e = base + i;
    int s = rseg[e];
    if (s != prev) {
      if (d < H) atomicAdd(&sums[prev * H + d], acc);
      acc = 0.f; prev = s;
    }
    if (d < H) acc += h[(size_t)rte[e] * H + d];
  }
  if (d < H) atomicAdd(&sums[prev * H + d], acc);
}

// ---------------- per-step: GRU on relations (thread-per-output-column GEMM) ----------------
__global__ __launch_bounds__(512) void k_gru2(const float* __restrict__ er,
                                              const float* __restrict__ sums,
                                              const int* __restrict__ segstart,
                                              const float* __restrict__ WihT,
                                              const float* __restrict__ WhhT,
                                              const float* __restrict__ b_ih,
                                              const float* __restrict__ b_hh,
                                              float* __restrict__ h0,
                                              float* __restrict__ h0_out) {
  __shared__ float xc[2 * H];      // x_cat row: [emb_rel | seg-mean]
  __shared__ float h0r[H];
  __shared__ float gi[3 * H], gh[3 * H];
  __shared__ float red[8];
  int r = blockIdx.x;
  int tid = threadIdx.x, wid = tid >> 6, lane = tid & 63;
  int cnt = segstart[r + 1] - segstart[r];
  float inv = cnt > 0 ? 1.0f / (float)cnt : 0.0f;
  if (tid < 2 * H)
    xc[tid] = (tid < H) ? er[r * H + tid] : sums[r * H + (tid - H)] * inv;
  if (tid < H) h0r[tid] = h0[r * H + tid];
  __syncthreads();

  for (int j = tid; j < 3 * H; j += 512) {
    float a = 0.f;
    #pragma unroll 4
    for (int k = 0; k < 2 * H; k++) a += xc[k] * WihT[k * (3 * H) + j];
    float b = 0.f;
    #pragma unroll 4
    for (int k = 0; k < H; k++) b += h0r[k] * WhhT[k * (3 * H) + j];
    gi[j] = a + b_ih[j];
    gh[j] = b + b_hh[j];
  }
  __syncthreads();

  float ssp = 0.f;
  for (int d = tid; d < H; d += 512) {
    float rg = sigmoidf(gi[d] + gh[d]);
    float z  = sigmoidf(gi[H + d] + gh[H + d]);
    float n  = tanhf(gi[2 * H + d] + rg * gh[2 * H + d]);
    float o  = (1.0f - z) * n + z * h0r[d];
    xc[d] = o;                       // reuse xc for output row
    ssp += o * o;
  }
  ssp = wave_sum(ssp);
  if (lane == 0) red[wid] = ssp;
  __syncthreads();
  float ss = 0.f;
  #pragma unroll
  for (int q = 0; q < 8; q++) ss += red[q];
  float sc = 1.0f / fmaxf(sqrtf(ss), 1e-12f);
  for (int d = tid; d < H; d += 512) {
    float o = xc[d] * sc;
    h0[r * H + d] = o;
    if (h0_out) h0_out[r * H + d] = o;
  }
}

// ---------------- per-step: fused node GEMMs (hW = h@Wn, tw = sigmoid(h@Tg+b)) ----------------
__global__ __launch_bounds__(256) void k_nodegemm(const float* __restrict__ h,
                                                  const float* __restrict__ wn,
                                                  const float* __restrict__ tg,
                                                  const float* __restrict__ tgb,
                                                  bf16* __restrict__ hWb,
                                                  bf16* __restrict__ twb) {
  int c = threadIdx.x;
  int row0 = blockIdx.x * 32;
  if (c >= H) return;
  float acc1[32] = {}, acc2[32] = {};
  for (int k = 0; k < H; k += 4) {
    float b1[4], b2[4];
    #pragma unroll
    for (int kk = 0; kk < 4; kk++) {
      b1[kk] = wn[(k + kk) * H + c];
      b2[kk] = tg[(k + kk) * H + c];
    }
    #pragma unroll
    for (int r = 0; r < 32; r++) {
      int rowc = min(row0 + r, NE - 1);
      const float4 a = *reinterpret_cast<const float4*>(h + (size_t)rowc * H + k);
      acc1[r] = fmaf(a.x, b1[0], fmaf(a.y, b1[1], fmaf(a.z, b1[2], fmaf(a.w, b1[3], acc1[r]))));
      acc2[r] = fmaf(a.x, b2[0], fmaf(a.y, b2[1], fmaf(a.z, b2[2], fmaf(a.w, b2[3], acc2[r]))));
    }
  }
  float bias = tgb[c];
  #pragma unroll
  for (int r = 0; r < 32; r++) {
    int row = row0 + r;
    if (row < NE) {
      hWb[(size_t)row * H + c] = f2b(acc1[r]);
      twb[(size_t)row * H + c] = f2b(sigmoidf(acc2[r] + bias));
    }
  }
}

// ---------------- per-step: CSR build by dst ----------------
__global__ void k_hist(const int* dst, int* deg) {
  int e = blockIdx.x * 256 + threadIdx.x;
  if (e < EC) atomicAdd(&deg[dst[e]], 1);
}

__global__ __launch_bounds__(256) void k_scan1(const int* deg, int* offs, int* bsums) {
  __shared__ int s[256];
  int i = blockIdx.x * 256 + threadIdx.x;
  int v = (i < NE) ? deg[i] : 0;
  s[threadIdx.x] = v;
  __syncthreads();
  for (int o = 1; o < 256; o <<= 1) {
    int add = (threadIdx.x >= o) ? s[threadIdx.x - o] : 0;
    __syncthreads();
    s[threadIdx.x] += add;
    __syncthreads();
  }
  if (i < NE) offs[i] = s[threadIdx.x] - v;  // exclusive
  if (threadIdx.x == 255) bsums[blockIdx.x] = s[255];
}

__global__ __launch_bounds__(256) void k_scan2(int* bsums) {
  __shared__ int s[256];
  int v = (threadIdx.x < NSCAN) ? bsums[threadIdx.x] : 0;
  s[threadIdx.x] = v;
  __syncthreads();
  for (int o = 1; o < 256; o <<= 1) {
    int add = (threadIdx.x >= o) ? s[threadIdx.x - o] : 0;
    __syncthreads();
    s[threadIdx.x] += add;
    __syncthreads();
  }
  if (threadIdx.x < NSCAN) bsums[threadIdx.x] = s[threadIdx.x] - v;  // exclusive
}

__global__ void k_scan3(int* offs, const int* bsums, int* cursor) {
  int i = blockIdx.x * 256 + threadIdx.x;
  if (i < NE) {
    int o = offs[i] + bsums[blockIdx.x];
    offs[i] = o;
    cursor[i] = o;
  }
  if (blockIdx.x == 0 && threadIdx.x == 0) offs[NE] = EC;
}

__global__ void k_scatter(const int* dst, int* cursor, int* eids) {
  int e = blockIdx.x * 256 + threadIdx.x;
  if (e < EC) {
    int pos = atomicAdd(&cursor[dst[e]], 1);
    eids[pos] = e;
  }
}

// ---------------- per-step: aggregate + rrelu + l2norm -> cur (stored in evolve[t] slot) ----------------
__global__ __launch_bounds__(256) void k_aggcur(const int* __restrict__ offs,
                                                const int* __restrict__ eids,
                                                const int* __restrict__ src,
                                                const int* __restrict__ et,
                                                const bf16* __restrict__ hWb,
                                                const float* __restrict__ relW,
                                                float* __restrict__ cur) {
  int wid = threadIdx.x >> 6, lane = threadIdx.x & 63;
  int i = blockIdx.x * 4 + wid;
  if (i >= NE) return;
  int s0 = offs[i], s1 = offs[i + 1];
  float acc[4] = {0.f, 0.f, 0.f, 0.f};
  for (int p = s0; p < s1; p++) {
    int e = eids[p];
    int s = src[e];
    int r = et[e];
    #pragma unroll
    for (int q = 0; q < 4; q++) {
      int d = lane + q * 64;
      if (d < H) acc[q] += b2f(hWb[(size_t)s * H + d]) + relW[r * H + d];
    }
  }
  int deg = s1 - s0;
  float nrm = deg > 0 ? 1.0f / (float)deg : 0.0f;
  float ss = 0.f;
  #pragma unroll
  for (int q = 0; q < 4; q++) {
    float v = acc[q] * nrm;
    v = v >= 0.f ? v : SLOPE * v;
    acc[q] = v;
    ss += v * v;
  }
  ss = wave_sum(ss);
  float sc = 1.0f / fmaxf(sqrtf(ss), 1e-12f);
  #pragma unroll
  for (int q = 0; q < 4; q++) {
    int d = lane + q * 64;
    if (d < H) cur[(size_t)i * H + d] = acc[q] * sc;
  }
}

// ---------------- per-step: time gate + combine + l2norm -> h, evolve (in-place over cur) ----------------
__global__ __launch_bounds__(256) void k_final(const bf16* __restrict__ twb,
                                               float* __restrict__ h,
                                               float* __restrict__ evolve) {
  int wid = threadIdx.x >> 6, lane = threadIdx.x & 63;
  int i = blockIdx.x * 4 + wid;
  if (i >= NE) return;
  float v[4]; float ss = 0.f;
  #pragma unroll
  for (int q = 0; q < 4; q++) {
    int d = lane + q * 64;
    if (d < H) {
      float cur = evolve[(size_t)i * H + d];
      float tw  = b2f(twb[(size_t)i * H + d]);
      float hv  = h[(size_t)i * H + d];
      float val = tw * cur + (1.0f - tw) * hv;
      v[q] = val; ss += val * val;
    } else v[q] = 0.f;
  }
  ss = wave_sum(ss);
  float sc = 1.0f / fmaxf(sqrtf(ss), 1e-12f);
  #pragma unroll
  for (int q = 0; q < 4; q++) {
    int d = lane + q * 64;
    if (d < H) {
      float o = v[q] * sc;
      h[(size_t)i * H + d] = o;
      evolve[(size_t)i * H + d] = o;
    }
  }
}

extern "C" void kernel_launch(void* const* d_in, const int* in_sizes, int n_in,
                              void* d_out, int out_size, void* d_ws, size_t ws_size,
                              hipStream_t stream) {
  const float* de  = (const float*)d_in[0];
  const float* er  = (const float*)d_in[1];
  const float* wih = (const float*)d_in[2];
  const float* whh = (const float*)d_in[3];
  const float* bih = (const float*)d_in[4];
  const float* bhh = (const float*)d_in[5];
  const float* wn  = (const float*)d_in[6];
  const float* tg  = (const float*)d_in[7];
  const float* tgb = (const float*)d_in[8];
  const int* src  = (const int*)d_in[9];
  const int* dst  = (const int*)d_in[10];
  const int* et   = (const int*)d_in[11];
  const int* rte  = (const int*)d_in[12];
  const int* rseg = (const int*)d_in[13];

  char* w = (char*)d_ws;
  auto alloc = [&](size_t bytes) -> char* {
    char* p = w;
    w += (bytes + 255) / 256 * 256;
    return p;
  };
  float* h     = (float*)alloc(sizeof(float) * (size_t)NE * H);   // 40 MB
  bf16*  hWb   = (bf16*) alloc(sizeof(bf16)  * (size_t)NE * H);   // 20 MB
  bf16*  twb   = (bf16*) alloc(sizeof(bf16)  * (size_t)NE * H);   // 20 MB
  float* relW  = (float*)alloc(sizeof(float) * R2C * H);
  float* h0    = (float*)alloc(sizeof(float) * R2C * H);
  float* sums  = (float*)alloc(sizeof(float) * R2C * H);
  float* WihT  = (float*)alloc(sizeof(float) * 2 * H * 3 * H);    // 960 KB
  float* WhhT  = (float*)alloc(sizeof(float) * H * 3 * H);        // 480 KB
  int* segstart= (int*)  alloc(sizeof(int) * (R2C + 1));
  int* deg     = (int*)  alloc(sizeof(int) * NE);
  int* offs    = (int*)  alloc(sizeof(int) * (NE + 1));
  int* cursor  = (int*)  alloc(sizeof(int) * NE);
  int* eids    = (int*)  alloc(sizeof(int) * EC);
  int* bsums   = (int*)  alloc(sizeof(int) * 256);
  (void)ws_size; (void)in_sizes; (void)n_in; (void)out_size;

  float* out    = (float*)d_out;
  float* evolve = out;                       // [TS, NE, H]
  float* h0out  = out + (size_t)TS * NE * H; // [R2C, H]

  const int gRow4  = (NE + 3) / 4;          // 12500
  const int gE     = (EC + 255) / 256;      // 1563
  const int gRel   = (R2C * H + 255) / 256; // 391
  const int gGemm  = (NE + 31) / 32;        // 1563
  const int gTr    = (2 * H * 3 * H + 255) / 256; // 938

  k_init_h<<<gRow4, 256, 0, stream>>>(de, h);
  k_init_h0<<<gRel, 256, 0, stream>>>(er, h0);
  k_relw<<<R2C, 256, 0, stream>>>(er, wn, relW);
  k_wtrans<<<gTr, 256, 0, stream>>>(wih, whh, WihT, WhhT);

  for (int t = 0; t < TS; t++) {
    const int* src_t  = src  + (size_t)t * EC;
    const int* dst_t  = dst  + (size_t)t * EC;
    const int* et_t   = et   + (size_t)t * EC;
    const int* rte_t  = rte  + (size_t)t * EC;
    const int* rseg_t = rseg + (size_t)t * EC;
    float* evo_t = evolve + (size_t)t * NE * H;

    // relation-segment means + GRU (uses pre-step h, h0)
    k_segbounds<<<1, 512, 0, stream>>>(rseg_t, segstart);
    k_zero_f<<<gRel, 256, 0, stream>>>(sums, R2C * H);
    k_relsums<<<gE, 256, 0, stream>>>(rseg_t, rte_t, h, sums);
    k_gru2<<<R2C, 512, 0, stream>>>(er, sums, segstart, WihT, WhhT, bih, bhh,
                                    h0, (t == TS - 1) ? h0out : (float*)nullptr);

    // node GEMMs (pre-step h)
    k_nodegemm<<<gGemm, 256, 0, stream>>>(h, wn, tg, tgb, hWb, twb);

    // CSR build by dst
    k_zero_i<<<NSCAN, 256, 0, stream>>>(deg, NE);
    k_hist<<<gE, 256, 0, stream>>>(dst_t, deg);
    k_scan1<<<NSCAN, 256, 0, stream>>>(deg, offs, bsums);
    k_scan2<<<1, 256, 0, stream>>>(bsums);
    k_scan3<<<NSCAN, 256, 0, stream>>>(offs, bsums, cursor);
    k_scatter<<<gE, 256, 0, stream>>>(dst_t, cursor, eids);

    // aggregate + rrelu + l2norm -> cur (stored in evolve[t] slot of d_out)
    k_aggcur<<<gRow4, 256, 0, stream>>>(offs, eids, src_t, et_t, hWb, relW, evo_t);

    // time gate + combine + l2norm; updates h in place, rewrites evolve[t] with h_new
    k_final<<<gRow4, 256, 0, stream>>>(twb, h, evo_t);
  }
}

// Round 4
// 2549.325 us; speedup vs baseline: 1.9202x; 1.3892x over previous
//
#include <hip/hip_runtime.h>
#include <hip/hip_bf16.h>

using bf16 = __hip_bfloat16;

constexpr int NE  = 50000;   // entities
constexpr int H   = 200;     // hidden dim
constexpr int R2C = 500;     // 2*num_rels
constexpr int TS  = 4;       // timesteps
constexpr int EC  = 400000;  // edges per step
constexpr float SLOPE = 0.22916666666666666f;  // rrelu eval slope
constexpr int NSCAN = (NE + 255) / 256;        // 196

// MFMA GEMM geometry
constexpr int KP = 224;      // K padded to 7*32
constexpr int NP = 208;      // N padded to 13*16
constexpr int KS = 7;        // k-steps of 32
constexpr int NT = 13;       // n-tiles of 16

#define DEVINL __device__ __forceinline__

typedef __bf16 bf16x8v __attribute__((ext_vector_type(8)));
typedef float  f32x4   __attribute__((ext_vector_type(4)));

DEVINL float b2f(bf16 v) { return __bfloat162float(v); }
DEVINL bf16  f2b(float v) { return __float2bfloat16(v); }
DEVINL unsigned short f2bu(float x) { bf16 b = f2b(x); return *reinterpret_cast<unsigned short*>(&b); }

DEVINL float wave_sum(float v) {
  #pragma unroll
  for (int o = 32; o > 0; o >>= 1) v += __shfl_xor(v, o, 64);
  return v;
}

DEVINL float sigmoidf(float x) { return 1.0f / (1.0f + expf(-x)); }

// ---------------- init ----------------
__global__ __launch_bounds__(256) void k_init_h(const float* de, float* h) {
  int wid = threadIdx.x >> 6, lane = threadIdx.x & 63;
  int row = blockIdx.x * 4 + wid;
  if (row >= NE) return;
  float v[4]; float ss = 0.f;
  #pragma unroll
  for (int q = 0; q < 4; q++) {
    int d = lane + q * 64;
    v[q] = (d < H) ? de[(size_t)row * H + d] : 0.f;
    ss += v[q] * v[q];
  }
  ss = wave_sum(ss);
  float sc = 1.0f / fmaxf(sqrtf(ss), 1e-12f);
  #pragma unroll
  for (int q = 0; q < 4; q++) {
    int d = lane + q * 64;
    if (d < H) h[(size_t)row * H + d] = v[q] * sc;
  }
}

__global__ __launch_bounds__(256) void k_init_h0(const float* er, float* h0) {
  int i = blockIdx.x * 256 + threadIdx.x;
  if (i < R2C * H) h0[i] = er[i];
}

// relW = emb_rel @ W_n   [R2C, H]
__global__ __launch_bounds__(256) void k_relw(const float* er, const float* wn, float* relW) {
  __shared__ float a[H];
  int r = blockIdx.x;
  for (int d = threadIdx.x; d < H; d += 256) a[d] = er[r * H + d];
  __syncthreads();
  for (int c = threadIdx.x; c < H; c += 256) {
    float s = 0.f;
    for (int k = 0; k < H; k++) s += a[k] * wn[k * H + c];
    relW[r * H + c] = s;
  }
}

// transpose GRU weights once: WihT[k][j] = wih[j][k] (400x600), WhhT[k][j] = whh[j][k] (200x600)
__global__ __launch_bounds__(256) void k_wtrans(const float* wih, const float* whh,
                                                float* WihT, float* WhhT) {
  int i = blockIdx.x * 256 + threadIdx.x;
  if (i < 2 * H * 3 * H) {
    int k = i / (3 * H), j = i % (3 * H);
    WihT[i] = wih[j * (2 * H) + k];
  }
  if (i < H * 3 * H) {
    int k = i / (3 * H), j = i % (3 * H);
    WhhT[i] = whh[j * H + k];
  }
}

// pack Wn and Tg into per-lane MFMA B-fragment order, zero-padded to [KP][NP].
// layout: bpack[m][((nt*KS + ks)*64 + lane)*8 + j] = W[k][n], k=ks*32+(lane>>4)*8+j, n=nt*16+(lane&15)
__global__ __launch_bounds__(256) void k_packb(const float* wn, const float* tg,
                                               unsigned short* bpack) {
  int t = blockIdx.x * 256 + threadIdx.x;
  int total = 2 * NT * KS * 64;
  if (t >= total) return;
  int m    = t / (NT * KS * 64);
  int rem  = t % (NT * KS * 64);
  int nt   = rem / (KS * 64);
  int rem2 = rem % (KS * 64);
  int ks   = rem2 / 64, lane = rem2 % 64;
  const float* W = m ? tg : wn;
  int n = nt * 16 + (lane & 15);
  unsigned short out[8];
  #pragma unroll
  for (int j = 0; j < 8; j++) {
    int k = ks * 32 + (lane >> 4) * 8 + j;
    float v = (k < H && n < H) ? W[k * H + n] : 0.f;
    out[j] = f2bu(v);
  }
  unsigned short* dst = bpack + (size_t)t * 8;
  #pragma unroll
  for (int j = 0; j < 8; j++) dst[j] = out[j];
}

// convert h (f32 [NE][H]) -> hb (bf16 [NE][KP], zero-padded cols 200..223)
__global__ __launch_bounds__(256) void k_h2b(const float* __restrict__ h,
                                             unsigned short* __restrict__ hb) {
  int i = (blockIdx.x * 256 + threadIdx.x) * 4;
  if (i >= NE * KP) return;
  int row = i / KP, col = i % KP;   // col % 4 == 0
  ushort4 o;
  if (col < H) {
    const float4 v = *reinterpret_cast<const float4*>(h + (size_t)row * H + col);
    o.x = f2bu(v.x); o.y = f2bu(v.y); o.z = f2bu(v.z); o.w = f2bu(v.w);
  } else {
    o.x = o.y = o.z = o.w = 0;
  }
  *reinterpret_cast<ushort4*>(hb + i) = o;
}

// ---------------- generic zero ----------------
__global__ void k_zero_f(float* p, int n) {
  int i = blockIdx.x * 256 + threadIdx.x;
  if (i < n) p[i] = 0.f;
}
__global__ void k_zero_i(int* p, int n) {
  int i = blockIdx.x * 256 + threadIdx.x;
  if (i < n) p[i] = 0;
}

// ---------------- per-step: relation segment bounds (sorted rseg) ----------------
__global__ __launch_bounds__(512) void k_segbounds(const int* rseg, int* segstart) {
  for (int r = threadIdx.x; r <= R2C; r += 512) {
    int lo = 0, hi = EC;
    while (lo < hi) { int m = (lo + hi) >> 1; if (rseg[m] < r) lo = m + 1; else hi = m; }
    segstart[r] = lo;
  }
}

// chunked segment-sum over sorted rseg; atomic flush on boundaries only
__global__ __launch_bounds__(256) void k_relsums(const int* rseg, const int* rte,
                                                 const float* h, float* sums) {
  int base = blockIdx.x * 256;
  int d = threadIdx.x;
  int cnt = min(256, EC - base);
  float acc = 0.f;
  int prev = rseg[base];
  for (int i = 0; i < cnt; i++) {
    int e = base + i;
    int s = rseg[e];
    if (s != prev) {
      if (d < H) atomicAdd(&sums[prev * H + d], acc);
      acc = 0.f; prev = s;
    }
    if (d < H) acc += h[(size_t)rte[e] * H + d];
  }
  if (d < H) atomicAdd(&sums[prev * H + d], acc);
}

// ---------------- per-step: GRU on relations (thread-per-output-column GEMM) ----------------
__global__ __launch_bounds__(512) void k_gru2(const float* __restrict__ er,
                                              const float* __restrict__ sums,
                                              const int* __restrict__ segstart,
                                              const float* __restrict__ WihT,
                                              const float* __restrict__ WhhT,
                                              const float* __restrict__ b_ih,
                                              const float* __restrict__ b_hh,
                                              float* __restrict__ h0,
                                              float* __restrict__ h0_out) {
  __shared__ float xc[2 * H];      // x_cat row: [emb_rel | seg-mean]
  __shared__ float h0r[H];
  __shared__ float gi[3 * H], gh[3 * H];
  __shared__ float red[8];
  int r = blockIdx.x;
  int tid = threadIdx.x, wid = tid >> 6, lane = tid & 63;
  int cnt = segstart[r + 1] - segstart[r];
  float inv = cnt > 0 ? 1.0f / (float)cnt : 0.0f;
  if (tid < 2 * H)
    xc[tid] = (tid < H) ? er[r * H + tid] : sums[r * H + (tid - H)] * inv;
  if (tid < H) h0r[tid] = h0[r * H + tid];
  __syncthreads();

  for (int j = tid; j < 3 * H; j += 512) {
    float a = 0.f;
    #pragma unroll 4
    for (int k = 0; k < 2 * H; k++) a += xc[k] * WihT[k * (3 * H) + j];
    float b = 0.f;
    #pragma unroll 4
    for (int k = 0; k < H; k++) b += h0r[k] * WhhT[k * (3 * H) + j];
    gi[j] = a + b_ih[j];
    gh[j] = b + b_hh[j];
  }
  __syncthreads();

  float ssp = 0.f;
  for (int d = tid; d < H; d += 512) {
    float rg = sigmoidf(gi[d] + gh[d]);
    float z  = sigmoidf(gi[H + d] + gh[H + d]);
    float n  = tanhf(gi[2 * H + d] + rg * gh[2 * H + d]);
    float o  = (1.0f - z) * n + z * h0r[d];
    xc[d] = o;                       // reuse xc for output row
    ssp += o * o;
  }
  ssp = wave_sum(ssp);
  if (lane == 0) red[wid] = ssp;
  __syncthreads();
  float ss = 0.f;
  #pragma unroll
  for (int q = 0; q < 8; q++) ss += red[q];
  float sc = 1.0f / fmaxf(sqrtf(ss), 1e-12f);
  for (int d = tid; d < H; d += 512) {
    float o = xc[d] * sc;
    h0[r * H + d] = o;
    if (h0_out) h0_out[r * H + d] = o;
  }
}

// ---------------- per-step: MFMA node GEMMs (hW = h@Wn, tw = sigmoid(h@Tg+b)) ----------------
__global__ __launch_bounds__(256) void k_mfma_gemm(const unsigned short* __restrict__ hb,
                                                   const unsigned short* __restrict__ bpack,
                                                   const float* __restrict__ tgb,
                                                   bf16* __restrict__ hWb,
                                                   bf16* __restrict__ twb) {
  int wid = threadIdx.x >> 6, lane = threadIdx.x & 63;
  int row0 = blockIdx.x * 64 + wid * 16;
  if (row0 >= NE) return;                 // wave-uniform
  f32x4 acc1[NT] = {};
  f32x4 acc2[NT] = {};
  int arow = min(row0 + (lane & 15), NE - 1);
  const unsigned short* ap = hb + (size_t)arow * KP + (lane >> 4) * 8;
  const unsigned short* b1p = bpack;
  const unsigned short* b2p = bpack + (size_t)NT * KS * 64 * 8;
  for (int ks = 0; ks < KS; ks++) {
    bf16x8v a = *reinterpret_cast<const bf16x8v*>(ap + ks * 32);
    #pragma unroll
    for (int nt = 0; nt < NT; nt++) {
      size_t boff = ((size_t)(nt * KS + ks) * 64 + lane) * 8;
      bf16x8v b1 = *reinterpret_cast<const bf16x8v*>(b1p + boff);
      bf16x8v b2 = *reinterpret_cast<const bf16x8v*>(b2p + boff);
      acc1[nt] = __builtin_amdgcn_mfma_f32_16x16x32_bf16(a, b1, acc1[nt], 0, 0, 0);
      acc2[nt] = __builtin_amdgcn_mfma_f32_16x16x32_bf16(a, b2, acc2[nt], 0, 0, 0);
    }
  }
  int colb = lane & 15;
  int rbase = row0 + (lane >> 4) * 4;
  #pragma unroll
  for (int nt = 0; nt < NT; nt++) {
    int col = nt * 16 + colb;
    bool cok = (col < H);
    float bias = cok ? tgb[col] : 0.f;
    #pragma unroll
    for (int q = 0; q < 4; q++) {
      int row = rbase + q;
      if (cok && row < NE) {
        hWb[(size_t)row * H + col] = f2b(acc1[nt][q]);
        twb[(size_t)row * H + col] = f2b(sigmoidf(acc2[nt][q] + bias));
      }
    }
  }
}

// ---------------- per-step: CSR build by dst ----------------
__global__ void k_hist(const int* dst, int* deg) {
  int e = blockIdx.x * 256 + threadIdx.x;
  if (e < EC) atomicAdd(&deg[dst[e]], 1);
}

__global__ __launch_bounds__(256) void k_scan1(const int* deg, int* offs, int* bsums) {
  __shared__ int s[256];
  int i = blockIdx.x * 256 + threadIdx.x;
  int v = (i < NE) ? deg[i] : 0;
  s[threadIdx.x] = v;
  __syncthreads();
  for (int o = 1; o < 256; o <<= 1) {
    int add = (threadIdx.x >= o) ? s[threadIdx.x - o] : 0;
    __syncthreads();
    s[threadIdx.x] += add;
    __syncthreads();
  }
  if (i < NE) offs[i] = s[threadIdx.x] - v;  // exclusive
  if (threadIdx.x == 255) bsums[blockIdx.x] = s[255];
}

__global__ __launch_bounds__(256) void k_scan2(int* bsums) {
  __shared__ int s[256];
  int v = (threadIdx.x < NSCAN) ? bsums[threadIdx.x] : 0;
  s[threadIdx.x] = v;
  __syncthreads();
  for (int o = 1; o < 256; o <<= 1) {
    int add = (threadIdx.x >= o) ? s[threadIdx.x - o] : 0;
    __syncthreads();
    s[threadIdx.x] += add;
    __syncthreads();
  }
  if (threadIdx.x < NSCAN) bsums[threadIdx.x] = s[threadIdx.x] - v;  // exclusive
}

__global__ void k_scan3(int* offs, const int* bsums, int* cursor) {
  int i = blockIdx.x * 256 + threadIdx.x;
  if (i < NE) {
    int o = offs[i] + bsums[blockIdx.x];
    offs[i] = o;
    cursor[i] = o;
  }
  if (blockIdx.x == 0 && threadIdx.x == 0) offs[NE] = EC;
}

__global__ void k_scatter(const int* dst, int* cursor, int* eids) {
  int e = blockIdx.x * 256 + threadIdx.x;
  if (e < EC) {
    int pos = atomicAdd(&cursor[dst[e]], 1);
    eids[pos] = e;
  }
}

// ---------------- per-step: aggregate + rrelu + l2norm -> cur (stored in evolve[t] slot) ----------------
__global__ __launch_bounds__(256) void k_aggcur(const int* __restrict__ offs,
                                                const int* __restrict__ eids,
                                                const int* __restrict__ src,
                                                const int* __restrict__ et,
                                                const bf16* __restrict__ hWb,
                                                const float* __restrict__ relW,
                                                float* __restrict__ cur) {
  int wid = threadIdx.x >> 6, lane = threadIdx.x & 63;
  int i = blockIdx.x * 4 + wid;
  if (i >= NE) return;
  int s0 = offs[i], s1 = offs[i + 1];
  float acc[4] = {0.f, 0.f, 0.f, 0.f};
  for (int p = s0; p < s1; p++) {
    int e = eids[p];
    int s = src[e];
    int r = et[e];
    #pragma unroll
    for (int q = 0; q < 4; q++) {
      int d = lane + q * 64;
      if (d < H) acc[q] += b2f(hWb[(size_t)s * H + d]) + relW[r * H + d];
    }
  }
  int deg = s1 - s0;
  float nrm = deg > 0 ? 1.0f / (float)deg : 0.0f;
  float ss = 0.f;
  #pragma unroll
  for (int q = 0; q < 4; q++) {
    float v = acc[q] * nrm;
    v = v >= 0.f ? v : SLOPE * v;
    acc[q] = v;
    ss += v * v;
  }
  ss = wave_sum(ss);
  float sc = 1.0f / fmaxf(sqrtf(ss), 1e-12f);
  #pragma unroll
  for (int q = 0; q < 4; q++) {
    int d = lane + q * 64;
    if (d < H) cur[(size_t)i * H + d] = acc[q] * sc;
  }
}

// ---------------- per-step: time gate + combine + l2norm -> h, evolve (in-place over cur) ----------------
__global__ __launch_bounds__(256) void k_final(const bf16* __restrict__ twb,
                                               float* __restrict__ h,
                                               float* __restrict__ evolve) {
  int wid = threadIdx.x >> 6, lane = threadIdx.x & 63;
  int i = blockIdx.x * 4 + wid;
  if (i >= NE) return;
  float v[4]; float ss = 0.f;
  #pragma unroll
  for (int q = 0; q < 4; q++) {
    int d = lane + q * 64;
    if (d < H) {
      float cur = evolve[(size_t)i * H + d];
      float tw  = b2f(twb[(size_t)i * H + d]);
      float hv  = h[(size_t)i * H + d];
      float val = tw * cur + (1.0f - tw) * hv;
      v[q] = val; ss += val * val;
    } else v[q] = 0.f;
  }
  ss = wave_sum(ss);
  float sc = 1.0f / fmaxf(sqrtf(ss), 1e-12f);
  #pragma unroll
  for (int q = 0; q < 4; q++) {
    int d = lane + q * 64;
    if (d < H) {
      float o = v[q] * sc;
      h[(size_t)i * H + d] = o;
      evolve[(size_t)i * H + d] = o;
    }
  }
}

extern "C" void kernel_launch(void* const* d_in, const int* in_sizes, int n_in,
                              void* d_out, int out_size, void* d_ws, size_t ws_size,
                              hipStream_t stream) {
  const float* de  = (const float*)d_in[0];
  const float* er  = (const float*)d_in[1];
  const float* wih = (const float*)d_in[2];
  const float* whh = (const float*)d_in[3];
  const float* bih = (const float*)d_in[4];
  const float* bhh = (const float*)d_in[5];
  const float* wn  = (const float*)d_in[6];
  const float* tg  = (const float*)d_in[7];
  const float* tgb = (const float*)d_in[8];
  const int* src  = (const int*)d_in[9];
  const int* dst  = (const int*)d_in[10];
  const int* et   = (const int*)d_in[11];
  const int* rte  = (const int*)d_in[12];
  const int* rseg = (const int*)d_in[13];

  char* w = (char*)d_ws;
  auto alloc = [&](size_t bytes) -> char* {
    char* p = w;
    w += (bytes + 255) / 256 * 256;
    return p;
  };
  float* h     = (float*)alloc(sizeof(float) * (size_t)NE * H);   // 40 MB
  bf16*  hWb   = (bf16*) alloc(sizeof(bf16)  * (size_t)NE * H);   // 20 MB
  bf16*  twb   = (bf16*) alloc(sizeof(bf16)  * (size_t)NE * H);   // 20 MB
  float* relW  = (float*)alloc(sizeof(float) * R2C * H);
  float* h0    = (float*)alloc(sizeof(float) * R2C * H);
  float* sums  = (float*)alloc(sizeof(float) * R2C * H);
  float* WihT  = (float*)alloc(sizeof(float) * 2 * H * 3 * H);    // 960 KB
  float* WhhT  = (float*)alloc(sizeof(float) * H * 3 * H);        // 480 KB
  unsigned short* bpack = (unsigned short*)alloc(sizeof(unsigned short) * 2 * NT * KS * 64 * 8); // 186 KB
  int* segstart= (int*)  alloc(sizeof(int) * (R2C + 1));
  int* deg     = (int*)  alloc(sizeof(int) * NE);
  int* offs    = (int*)  alloc(sizeof(int) * (NE + 1));
  int* cursor  = (int*)  alloc(sizeof(int) * NE);
  int* eids    = (int*)  alloc(sizeof(int) * EC);
  int* bsums   = (int*)  alloc(sizeof(int) * 256);
  (void)ws_size; (void)in_sizes; (void)n_in; (void)out_size;

  float* out    = (float*)d_out;
  float* evolve = out;                       // [TS, NE, H]
  float* h0out  = out + (size_t)TS * NE * H; // [R2C, H]

  const int gRow4  = (NE + 3) / 4;          // 12500
  const int gE     = (EC + 255) / 256;      // 1563
  const int gRel   = (R2C * H + 255) / 256; // 391
  const int gTr    = (2 * H * 3 * H + 255) / 256; // 938
  const int gPack  = (2 * NT * KS * 64 + 255) / 256;     // 46
  const int gH2b   = (NE * KP / 4 + 255) / 256;          // 10938
  const int gGemm  = (NE + 63) / 64;                     // 782

  k_init_h<<<gRow4, 256, 0, stream>>>(de, h);
  k_init_h0<<<gRel, 256, 0, stream>>>(er, h0);
  k_relw<<<R2C, 256, 0, stream>>>(er, wn, relW);
  k_wtrans<<<gTr, 256, 0, stream>>>(wih, whh, WihT, WhhT);
  k_packb<<<gPack, 256, 0, stream>>>(wn, tg, bpack);

  for (int t = 0; t < TS; t++) {
    const int* src_t  = src  + (size_t)t * EC;
    const int* dst_t  = dst  + (size_t)t * EC;
    const int* et_t   = et   + (size_t)t * EC;
    const int* rte_t  = rte  + (size_t)t * EC;
    const int* rseg_t = rseg + (size_t)t * EC;
    float* evo_t = evolve + (size_t)t * NE * H;
    // bf16 A matrix for the node GEMM aliases the evolve[t] slot (22.4 MB < 40 MB);
    // it is dead before k_aggcur overwrites the slot later in this step.
    unsigned short* hb = (unsigned short*)evo_t;

    // relation-segment means + GRU (uses pre-step h, h0)
    k_segbounds<<<1, 512, 0, stream>>>(rseg_t, segstart);
    k_zero_f<<<gRel, 256, 0, stream>>>(sums, R2C * H);
    k_relsums<<<gE, 256, 0, stream>>>(rseg_t, rte_t, h, sums);
    k_gru2<<<R2C, 512, 0, stream>>>(er, sums, segstart, WihT, WhhT, bih, bhh,
                                    h0, (t == TS - 1) ? h0out : (float*)nullptr);

    // node GEMMs via MFMA (pre-step h)
    k_h2b<<<gH2b, 256, 0, stream>>>(h, hb);
    k_mfma_gemm<<<gGemm, 256, 0, stream>>>(hb, bpack, tgb, hWb, twb);

    // CSR build by dst
    k_zero_i<<<NSCAN, 256, 0, stream>>>(deg, NE);
    k_hist<<<gE, 256, 0, stream>>>(dst_t, deg);
    k_scan1<<<NSCAN, 256, 0, stream>>>(deg, offs, bsums);
    k_scan2<<<1, 256, 0, stream>>>(bsums);
    k_scan3<<<NSCAN, 256, 0, stream>>>(offs, bsums, cursor);
    k_scatter<<<gE, 256, 0, stream>>>(dst_t, cursor, eids);

    // aggregate + rrelu + l2norm -> cur (stored in evolve[t] slot of d_out)
    k_aggcur<<<gRow4, 256, 0, stream>>>(offs, eids, src_t, et_t, hWb, relW, evo_t);

    // time gate + combine + l2norm; updates h in place, rewrites evolve[t] with h_new
    k_final<<<gRow4, 256, 0, stream>>>(twb, h, evo_t);
  }
}

// Round 5
// 1822.015 us; speedup vs baseline: 2.6867x; 1.3992x over previous
//
#include <hip/hip_runtime.h>
#include <hip/hip_bf16.h>

using bf16 = __hip_bfloat16;

constexpr int NE  = 50000;   // entities
constexpr int H   = 200;     // hidden dim
constexpr int R2C = 500;     // 2*num_rels
constexpr int TS  = 4;       // timesteps
constexpr int EC  = 400000;  // edges per step
constexpr float SLOPE = 0.22916666666666666f;  // rrelu eval slope
constexpr int NSCAN = (NE + 255) / 256;        // 196

// MFMA GEMM geometry
constexpr int KP = 224;      // K padded to 7*32
constexpr int NP = 208;      // N padded to 13*16
constexpr int KS = 7;        // k-steps of 32
constexpr int NT = 13;       // n-tiles of 16

constexpr int RCH = 128;     // edges per block in k_relsums

#define DEVINL __device__ __forceinline__

typedef __bf16 bf16x8v __attribute__((ext_vector_type(8)));
typedef float  f32x4   __attribute__((ext_vector_type(4)));

DEVINL float b2f(bf16 v) { return __bfloat162float(v); }
DEVINL bf16  f2b(float v) { return __float2bfloat16(v); }
DEVINL unsigned short f2bu(float x) { bf16 b = f2b(x); return *reinterpret_cast<unsigned short*>(&b); }
DEVINL float u2f(unsigned short u) { unsigned int w = (unsigned int)u << 16; float f; __builtin_memcpy(&f, &w, 4); return f; }

DEVINL float wave_sum(float v) {
  #pragma unroll
  for (int o = 32; o > 0; o >>= 1) v += __shfl_xor(v, o, 64);
  return v;
}

DEVINL float sigmoidf(float x) { return 1.0f / (1.0f + expf(-x)); }

// ---------------- init ----------------
__global__ __launch_bounds__(256) void k_init_h(const float* de, float* h) {
  int wid = threadIdx.x >> 6, lane = threadIdx.x & 63;
  int row = blockIdx.x * 4 + wid;
  if (row >= NE) return;
  float v[4]; float ss = 0.f;
  #pragma unroll
  for (int q = 0; q < 4; q++) {
    int d = lane + q * 64;
    v[q] = (d < H) ? de[(size_t)row * H + d] : 0.f;
    ss += v[q] * v[q];
  }
  ss = wave_sum(ss);
  float sc = 1.0f / fmaxf(sqrtf(ss), 1e-12f);
  #pragma unroll
  for (int q = 0; q < 4; q++) {
    int d = lane + q * 64;
    if (d < H) h[(size_t)row * H + d] = v[q] * sc;
  }
}

__global__ __launch_bounds__(256) void k_init_h0(const float* er, float* h0) {
  int i = blockIdx.x * 256 + threadIdx.x;
  if (i < R2C * H) h0[i] = er[i];
}

// relW = emb_rel @ W_n   [R2C, H]
__global__ __launch_bounds__(256) void k_relw(const float* er, const float* wn, float* relW) {
  __shared__ float a[H];
  int r = blockIdx.x;
  for (int d = threadIdx.x; d < H; d += 256) a[d] = er[r * H + d];
  __syncthreads();
  for (int c = threadIdx.x; c < H; c += 256) {
    float s = 0.f;
    for (int k = 0; k < H; k++) s += a[k] * wn[k * H + c];
    relW[r * H + c] = s;
  }
}

// transpose GRU weights once: WihT[k][j] = wih[j][k] (400x600), WhhT[k][j] = whh[j][k] (200x600)
__global__ __launch_bounds__(256) void k_wtrans(const float* wih, const float* whh,
                                                float* WihT, float* WhhT) {
  int i = blockIdx.x * 256 + threadIdx.x;
  if (i < 2 * H * 3 * H) {
    int k = i / (3 * H), j = i % (3 * H);
    WihT[i] = wih[j * (2 * H) + k];
  }
  if (i < H * 3 * H) {
    int k = i / (3 * H), j = i % (3 * H);
    WhhT[i] = whh[j * H + k];
  }
}

// pack Wn and Tg into per-lane MFMA B-fragment order, zero-padded to [KP][NP].
__global__ __launch_bounds__(256) void k_packb(const float* wn, const float* tg,
                                               unsigned short* bpack) {
  int t = blockIdx.x * 256 + threadIdx.x;
  int total = 2 * NT * KS * 64;
  if (t >= total) return;
  int m    = t / (NT * KS * 64);
  int rem  = t % (NT * KS * 64);
  int nt   = rem / (KS * 64);
  int rem2 = rem % (KS * 64);
  int ks   = rem2 / 64, lane = rem2 % 64;
  const float* W = m ? tg : wn;
  int n = nt * 16 + (lane & 15);
  unsigned short out[8];
  #pragma unroll
  for (int j = 0; j < 8; j++) {
    int k = ks * 32 + (lane >> 4) * 8 + j;
    float v = (k < H && n < H) ? W[k * H + n] : 0.f;
    out[j] = f2bu(v);
  }
  unsigned short* dst = bpack + (size_t)t * 8;
  #pragma unroll
  for (int j = 0; j < 8; j++) dst[j] = out[j];
}

// convert h (f32 [NE][H]) -> hb (bf16 [NE][KP], zero-padded cols 200..223)
__global__ __launch_bounds__(256) void k_h2b(const float* __restrict__ h,
                                             unsigned short* __restrict__ hb) {
  int i = (blockIdx.x * 256 + threadIdx.x) * 4;
  if (i >= NE * KP) return;
  int row = i / KP, col = i % KP;   // col % 4 == 0
  ushort4 o;
  if (col < H) {
    const float4 v = *reinterpret_cast<const float4*>(h + (size_t)row * H + col);
    o.x = f2bu(v.x); o.y = f2bu(v.y); o.z = f2bu(v.z); o.w = f2bu(v.w);
  } else {
    o.x = o.y = o.z = o.w = 0;
  }
  *reinterpret_cast<ushort4*>(hb + i) = o;
}

// ---------------- generic zero ----------------
__global__ void k_zero_f(float* p, int n) {
  int i = blockIdx.x * 256 + threadIdx.x;
  if (i < n) p[i] = 0.f;
}
__global__ void k_zero_i(int* p, int n) {
  int i = blockIdx.x * 256 + threadIdx.x;
  if (i < n) p[i] = 0;
}

// ---------------- per-step: relation segment bounds (sorted rseg) ----------------
__global__ __launch_bounds__(512) void k_segbounds(const int* rseg, int* segstart) {
  for (int r = threadIdx.x; r <= R2C; r += 512) {
    int lo = 0, hi = EC;
    while (lo < hi) { int m = (lo + hi) >> 1; if (rseg[m] < r) lo = m + 1; else hi = m; }
    segstart[r] = lo;
  }
}

// segment-sum over sorted rseg, gathering bf16 rows of hb.
// 128 edges/block, 4 independent accumulator chains; block-uniform fast path.
__global__ __launch_bounds__(256) void k_relsums(const int* __restrict__ rseg,
                                                 const int* __restrict__ rte,
                                                 const unsigned short* __restrict__ hb,
                                                 float* __restrict__ sums) {
  int base = blockIdx.x * RCH;
  int d = threadIdx.x;
  bool act = d < H;
  float a0 = 0.f, a1 = 0.f, a2 = 0.f, a3 = 0.f;
  int prev = rseg[base];
  for (int g = 0; g < RCH; g += 4) {
    int e = base + g;
    int4 sg = *reinterpret_cast<const int4*>(rseg + e);
    int4 rr = *reinterpret_cast<const int4*>(rte + e);
    if (sg.w == prev) {            // sorted => whole group in same segment (uniform branch)
      if (act) {
        a0 += u2f(hb[(size_t)rr.x * KP + d]);
        a1 += u2f(hb[(size_t)rr.y * KP + d]);
        a2 += u2f(hb[(size_t)rr.z * KP + d]);
        a3 += u2f(hb[(size_t)rr.w * KP + d]);
      }
    } else {                       // boundary group (rare): scalar path
      int ss[4] = {sg.x, sg.y, sg.z, sg.w};
      int rr2[4] = {rr.x, rr.y, rr.z, rr.w};
      #pragma unroll
      for (int j = 0; j < 4; j++) {
        if (ss[j] != prev) {
          if (act) atomicAdd(&sums[prev * H + d], a0 + a1 + a2 + a3);
          a0 = a1 = a2 = a3 = 0.f;
          prev = ss[j];
        }
        if (act) a0 += u2f(hb[(size_t)rr2[j] * KP + d]);
      }
    }
  }
  if (act) atomicAdd(&sums[prev * H + d], a0 + a1 + a2 + a3);
}

// ---------------- per-step: GRU on relations (thread-per-output-column GEMM) ----------------
__global__ __launch_bounds__(512) void k_gru2(const float* __restrict__ er,
                                              const float* __restrict__ sums,
                                              const int* __restrict__ segstart,
                                              const float* __restrict__ WihT,
                                              const float* __restrict__ WhhT,
                                              const float* __restrict__ b_ih,
                                              const float* __restrict__ b_hh,
                                              float* __restrict__ h0,
                                              float* __restrict__ h0_out) {
  __shared__ float xc[2 * H];      // x_cat row: [emb_rel | seg-mean]
  __shared__ float h0r[H];
  __shared__ float gi[3 * H], gh[3 * H];
  __shared__ float red[8];
  int r = blockIdx.x;
  int tid = threadIdx.x, wid = tid >> 6, lane = tid & 63;
  int cnt = segstart[r + 1] - segstart[r];
  float inv = cnt > 0 ? 1.0f / (float)cnt : 0.0f;
  if (tid < 2 * H)
    xc[tid] = (tid < H) ? er[r * H + tid] : sums[r * H + (tid - H)] * inv;
  if (tid < H) h0r[tid] = h0[r * H + tid];
  __syncthreads();

  for (int j = tid; j < 3 * H; j += 512) {
    float a = 0.f;
    #pragma unroll 4
    for (int k = 0; k < 2 * H; k++) a += xc[k] * WihT[k * (3 * H) + j];
    float b = 0.f;
    #pragma unroll 4
    for (int k = 0; k < H; k++) b += h0r[k] * WhhT[k * (3 * H) + j];
    gi[j] = a + b_ih[j];
    gh[j] = b + b_hh[j];
  }
  __syncthreads();

  float ssp = 0.f;
  for (int d = tid; d < H; d += 512) {
    float rg = sigmoidf(gi[d] + gh[d]);
    float z  = sigmoidf(gi[H + d] + gh[H + d]);
    float n  = tanhf(gi[2 * H + d] + rg * gh[2 * H + d]);
    float o  = (1.0f - z) * n + z * h0r[d];
    xc[d] = o;                       // reuse xc for output row
    ssp += o * o;
  }
  ssp = wave_sum(ssp);
  if (lane == 0) red[wid] = ssp;
  __syncthreads();
  float ss = 0.f;
  #pragma unroll
  for (int q = 0; q < 8; q++) ss += red[q];
  float sc = 1.0f / fmaxf(sqrtf(ss), 1e-12f);
  for (int d = tid; d < H; d += 512) {
    float o = xc[d] * sc;
    h0[r * H + d] = o;
    if (h0_out) h0_out[r * H + d] = o;
  }
}

// ---------------- per-step: MFMA node GEMMs (hW = h@Wn, tw = sigmoid(h@Tg+b)) ----------------
__global__ __launch_bounds__(256) void k_mfma_gemm(const unsigned short* __restrict__ hb,
                                                   const unsigned short* __restrict__ bpack,
                                                   const float* __restrict__ tgb,
                                                   bf16* __restrict__ hWb,
                                                   bf16* __restrict__ twb) {
  int wid = threadIdx.x >> 6, lane = threadIdx.x & 63;
  int row0 = blockIdx.x * 64 + wid * 16;
  if (row0 >= NE) return;                 // wave-uniform
  f32x4 acc1[NT] = {};
  f32x4 acc2[NT] = {};
  int arow = min(row0 + (lane & 15), NE - 1);
  const unsigned short* ap = hb + (size_t)arow * KP + (lane >> 4) * 8;
  const unsigned short* b1p = bpack;
  const unsigned short* b2p = bpack + (size_t)NT * KS * 64 * 8;
  for (int ks = 0; ks < KS; ks++) {
    bf16x8v a = *reinterpret_cast<const bf16x8v*>(ap + ks * 32);
    #pragma unroll
    for (int nt = 0; nt < NT; nt++) {
      size_t boff = ((size_t)(nt * KS + ks) * 64 + lane) * 8;
      bf16x8v b1 = *reinterpret_cast<const bf16x8v*>(b1p + boff);
      bf16x8v b2 = *reinterpret_cast<const bf16x8v*>(b2p + boff);
      acc1[nt] = __builtin_amdgcn_mfma_f32_16x16x32_bf16(a, b1, acc1[nt], 0, 0, 0);
      acc2[nt] = __builtin_amdgcn_mfma_f32_16x16x32_bf16(a, b2, acc2[nt], 0, 0, 0);
    }
  }
  int colb = lane & 15;
  int rbase = row0 + (lane >> 4) * 4;
  #pragma unroll
  for (int nt = 0; nt < NT; nt++) {
    int col = nt * 16 + colb;
    bool cok = (col < H);
    float bias = cok ? tgb[col] : 0.f;
    #pragma unroll
    for (int q = 0; q < 4; q++) {
      int row = rbase + q;
      if (cok && row < NE) {
        hWb[(size_t)row * H + col] = f2b(acc1[nt][q]);
        twb[(size_t)row * H + col] = f2b(sigmoidf(acc2[nt][q] + bias));
      }
    }
  }
}

// ---------------- per-step: CSR build by dst ----------------
__global__ void k_hist(const int* dst, int* deg) {
  int e = blockIdx.x * 256 + threadIdx.x;
  if (e < EC) atomicAdd(&deg[dst[e]], 1);
}

__global__ __launch_bounds__(256) void k_scan1(const int* deg, int* offs, int* bsums) {
  __shared__ int s[256];
  int i = blockIdx.x * 256 + threadIdx.x;
  int v = (i < NE) ? deg[i] : 0;
  s[threadIdx.x] = v;
  __syncthreads();
  for (int o = 1; o < 256; o <<= 1) {
    int add = (threadIdx.x >= o) ? s[threadIdx.x - o] : 0;
    __syncthreads();
    s[threadIdx.x] += add;
    __syncthreads();
  }
  if (i < NE) offs[i] = s[threadIdx.x] - v;  // exclusive
  if (threadIdx.x == 255) bsums[blockIdx.x] = s[255];
}

__global__ __launch_bounds__(256) void k_scan2(int* bsums) {
  __shared__ int s[256];
  int v = (threadIdx.x < NSCAN) ? bsums[threadIdx.x] : 0;
  s[threadIdx.x] = v;
  __syncthreads();
  for (int o = 1; o < 256; o <<= 1) {
    int add = (threadIdx.x >= o) ? s[threadIdx.x - o] : 0;
    __syncthreads();
    s[threadIdx.x] += add;
    __syncthreads();
  }
  if (threadIdx.x < NSCAN) bsums[threadIdx.x] = s[threadIdx.x] - v;  // exclusive
}

__global__ void k_scan3(int* offs, const int* bsums, int* cursor) {
  int i = blockIdx.x * 256 + threadIdx.x;
  if (i < NE) {
    int o = offs[i] + bsums[blockIdx.x];
    offs[i] = o;
    cursor[i] = o;
  }
  if (blockIdx.x == 0 && threadIdx.x == 0) offs[NE] = EC;
}

__global__ void k_scatter(const int* dst, int* cursor, int* eids) {
  int e = blockIdx.x * 256 + threadIdx.x;
  if (e < EC) {
    int pos = atomicAdd(&cursor[dst[e]], 1);
    eids[pos] = e;
  }
}

// ---------------- per-step: aggregate + rrelu + l2norm -> cur (stored in evolve[t] slot) ----------------
__global__ __launch_bounds__(256) void k_aggcur(const int* __restrict__ offs,
                                                const int* __restrict__ eids,
                                                const int* __restrict__ src,
                                                const int* __restrict__ et,
                                                const bf16* __restrict__ hWb,
                                                const float* __restrict__ relW,
                                                float* __restrict__ cur) {
  int wid = threadIdx.x >> 6, lane = threadIdx.x & 63;
  int i = blockIdx.x * 4 + wid;
  if (i >= NE) return;
  int s0 = offs[i], s1 = offs[i + 1];
  float acc[4] = {0.f, 0.f, 0.f, 0.f};
  for (int p = s0; p < s1; p++) {
    int e = eids[p];
    int s = src[e];
    int r = et[e];
    #pragma unroll
    for (int q = 0; q < 4; q++) {
      int d = lane + q * 64;
      if (d < H) acc[q] += b2f(hWb[(size_t)s * H + d]) + relW[r * H + d];
    }
  }
  int deg = s1 - s0;
  float nrm = deg > 0 ? 1.0f / (float)deg : 0.0f;
  float ss = 0.f;
  #pragma unroll
  for (int q = 0; q < 4; q++) {
    float v = acc[q] * nrm;
    v = v >= 0.f ? v : SLOPE * v;
    acc[q] = v;
    ss += v * v;
  }
  ss = wave_sum(ss);
  float sc = 1.0f / fmaxf(sqrtf(ss), 1e-12f);
  #pragma unroll
  for (int q = 0; q < 4; q++) {
    int d = lane + q * 64;
    if (d < H) cur[(size_t)i * H + d] = acc[q] * sc;
  }
}

// ---------------- per-step: time gate + combine + l2norm -> h, evolve (in-place over cur) ----------------
__global__ __launch_bounds__(256) void k_final(const bf16* __restrict__ twb,
                                               float* __restrict__ h,
                                               float* __restrict__ evolve) {
  int wid = threadIdx.x >> 6, lane = threadIdx.x & 63;
  int i = blockIdx.x * 4 + wid;
  if (i >= NE) return;
  float v[4]; float ss = 0.f;
  #pragma unroll
  for (int q = 0; q < 4; q++) {
    int d = lane + q * 64;
    if (d < H) {
      float cur = evolve[(size_t)i * H + d];
      float tw  = b2f(twb[(size_t)i * H + d]);
      float hv  = h[(size_t)i * H + d];
      float val = tw * cur + (1.0f - tw) * hv;
      v[q] = val; ss += val * val;
    } else v[q] = 0.f;
  }
  ss = wave_sum(ss);
  float sc = 1.0f / fmaxf(sqrtf(ss), 1e-12f);
  #pragma unroll
  for (int q = 0; q < 4; q++) {
    int d = lane + q * 64;
    if (d < H) {
      float o = v[q] * sc;
      h[(size_t)i * H + d] = o;
      evolve[(size_t)i * H + d] = o;
    }
  }
}

extern "C" void kernel_launch(void* const* d_in, const int* in_sizes, int n_in,
                              void* d_out, int out_size, void* d_ws, size_t ws_size,
                              hipStream_t stream) {
  const float* de  = (const float*)d_in[0];
  const float* er  = (const float*)d_in[1];
  const float* wih = (const float*)d_in[2];
  const float* whh = (const float*)d_in[3];
  const float* bih = (const float*)d_in[4];
  const float* bhh = (const float*)d_in[5];
  const float* wn  = (const float*)d_in[6];
  const float* tg  = (const float*)d_in[7];
  const float* tgb = (const float*)d_in[8];
  const int* src  = (const int*)d_in[9];
  const int* dst  = (const int*)d_in[10];
  const int* et   = (const int*)d_in[11];
  const int* rte  = (const int*)d_in[12];
  const int* rseg = (const int*)d_in[13];

  char* w = (char*)d_ws;
  auto alloc = [&](size_t bytes) -> char* {
    char* p = w;
    w += (bytes + 255) / 256 * 256;
    return p;
  };
  float* h     = (float*)alloc(sizeof(float) * (size_t)NE * H);   // 40 MB
  bf16*  hWb   = (bf16*) alloc(sizeof(bf16)  * (size_t)NE * H);   // 20 MB
  bf16*  twb   = (bf16*) alloc(sizeof(bf16)  * (size_t)NE * H);   // 20 MB
  float* relW  = (float*)alloc(sizeof(float) * R2C * H);
  float* h0    = (float*)alloc(sizeof(float) * R2C * H);
  float* sums  = (float*)alloc(sizeof(float) * R2C * H);
  float* WihT  = (float*)alloc(sizeof(float) * 2 * H * 3 * H);    // 960 KB
  float* WhhT  = (float*)alloc(sizeof(float) * H * 3 * H);        // 480 KB
  unsigned short* bpack = (unsigned short*)alloc(sizeof(unsigned short) * 2 * NT * KS * 64 * 8); // 186 KB
  int* segstart= (int*)  alloc(sizeof(int) * (R2C + 1));
  int* deg     = (int*)  alloc(sizeof(int) * NE);
  int* offs    = (int*)  alloc(sizeof(int) * (NE + 1));
  int* cursor  = (int*)  alloc(sizeof(int) * NE);
  int* eids    = (int*)  alloc(sizeof(int) * EC);
  int* bsums   = (int*)  alloc(sizeof(int) * 256);
  (void)ws_size; (void)in_sizes; (void)n_in; (void)out_size;

  float* out    = (float*)d_out;
  float* evolve = out;                       // [TS, NE, H]
  float* h0out  = out + (size_t)TS * NE * H; // [R2C, H]

  const int gRow4  = (NE + 3) / 4;          // 12500
  const int gE     = (EC + 255) / 256;      // 1563
  const int gRel   = (R2C * H + 255) / 256; // 391
  const int gTr    = (2 * H * 3 * H + 255) / 256; // 938
  const int gPack  = (2 * NT * KS * 64 + 255) / 256;     // 46
  const int gH2b   = (NE * KP / 4 + 255) / 256;          // 10938
  const int gGemm  = (NE + 63) / 64;                     // 782
  const int gRelsum= EC / RCH;                           // 3125

  k_init_h<<<gRow4, 256, 0, stream>>>(de, h);
  k_init_h0<<<gRel, 256, 0, stream>>>(er, h0);
  k_relw<<<R2C, 256, 0, stream>>>(er, wn, relW);
  k_wtrans<<<gTr, 256, 0, stream>>>(wih, whh, WihT, WhhT);
  k_packb<<<gPack, 256, 0, stream>>>(wn, tg, bpack);

  for (int t = 0; t < TS; t++) {
    const int* src_t  = src  + (size_t)t * EC;
    const int* dst_t  = dst  + (size_t)t * EC;
    const int* et_t   = et   + (size_t)t * EC;
    const int* rte_t  = rte  + (size_t)t * EC;
    const int* rseg_t = rseg + (size_t)t * EC;
    float* evo_t = evolve + (size_t)t * NE * H;
    // bf16 A matrix (and relsums gather source) aliases the evolve[t] slot
    // (22.4 MB < 40 MB); dead before k_aggcur overwrites the slot.
    unsigned short* hb = (unsigned short*)evo_t;

    // bf16 copy of pre-step h first: feeds both relsums gather and MFMA GEMM
    k_h2b<<<gH2b, 256, 0, stream>>>(h, hb);

    // relation-segment means + GRU (uses pre-step h, h0)
    k_segbounds<<<1, 512, 0, stream>>>(rseg_t, segstart);
    k_zero_f<<<gRel, 256, 0, stream>>>(sums, R2C * H);
    k_relsums<<<gRelsum, 256, 0, stream>>>(rseg_t, rte_t, hb, sums);
    k_gru2<<<R2C, 512, 0, stream>>>(er, sums, segstart, WihT, WhhT, bih, bhh,
                                    h0, (t == TS - 1) ? h0out : (float*)nullptr);

    // node GEMMs via MFMA (pre-step h)
    k_mfma_gemm<<<gGemm, 256, 0, stream>>>(hb, bpack, tgb, hWb, twb);

    // CSR build by dst
    k_zero_i<<<NSCAN, 256, 0, stream>>>(deg, NE);
    k_hist<<<gE, 256, 0, stream>>>(dst_t, deg);
    k_scan1<<<NSCAN, 256, 0, stream>>>(deg, offs, bsums);
    k_scan2<<<1, 256, 0, stream>>>(bsums);
    k_scan3<<<NSCAN, 256, 0, stream>>>(offs, bsums, cursor);
    k_scatter<<<gE, 256, 0, stream>>>(dst_t, cursor, eids);

    // aggregate + rrelu + l2norm -> cur (stored in evolve[t] slot of d_out)
    k_aggcur<<<gRow4, 256, 0, stream>>>(offs, eids, src_t, et_t, hWb, relW, evo_t);

    // time gate + combine + l2norm; updates h in place, rewrites evolve[t] with h_new
    k_final<<<gRow4, 256, 0, stream>>>(twb, h, evo_t);
  }
}

// Round 6
// 1553.436 us; speedup vs baseline: 3.1513x; 1.1729x over previous
//
#include <hip/hip_runtime.h>
#include <hip/hip_bf16.h>

using bf16 = __hip_bfloat16;

constexpr int NE  = 50000;   // entities
constexpr int H   = 200;     // hidden dim
constexpr int R2C = 500;     // 2*num_rels
constexpr int TS  = 4;       // timesteps
constexpr int EC  = 400000;  // edges per step
constexpr float SLOPE = 0.22916666666666666f;  // rrelu eval slope
constexpr int NSCAN = (NE + 255) / 256;        // 196

// MFMA GEMM geometry
constexpr int KP = 224;      // K padded to 7*32
constexpr int NP = 208;      // N padded to 13*16
constexpr int KS = 7;        // k-steps of 32
constexpr int NT = 13;       // n-tiles of 16

constexpr int RCH = 128;     // edges per block in k_relsums

#define DEVINL __device__ __forceinline__

typedef __bf16 bf16x8v __attribute__((ext_vector_type(8)));
typedef float  f32x4   __attribute__((ext_vector_type(4)));

DEVINL float b2f(bf16 v) { return __bfloat162float(v); }
DEVINL bf16  f2b(float v) { return __float2bfloat16(v); }
DEVINL unsigned short f2bu(float x) { bf16 b = f2b(x); return *reinterpret_cast<unsigned short*>(&b); }
DEVINL float u2f(unsigned short u) { unsigned int w = (unsigned int)u << 16; float f; __builtin_memcpy(&f, &w, 4); return f; }

DEVINL float wave_sum(float v) {
  #pragma unroll
  for (int o = 32; o > 0; o >>= 1) v += __shfl_xor(v, o, 64);
  return v;
}

DEVINL float sigmoidf(float x) { return 1.0f / (1.0f + expf(-x)); }

// ---------------- init ----------------
__global__ __launch_bounds__(256) void k_init_h(const float* de, float* h) {
  int wid = threadIdx.x >> 6, lane = threadIdx.x & 63;
  int row = blockIdx.x * 4 + wid;
  if (row >= NE) return;
  float v[4]; float ss = 0.f;
  #pragma unroll
  for (int q = 0; q < 4; q++) {
    int d = lane + q * 64;
    v[q] = (d < H) ? de[(size_t)row * H + d] : 0.f;
    ss += v[q] * v[q];
  }
  ss = wave_sum(ss);
  float sc = 1.0f / fmaxf(sqrtf(ss), 1e-12f);
  #pragma unroll
  for (int q = 0; q < 4; q++) {
    int d = lane + q * 64;
    if (d < H) h[(size_t)row * H + d] = v[q] * sc;
  }
}

__global__ __launch_bounds__(256) void k_init_h0(const float* er, float* h0) {
  int i = blockIdx.x * 256 + threadIdx.x;
  if (i < R2C * H) h0[i] = er[i];
}

// relW = emb_rel @ W_n   [R2C, H]
__global__ __launch_bounds__(256) void k_relw(const float* er, const float* wn, float* relW) {
  __shared__ float a[H];
  int r = blockIdx.x;
  for (int d = threadIdx.x; d < H; d += 256) a[d] = er[r * H + d];
  __syncthreads();
  for (int c = threadIdx.x; c < H; c += 256) {
    float s = 0.f;
    for (int k = 0; k < H; k++) s += a[k] * wn[k * H + c];
    relW[r * H + c] = s;
  }
}

// transpose GRU weights once: WihT[k][j] = wih[j][k] (400x600), WhhT[k][j] = whh[j][k] (200x600)
__global__ __launch_bounds__(256) void k_wtrans(const float* wih, const float* whh,
                                                float* WihT, float* WhhT) {
  int i = blockIdx.x * 256 + threadIdx.x;
  if (i < 2 * H * 3 * H) {
    int k = i / (3 * H), j = i % (3 * H);
    WihT[i] = wih[j * (2 * H) + k];
  }
  if (i < H * 3 * H) {
    int k = i / (3 * H), j = i % (3 * H);
    WhhT[i] = whh[j * H + k];
  }
}

// pack Wn and Tg into per-lane MFMA B-fragment order, zero-padded to [KP][NP].
__global__ __launch_bounds__(256) void k_packb(const float* wn, const float* tg,
                                               unsigned short* bpack) {
  int t = blockIdx.x * 256 + threadIdx.x;
  int total = 2 * NT * KS * 64;
  if (t >= total) return;
  int m    = t / (NT * KS * 64);
  int rem  = t % (NT * KS * 64);
  int nt   = rem / (KS * 64);
  int rem2 = rem % (KS * 64);
  int ks   = rem2 / 64, lane = rem2 % 64;
  const float* W = m ? tg : wn;
  int n = nt * 16 + (lane & 15);
  unsigned short out[8];
  #pragma unroll
  for (int j = 0; j < 8; j++) {
    int k = ks * 32 + (lane >> 4) * 8 + j;
    float v = (k < H && n < H) ? W[k * H + n] : 0.f;
    out[j] = f2bu(v);
  }
  unsigned short* dst = bpack + (size_t)t * 8;
  #pragma unroll
  for (int j = 0; j < 8; j++) dst[j] = out[j];
}

// convert h (f32 [NE][H]) -> hb (bf16 [NE][KP], zero-padded cols 200..223)
__global__ __launch_bounds__(256) void k_h2b(const float* __restrict__ h,
                                             unsigned short* __restrict__ hb) {
  int i = (blockIdx.x * 256 + threadIdx.x) * 4;
  if (i >= NE * KP) return;
  int row = i / KP, col = i % KP;   // col % 4 == 0
  ushort4 o;
  if (col < H) {
    const float4 v = *reinterpret_cast<const float4*>(h + (size_t)row * H + col);
    o.x = f2bu(v.x); o.y = f2bu(v.y); o.z = f2bu(v.z); o.w = f2bu(v.w);
  } else {
    o.x = o.y = o.z = o.w = 0;
  }
  *reinterpret_cast<ushort4*>(hb + i) = o;
}

// ---------------- generic zero ----------------
__global__ void k_zero_f(float* p, int n) {
  int i = blockIdx.x * 256 + threadIdx.x;
  if (i < n) p[i] = 0.f;
}
__global__ void k_zero_i(int* p, int n) {
  int i = blockIdx.x * 256 + threadIdx.x;
  if (i < n) p[i] = 0;
}

// ---------------- per-step: relation segment bounds (sorted rseg) ----------------
__global__ __launch_bounds__(512) void k_segbounds(const int* rseg, int* segstart) {
  for (int r = threadIdx.x; r <= R2C; r += 512) {
    int lo = 0, hi = EC;
    while (lo < hi) { int m = (lo + hi) >> 1; if (rseg[m] < r) lo = m + 1; else hi = m; }
    segstart[r] = lo;
  }
}

// segment-sum over sorted rseg, gathering bf16 rows of hb.
// 128 edges/block, 4 independent accumulator chains; block-uniform fast path.
__global__ __launch_bounds__(256) void k_relsums(const int* __restrict__ rseg,
                                                 const int* __restrict__ rte,
                                                 const unsigned short* __restrict__ hb,
                                                 float* __restrict__ sums) {
  int base = blockIdx.x * RCH;
  int d = threadIdx.x;
  bool act = d < H;
  float a0 = 0.f, a1 = 0.f, a2 = 0.f, a3 = 0.f;
  int prev = rseg[base];
  for (int g = 0; g < RCH; g += 4) {
    int e = base + g;
    int4 sg = *reinterpret_cast<const int4*>(rseg + e);
    int4 rr = *reinterpret_cast<const int4*>(rte + e);
    if (sg.w == prev) {            // sorted => whole group in same segment (uniform branch)
      if (act) {
        a0 += u2f(hb[(size_t)rr.x * KP + d]);
        a1 += u2f(hb[(size_t)rr.y * KP + d]);
        a2 += u2f(hb[(size_t)rr.z * KP + d]);
        a3 += u2f(hb[(size_t)rr.w * KP + d]);
      }
    } else {                       // boundary group (rare): scalar path
      int ss[4] = {sg.x, sg.y, sg.z, sg.w};
      int rr2[4] = {rr.x, rr.y, rr.z, rr.w};
      #pragma unroll
      for (int j = 0; j < 4; j++) {
        if (ss[j] != prev) {
          if (act) atomicAdd(&sums[prev * H + d], a0 + a1 + a2 + a3);
          a0 = a1 = a2 = a3 = 0.f;
          prev = ss[j];
        }
        if (act) a0 += u2f(hb[(size_t)rr2[j] * KP + d]);
      }
    }
  }
  if (act) atomicAdd(&sums[prev * H + d], a0 + a1 + a2 + a3);
}

// ---------------- per-step: GRU on relations (thread-per-output-column GEMM) ----------------
__global__ __launch_bounds__(512) void k_gru2(const float* __restrict__ er,
                                              const float* __restrict__ sums,
                                              const int* __restrict__ segstart,
                                              const float* __restrict__ WihT,
                                              const float* __restrict__ WhhT,
                                              const float* __restrict__ b_ih,
                                              const float* __restrict__ b_hh,
                                              float* __restrict__ h0,
                                              float* __restrict__ h0_out) {
  __shared__ float xc[2 * H];      // x_cat row: [emb_rel | seg-mean]
  __shared__ float h0r[H];
  __shared__ float gi[3 * H], gh[3 * H];
  __shared__ float red[8];
  int r = blockIdx.x;
  int tid = threadIdx.x, wid = tid >> 6, lane = tid & 63;
  int cnt = segstart[r + 1] - segstart[r];
  float inv = cnt > 0 ? 1.0f / (float)cnt : 0.0f;
  if (tid < 2 * H)
    xc[tid] = (tid < H) ? er[r * H + tid] : sums[r * H + (tid - H)] * inv;
  if (tid < H) h0r[tid] = h0[r * H + tid];
  __syncthreads();

  for (int j = tid; j < 3 * H; j += 512) {
    float a = 0.f;
    #pragma unroll 4
    for (int k = 0; k < 2 * H; k++) a += xc[k] * WihT[k * (3 * H) + j];
    float b = 0.f;
    #pragma unroll 4
    for (int k = 0; k < H; k++) b += h0r[k] * WhhT[k * (3 * H) + j];
    gi[j] = a + b_ih[j];
    gh[j] = b + b_hh[j];
  }
  __syncthreads();

  float ssp = 0.f;
  for (int d = tid; d < H; d += 512) {
    float rg = sigmoidf(gi[d] + gh[d]);
    float z  = sigmoidf(gi[H + d] + gh[H + d]);
    float n  = tanhf(gi[2 * H + d] + rg * gh[2 * H + d]);
    float o  = (1.0f - z) * n + z * h0r[d];
    xc[d] = o;                       // reuse xc for output row
    ssp += o * o;
  }
  ssp = wave_sum(ssp);
  if (lane == 0) red[wid] = ssp;
  __syncthreads();
  float ss = 0.f;
  #pragma unroll
  for (int q = 0; q < 8; q++) ss += red[q];
  float sc = 1.0f / fmaxf(sqrtf(ss), 1e-12f);
  for (int d = tid; d < H; d += 512) {
    float o = xc[d] * sc;
    h0[r * H + d] = o;
    if (h0_out) h0_out[r * H + d] = o;
  }
}

// ---------------- per-step: MFMA node GEMMs (hW = h@Wn, tw = sigmoid(h@Tg+b)) ----------------
// nt-outer structure: A hoisted to regs (reused across all nt); per nt the 14
// independent B-frag loads are issued as a batch, then a 14-MFMA chain into 2
// live accumulators. 13 latency exposures per wave instead of 182.
__global__ __launch_bounds__(256) void k_mfma_gemm(const unsigned short* __restrict__ hb,
                                                   const unsigned short* __restrict__ bpack,
                                                   const float* __restrict__ tgb,
                                                   bf16* __restrict__ hWb,
                                                   bf16* __restrict__ twb) {
  int wid = threadIdx.x >> 6, lane = threadIdx.x & 63;
  int row0 = blockIdx.x * 64 + wid * 16;
  if (row0 >= NE) return;                 // wave-uniform
  int arow = min(row0 + (lane & 15), NE - 1);
  const unsigned short* ap = hb + (size_t)arow * KP + (lane >> 4) * 8;
  bf16x8v a[KS];
  #pragma unroll
  for (int ks = 0; ks < KS; ks++)
    a[ks] = *reinterpret_cast<const bf16x8v*>(ap + ks * 32);

  const unsigned short* b1p = bpack + (size_t)lane * 8;
  const unsigned short* b2p = b1p + (size_t)NT * KS * 64 * 8;
  int colb = lane & 15;
  int rbase = row0 + (lane >> 4) * 4;

  for (int nt = 0; nt < NT; nt++) {
    bf16x8v b1[KS], b2[KS];
    #pragma unroll
    for (int ks = 0; ks < KS; ks++) {
      size_t boff = (size_t)(nt * KS + ks) * 64 * 8;
      b1[ks] = *reinterpret_cast<const bf16x8v*>(b1p + boff);
      b2[ks] = *reinterpret_cast<const bf16x8v*>(b2p + boff);
    }
    f32x4 acc1 = {}, acc2 = {};
    #pragma unroll
    for (int ks = 0; ks < KS; ks++) {
      acc1 = __builtin_amdgcn_mfma_f32_16x16x32_bf16(a[ks], b1[ks], acc1, 0, 0, 0);
      acc2 = __builtin_amdgcn_mfma_f32_16x16x32_bf16(a[ks], b2[ks], acc2, 0, 0, 0);
    }
    int col = nt * 16 + colb;
    bool cok = (col < H);
    float bias = cok ? tgb[col] : 0.f;
    #pragma unroll
    for (int q = 0; q < 4; q++) {
      int row = rbase + q;
      if (cok && row < NE) {
        hWb[(size_t)row * H + col] = f2b(acc1[q]);
        twb[(size_t)row * H + col] = f2b(sigmoidf(acc2[q] + bias));
      }
    }
  }
}

// ---------------- per-step: CSR build by dst ----------------
__global__ void k_hist(const int* dst, int* deg) {
  int e = blockIdx.x * 256 + threadIdx.x;
  if (e < EC) atomicAdd(&deg[dst[e]], 1);
}

__global__ __launch_bounds__(256) void k_scan1(const int* deg, int* offs, int* bsums) {
  __shared__ int s[256];
  int i = blockIdx.x * 256 + threadIdx.x;
  int v = (i < NE) ? deg[i] : 0;
  s[threadIdx.x] = v;
  __syncthreads();
  for (int o = 1; o < 256; o <<= 1) {
    int add = (threadIdx.x >= o) ? s[threadIdx.x - o] : 0;
    __syncthreads();
    s[threadIdx.x] += add;
    __syncthreads();
  }
  if (i < NE) offs[i] = s[threadIdx.x] - v;  // exclusive
  if (threadIdx.x == 255) bsums[blockIdx.x] = s[255];
}

__global__ __launch_bounds__(256) void k_scan2(int* bsums) {
  __shared__ int s[256];
  int v = (threadIdx.x < NSCAN) ? bsums[threadIdx.x] : 0;
  s[threadIdx.x] = v;
  __syncthreads();
  for (int o = 1; o < 256; o <<= 1) {
    int add = (threadIdx.x >= o) ? s[threadIdx.x - o] : 0;
    __syncthreads();
    s[threadIdx.x] += add;
    __syncthreads();
  }
  if (threadIdx.x < NSCAN) bsums[threadIdx.x] = s[threadIdx.x] - v;  // exclusive
}

__global__ void k_scan3(int* offs, const int* bsums, int* cursor) {
  int i = blockIdx.x * 256 + threadIdx.x;
  if (i < NE) {
    int o = offs[i] + bsums[blockIdx.x];
    offs[i] = o;
    cursor[i] = o;
  }
  if (blockIdx.x == 0 && threadIdx.x == 0) offs[NE] = EC;
}

__global__ void k_scatter(const int* dst, int* cursor, int* eids) {
  int e = blockIdx.x * 256 + threadIdx.x;
  if (e < EC) {
    int pos = atomicAdd(&cursor[dst[e]], 1);
    eids[pos] = e;
  }
}

// ---------------- per-step: aggregate + rrelu + l2norm -> cur (stored in evolve[t] slot) ----------------
__global__ __launch_bounds__(256) void k_aggcur(const int* __restrict__ offs,
                                                const int* __restrict__ eids,
                                                const int* __restrict__ src,
                                                const int* __restrict__ et,
                                                const bf16* __restrict__ hWb,
                                                const float* __restrict__ relW,
                                                float* __restrict__ cur) {
  int wid = threadIdx.x >> 6, lane = threadIdx.x & 63;
  int i = blockIdx.x * 4 + wid;
  if (i >= NE) return;
  int s0 = offs[i], s1 = offs[i + 1];
  float acc[4] = {0.f, 0.f, 0.f, 0.f};
  for (int p = s0; p < s1; p++) {
    int e = eids[p];
    int s = src[e];
    int r = et[e];
    #pragma unroll
    for (int q = 0; q < 4; q++) {
      int d = lane + q * 64;
      if (d < H) acc[q] += b2f(hWb[(size_t)s * H + d]) + relW[r * H + d];
    }
  }
  int deg = s1 - s0;
  float nrm = deg > 0 ? 1.0f / (float)deg : 0.0f;
  float ss = 0.f;
  #pragma unroll
  for (int q = 0; q < 4; q++) {
    float v = acc[q] * nrm;
    v = v >= 0.f ? v : SLOPE * v;
    acc[q] = v;
    ss += v * v;
  }
  ss = wave_sum(ss);
  float sc = 1.0f / fmaxf(sqrtf(ss), 1e-12f);
  #pragma unroll
  for (int q = 0; q < 4; q++) {
    int d = lane + q * 64;
    if (d < H) cur[(size_t)i * H + d] = acc[q] * sc;
  }
}

// ---------------- per-step: time gate + combine + l2norm -> h, evolve (in-place over cur) ----------------
__global__ __launch_bounds__(256) void k_final(const bf16* __restrict__ twb,
                                               float* __restrict__ h,
                                               float* __restrict__ evolve) {
  int wid = threadIdx.x >> 6, lane = threadIdx.x & 63;
  int i = blockIdx.x * 4 + wid;
  if (i >= NE) return;
  float v[4]; float ss = 0.f;
  #pragma unroll
  for (int q = 0; q < 4; q++) {
    int d = lane + q * 64;
    if (d < H) {
      float cur = evolve[(size_t)i * H + d];
      float tw  = b2f(twb[(size_t)i * H + d]);
      float hv  = h[(size_t)i * H + d];
      float val = tw * cur + (1.0f - tw) * hv;
      v[q] = val; ss += val * val;
    } else v[q] = 0.f;
  }
  ss = wave_sum(ss);
  float sc = 1.0f / fmaxf(sqrtf(ss), 1e-12f);
  #pragma unroll
  for (int q = 0; q < 4; q++) {
    int d = lane + q * 64;
    if (d < H) {
      float o = v[q] * sc;
      h[(size_t)i * H + d] = o;
      evolve[(size_t)i * H + d] = o;
    }
  }
}

extern "C" void kernel_launch(void* const* d_in, const int* in_sizes, int n_in,
                              void* d_out, int out_size, void* d_ws, size_t ws_size,
                              hipStream_t stream) {
  const float* de  = (const float*)d_in[0];
  const float* er  = (const float*)d_in[1];
  const float* wih = (const float*)d_in[2];
  const float* whh = (const float*)d_in[3];
  const float* bih = (const float*)d_in[4];
  const float* bhh = (const float*)d_in[5];
  const float* wn  = (const float*)d_in[6];
  const float* tg  = (const float*)d_in[7];
  const float* tgb = (const float*)d_in[8];
  const int* src  = (const int*)d_in[9];
  const int* dst  = (const int*)d_in[10];
  const int* et   = (const int*)d_in[11];
  const int* rte  = (const int*)d_in[12];
  const int* rseg = (const int*)d_in[13];

  char* w = (char*)d_ws;
  auto alloc = [&](size_t bytes) -> char* {
    char* p = w;
    w += (bytes + 255) / 256 * 256;
    return p;
  };
  float* h     = (float*)alloc(sizeof(float) * (size_t)NE * H);   // 40 MB
  bf16*  hWb   = (bf16*) alloc(sizeof(bf16)  * (size_t)NE * H);   // 20 MB
  bf16*  twb   = (bf16*) alloc(sizeof(bf16)  * (size_t)NE * H);   // 20 MB
  float* relW  = (float*)alloc(sizeof(float) * R2C * H);
  float* h0    = (float*)alloc(sizeof(float) * R2C * H);
  float* sums  = (float*)alloc(sizeof(float) * R2C * H);
  float* WihT  = (float*)alloc(sizeof(float) * 2 * H * 3 * H);    // 960 KB
  float* WhhT  = (float*)alloc(sizeof(float) * H * 3 * H);        // 480 KB
  unsigned short* bpack = (unsigned short*)alloc(sizeof(unsigned short) * 2 * NT * KS * 64 * 8); // 186 KB
  int* segstart= (int*)  alloc(sizeof(int) * (R2C + 1));
  int* deg     = (int*)  alloc(sizeof(int) * NE);
  int* offs    = (int*)  alloc(sizeof(int) * (NE + 1));
  int* cursor  = (int*)  alloc(sizeof(int) * NE);
  int* eids    = (int*)  alloc(sizeof(int) * EC);
  int* bsums   = (int*)  alloc(sizeof(int) * 256);
  (void)ws_size; (void)in_sizes; (void)n_in; (void)out_size;

  float* out    = (float*)d_out;
  float* evolve = out;                       // [TS, NE, H]
  float* h0out  = out + (size_t)TS * NE * H; // [R2C, H]

  const int gRow4  = (NE + 3) / 4;          // 12500
  const int gE     = (EC + 255) / 256;      // 1563
  const int gRel   = (R2C * H + 255) / 256; // 391
  const int gTr    = (2 * H * 3 * H + 255) / 256; // 938
  const int gPack  = (2 * NT * KS * 64 + 255) / 256;     // 46
  const int gH2b   = (NE * KP / 4 + 255) / 256;          // 10938
  const int gGemm  = (NE + 63) / 64;                     // 782
  const int gRelsum= EC / RCH;                           // 3125

  k_init_h<<<gRow4, 256, 0, stream>>>(de, h);
  k_init_h0<<<gRel, 256, 0, stream>>>(er, h0);
  k_relw<<<R2C, 256, 0, stream>>>(er, wn, relW);
  k_wtrans<<<gTr, 256, 0, stream>>>(wih, whh, WihT, WhhT);
  k_packb<<<gPack, 256, 0, stream>>>(wn, tg, bpack);

  for (int t = 0; t < TS; t++) {
    const int* src_t  = src  + (size_t)t * EC;
    const int* dst_t  = dst  + (size_t)t * EC;
    const int* et_t   = et   + (size_t)t * EC;
    const int* rte_t  = rte  + (size_t)t * EC;
    const int* rseg_t = rseg + (size_t)t * EC;
    float* evo_t = evolve + (size_t)t * NE * H;
    // bf16 A matrix (and relsums gather source) aliases the evolve[t] slot
    // (22.4 MB < 40 MB); dead before k_aggcur overwrites the slot.
    unsigned short* hb = (unsigned short*)evo_t;

    // bf16 copy of pre-step h first: feeds both relsums gather and MFMA GEMM
    k_h2b<<<gH2b, 256, 0, stream>>>(h, hb);

    // relation-segment means + GRU (uses pre-step h, h0)
    k_segbounds<<<1, 512, 0, stream>>>(rseg_t, segstart);
    k_zero_f<<<gRel, 256, 0, stream>>>(sums, R2C * H);
    k_relsums<<<gRelsum, 256, 0, stream>>>(rseg_t, rte_t, hb, sums);
    k_gru2<<<R2C, 512, 0, stream>>>(er, sums, segstart, WihT, WhhT, bih, bhh,
                                    h0, (t == TS - 1) ? h0out : (float*)nullptr);

    // node GEMMs via MFMA (pre-step h)
    k_mfma_gemm<<<gGemm, 256, 0, stream>>>(hb, bpack, tgb, hWb, twb);

    // CSR build by dst
    k_zero_i<<<NSCAN, 256, 0, stream>>>(deg, NE);
    k_hist<<<gE, 256, 0, stream>>>(dst_t, deg);
    k_scan1<<<NSCAN, 256, 0, stream>>>(deg, offs, bsums);
    k_scan2<<<1, 256, 0, stream>>>(bsums);
    k_scan3<<<NSCAN, 256, 0, stream>>>(offs, bsums, cursor);
    k_scatter<<<gE, 256, 0, stream>>>(dst_t, cursor, eids);

    // aggregate + rrelu + l2norm -> cur (stored in evolve[t] slot of d_out)
    k_aggcur<<<gRow4, 256, 0, stream>>>(offs, eids, src_t, et_t, hWb, relW, evo_t);

    // time gate + combine + l2norm; updates h in place, rewrites evolve[t] with h_new
    k_final<<<gRow4, 256, 0, stream>>>(twb, h, evo_t);
  }
}

// Round 7
// 1208.800 us; speedup vs baseline: 4.0497x; 1.2851x over previous
//
#include <hip/hip_runtime.h>
#include <hip/hip_bf16.h>

using bf16 = __hip_bfloat16;

constexpr int NE  = 50000;   // entities
constexpr int H   = 200;     // hidden dim
constexpr int R2C = 500;     // 2*num_rels
constexpr int TS  = 4;       // timesteps
constexpr int EC  = 400000;  // edges per step
constexpr float SLOPE = 0.22916666666666666f;  // rrelu eval slope
constexpr int NSCAN = (NE + 255) / 256;        // 196

// node-GEMM MFMA geometry
constexpr int KP = 224;      // K padded to 7*32
constexpr int KS = 7;        // k-steps of 32
constexpr int NT = 13;       // n-tiles of 16

// GRU-GEMM MFMA geometry (out [512][608])
constexpr int GNT = 38;      // n-tiles (608/16)
constexpr int GKI = 13;      // k-steps for W_ih (416/32)
constexpr int GKH = 7;       // k-steps for W_hh (224/32)
constexpr int GR  = 512;     // padded relation rows
constexpr int GCS = 608;     // padded gate cols (stride)

constexpr int RCH = 128;     // edges per block in k_relsums

#define DEVINL __device__ __forceinline__

typedef __bf16 bf16x8v __attribute__((ext_vector_type(8)));
typedef float  f32x4   __attribute__((ext_vector_type(4)));

DEVINL float b2f(bf16 v) { return __bfloat162float(v); }
DEVINL bf16  f2b(float v) { return __float2bfloat16(v); }
DEVINL unsigned short f2bu(float x) { bf16 b = f2b(x); return *reinterpret_cast<unsigned short*>(&b); }
DEVINL float u2f(unsigned short u) { unsigned int w = (unsigned int)u << 16; float f; __builtin_memcpy(&f, &w, 4); return f; }

DEVINL float wave_sum(float v) {
  #pragma unroll
  for (int o = 32; o > 0; o >>= 1) v += __shfl_xor(v, o, 64);
  return v;
}

DEVINL float sigmoidf(float x) { return 1.0f / (1.0f + expf(-x)); }

// ---------------- init ----------------
__global__ __launch_bounds__(256) void k_init_h(const float* de, float* h) {
  int wid = threadIdx.x >> 6, lane = threadIdx.x & 63;
  int row = blockIdx.x * 4 + wid;
  if (row >= NE) return;
  float v[4]; float ss = 0.f;
  #pragma unroll
  for (int q = 0; q < 4; q++) {
    int d = lane + q * 64;
    v[q] = (d < H) ? de[(size_t)row * H + d] : 0.f;
    ss += v[q] * v[q];
  }
  ss = wave_sum(ss);
  float sc = 1.0f / fmaxf(sqrtf(ss), 1e-12f);
  #pragma unroll
  for (int q = 0; q < 4; q++) {
    int d = lane + q * 64;
    if (d < H) h[(size_t)row * H + d] = v[q] * sc;
  }
}

__global__ __launch_bounds__(256) void k_init_h0(const float* er, float* h0) {
  int i = blockIdx.x * 256 + threadIdx.x;
  if (i < R2C * H) h0[i] = er[i];
}

// relW = emb_rel @ W_n   [R2C, H]
__global__ __launch_bounds__(256) void k_relw(const float* er, const float* wn, float* relW) {
  __shared__ float a[H];
  int r = blockIdx.x;
  for (int d = threadIdx.x; d < H; d += 256) a[d] = er[r * H + d];
  __syncthreads();
  for (int c = threadIdx.x; c < H; c += 256) {
    float s = 0.f;
    for (int k = 0; k < H; k++) s += a[k] * wn[k * H + c];
    relW[r * H + c] = s;
  }
}

// pack Wn and Tg into per-lane MFMA B-fragment order, zero-padded to [KP][NP].
__global__ __launch_bounds__(256) void k_packb(const float* wn, const float* tg,
                                               unsigned short* bpack) {
  int t = blockIdx.x * 256 + threadIdx.x;
  int total = 2 * NT * KS * 64;
  if (t >= total) return;
  int m    = t / (NT * KS * 64);
  int rem  = t % (NT * KS * 64);
  int nt   = rem / (KS * 64);
  int rem2 = rem % (KS * 64);
  int ks   = rem2 / 64, lane = rem2 % 64;
  const float* W = m ? tg : wn;
  int n = nt * 16 + (lane & 15);
  unsigned short out[8];
  #pragma unroll
  for (int j = 0; j < 8; j++) {
    int k = ks * 32 + (lane >> 4) * 8 + j;
    float v = (k < H && n < H) ? W[k * H + n] : 0.f;
    out[j] = f2bu(v);
  }
  unsigned short* dst = bpack + (size_t)t * 8;
  #pragma unroll
  for (int j = 0; j < 8; j++) dst[j] = out[j];
}

// pack W_ih [600,400] and W_hh [600,200] (row-major [n][k]) into B-frag order
// for out = A @ W^T: B[k][n] = W[n][k]. Padded to K=416/224, N=608.
__global__ __launch_bounds__(256) void k_packgru(const float* __restrict__ wih,
                                                 const float* __restrict__ whh,
                                                 unsigned short* __restrict__ bgi,
                                                 unsigned short* __restrict__ bgh) {
  int t = blockIdx.x * 256 + threadIdx.x;
  const int tot_i = GNT * GKI * 64;
  const int tot_h = GNT * GKH * 64;
  if (t < tot_i) {
    int nt = t / (GKI * 64);
    int rem = t % (GKI * 64);
    int ks = rem / 64, lane = rem % 64;
    int n = nt * 16 + (lane & 15);
    unsigned short o[8];
    #pragma unroll
    for (int j = 0; j < 8; j++) {
      int k = ks * 32 + (lane >> 4) * 8 + j;
      o[j] = (n < 3 * H && k < 2 * H) ? f2bu(wih[n * (2 * H) + k]) : (unsigned short)0;
    }
    unsigned short* dstp = bgi + (size_t)t * 8;
    #pragma unroll
    for (int j = 0; j < 8; j++) dstp[j] = o[j];
  } else if (t < tot_i + tot_h) {
    int t2 = t - tot_i;
    int nt = t2 / (GKH * 64);
    int rem = t2 % (GKH * 64);
    int ks = rem / 64, lane = rem % 64;
    int n = nt * 16 + (lane & 15);
    unsigned short o[8];
    #pragma unroll
    for (int j = 0; j < 8; j++) {
      int k = ks * 32 + (lane >> 4) * 8 + j;
      o[j] = (n < 3 * H && k < H) ? f2bu(whh[n * H + k]) : (unsigned short)0;
    }
    unsigned short* dstp = bgh + (size_t)t2 * 8;
    #pragma unroll
    for (int j = 0; j < 8; j++) dstp[j] = o[j];
  }
}

// convert h (f32 [NE][H]) -> hb (bf16 [NE][KP], zero-padded cols 200..223)
__global__ __launch_bounds__(256) void k_h2b(const float* __restrict__ h,
                                             unsigned short* __restrict__ hb) {
  int i = (blockIdx.x * 256 + threadIdx.x) * 4;
  if (i >= NE * KP) return;
  int row = i / KP, col = i % KP;   // col % 4 == 0
  ushort4 o;
  if (col < H) {
    const float4 v = *reinterpret_cast<const float4*>(h + (size_t)row * H + col);
    o.x = f2bu(v.x); o.y = f2bu(v.y); o.z = f2bu(v.z); o.w = f2bu(v.w);
  } else {
    o.x = o.y = o.z = o.w = 0;
  }
  *reinterpret_cast<ushort4*>(hb + i) = o;
}

// build GRU A-matrices: xcatb [512][416] = [emb_rel | seg-mean], h0b [512][224]
__global__ __launch_bounds__(256) void k_a2b(const float* __restrict__ er,
                                             const float* __restrict__ sums,
                                             const int* __restrict__ segstart,
                                             const float* __restrict__ h0,
                                             unsigned short* __restrict__ xcatb,
                                             unsigned short* __restrict__ h0b) {
  int i = blockIdx.x * 256 + threadIdx.x;
  const int n1 = GR * 416;
  if (i < n1) {
    int r = i / 416, c = i % 416;
    float v = 0.f;
    if (r < R2C) {
      if (c < H) v = er[r * H + c];
      else if (c < 2 * H) {
        int cnt = segstart[r + 1] - segstart[r];
        float inv = cnt > 0 ? 1.0f / (float)cnt : 0.0f;
        v = sums[r * H + (c - H)] * inv;
      }
    }
    xcatb[i] = f2bu(v);
  } else {
    int i2 = i - n1;
    if (i2 < GR * 224) {
      int r = i2 / 224, c = i2 % 224;
      float v = (r < R2C && c < H) ? h0[r * H + c] : 0.f;
      h0b[i2] = f2bu(v);
    }
  }
}

// ---------------- generic zero ----------------
__global__ void k_zero_f(float* p, int n) {
  int i = blockIdx.x * 256 + threadIdx.x;
  if (i < n) p[i] = 0.f;
}
__global__ void k_zero_i(int* p, int n) {
  int i = blockIdx.x * 256 + threadIdx.x;
  if (i < n) p[i] = 0;
}

// ---------------- per-step: relation segment bounds (sorted rseg) ----------------
__global__ __launch_bounds__(512) void k_segbounds(const int* rseg, int* segstart) {
  for (int r = threadIdx.x; r <= R2C; r += 512) {
    int lo = 0, hi = EC;
    while (lo < hi) { int m = (lo + hi) >> 1; if (rseg[m] < r) lo = m + 1; else hi = m; }
    segstart[r] = lo;
  }
}

// segment-sum over sorted rseg, gathering bf16 rows of hb.
__global__ __launch_bounds__(256) void k_relsums(const int* __restrict__ rseg,
                                                 const int* __restrict__ rte,
                                                 const unsigned short* __restrict__ hb,
                                                 float* __restrict__ sums) {
  int base = blockIdx.x * RCH;
  int d = threadIdx.x;
  bool act = d < H;
  float a0 = 0.f, a1 = 0.f, a2 = 0.f, a3 = 0.f;
  int prev = rseg[base];
  for (int g = 0; g < RCH; g += 4) {
    int e = base + g;
    int4 sg = *reinterpret_cast<const int4*>(rseg + e);
    int4 rr = *reinterpret_cast<const int4*>(rte + e);
    if (sg.w == prev) {            // sorted => whole group in same segment (uniform branch)
      if (act) {
        a0 += u2f(hb[(size_t)rr.x * KP + d]);
        a1 += u2f(hb[(size_t)rr.y * KP + d]);
        a2 += u2f(hb[(size_t)rr.z * KP + d]);
        a3 += u2f(hb[(size_t)rr.w * KP + d]);
      }
    } else {                       // boundary group (rare): scalar path
      int ss[4] = {sg.x, sg.y, sg.z, sg.w};
      int rr2[4] = {rr.x, rr.y, rr.z, rr.w};
      #pragma unroll
      for (int j = 0; j < 4; j++) {
        if (ss[j] != prev) {
          if (act) atomicAdd(&sums[prev * H + d], a0 + a1 + a2 + a3);
          a0 = a1 = a2 = a3 = 0.f;
          prev = ss[j];
        }
        if (act) a0 += u2f(hb[(size_t)rr2[j] * KP + d]);
      }
    }
  }
  if (act) atomicAdd(&sums[prev * H + d], a0 + a1 + a2 + a3);
}

// ---------------- per-step: GRU GEMMs via MFMA -> gi, gh [512][608] f32 ----------------
__global__ __launch_bounds__(256) void k_grumm(const unsigned short* __restrict__ xcatb,
                                               const unsigned short* __restrict__ h0b,
                                               const unsigned short* __restrict__ bgi,
                                               const unsigned short* __restrict__ bgh,
                                               float* __restrict__ gi_ws,
                                               float* __restrict__ gh_ws) {
  int wid = threadIdx.x >> 6, lane = threadIdx.x & 63;
  int nt   = blockIdx.x % GNT;
  int row0 = (blockIdx.x / GNT) * 64 + wid * 16;
  int arow = row0 + (lane & 15);

  const unsigned short* api = xcatb + (size_t)arow * 416 + (lane >> 4) * 8;
  bf16x8v ai[GKI];
  #pragma unroll
  for (int ks = 0; ks < GKI; ks++)
    ai[ks] = *reinterpret_cast<const bf16x8v*>(api + ks * 32);
  const unsigned short* aph = h0b + (size_t)arow * 224 + (lane >> 4) * 8;
  bf16x8v ah[GKH];
  #pragma unroll
  for (int ks = 0; ks < GKH; ks++)
    ah[ks] = *reinterpret_cast<const bf16x8v*>(aph + ks * 32);

  const unsigned short* bip = bgi + ((size_t)(nt * GKI) * 64 + lane) * 8;
  bf16x8v bi[GKI];
  #pragma unroll
  for (int ks = 0; ks < GKI; ks++)
    bi[ks] = *reinterpret_cast<const bf16x8v*>(bip + (size_t)ks * 64 * 8);
  const unsigned short* bhp = bgh + ((size_t)(nt * GKH) * 64 + lane) * 8;
  bf16x8v bh[GKH];
  #pragma unroll
  for (int ks = 0; ks < GKH; ks++)
    bh[ks] = *reinterpret_cast<const bf16x8v*>(bhp + (size_t)ks * 64 * 8);

  f32x4 a1 = {}, a2 = {};
  #pragma unroll
  for (int ks = 0; ks < GKI; ks++)
    a1 = __builtin_amdgcn_mfma_f32_16x16x32_bf16(ai[ks], bi[ks], a1, 0, 0, 0);
  #pragma unroll
  for (int ks = 0; ks < GKH; ks++)
    a2 = __builtin_amdgcn_mfma_f32_16x16x32_bf16(ah[ks], bh[ks], a2, 0, 0, 0);

  int col = nt * 16 + (lane & 15);
  int rb = row0 + (lane >> 4) * 4;
  #pragma unroll
  for (int q = 0; q < 4; q++) {
    gi_ws[(size_t)(rb + q) * GCS + col] = a1[q];
    gh_ws[(size_t)(rb + q) * GCS + col] = a2[q];
  }
}

// ---------------- per-step: GRU gates + l2norm -> h0 (and h0_out on last step) ----------------
__global__ __launch_bounds__(256) void k_grutail(const float* __restrict__ gi_ws,
                                                 const float* __restrict__ gh_ws,
                                                 const float* __restrict__ b_ih,
                                                 const float* __restrict__ b_hh,
                                                 float* __restrict__ h0,
                                                 float* __restrict__ h0_out) {
  __shared__ float xc[H];
  __shared__ float red[4];
  int r = blockIdx.x;
  int tid = threadIdx.x, wid = tid >> 6, lane = tid & 63;
  float ssp = 0.f;
  for (int d = tid; d < H; d += 256) {
    float gir = gi_ws[(size_t)r * GCS + d]         + b_ih[d];
    float ghr = gh_ws[(size_t)r * GCS + d]         + b_hh[d];
    float giz = gi_ws[(size_t)r * GCS + H + d]     + b_ih[H + d];
    float ghz = gh_ws[(size_t)r * GCS + H + d]     + b_hh[H + d];
    float gin = gi_ws[(size_t)r * GCS + 2 * H + d] + b_ih[2 * H + d];
    float ghn = gh_ws[(size_t)r * GCS + 2 * H + d] + b_hh[2 * H + d];
    float rg = sigmoidf(gir + ghr);
    float z  = sigmoidf(giz + ghz);
    float n  = tanhf(gin + rg * ghn);
    float hv = h0[r * H + d];
    float o  = (1.0f - z) * n + z * hv;
    xc[d] = o;
    ssp += o * o;
  }
  ssp = wave_sum(ssp);
  if (lane == 0) red[wid] = ssp;
  __syncthreads();
  float ss = red[0] + red[1] + red[2] + red[3];
  float sc = 1.0f / fmaxf(sqrtf(ss), 1e-12f);
  for (int d = tid; d < H; d += 256) {
    float o = xc[d] * sc;
    h0[r * H + d] = o;
    if (h0_out) h0_out[r * H + d] = o;
  }
}

// ---------------- per-step: MFMA node GEMMs (hW = h@Wn, tw = sigmoid(h@Tg+b)) ----------------
__global__ __launch_bounds__(256) void k_mfma_gemm(const unsigned short* __restrict__ hb,
                                                   const unsigned short* __restrict__ bpack,
                                                   const float* __restrict__ tgb,
                                                   bf16* __restrict__ hWb,
                                                   bf16* __restrict__ twb) {
  int wid = threadIdx.x >> 6, lane = threadIdx.x & 63;
  int row0 = blockIdx.x * 64 + wid * 16;
  if (row0 >= NE) return;                 // wave-uniform
  int arow = min(row0 + (lane & 15), NE - 1);
  const unsigned short* ap = hb + (size_t)arow * KP + (lane >> 4) * 8;
  bf16x8v a[KS];
  #pragma unroll
  for (int ks = 0; ks < KS; ks++)
    a[ks] = *reinterpret_cast<const bf16x8v*>(ap + ks * 32);

  const unsigned short* b1p = bpack + (size_t)lane * 8;
  const unsigned short* b2p = b1p + (size_t)NT * KS * 64 * 8;
  int colb = lane & 15;
  int rbase = row0 + (lane >> 4) * 4;

  for (int nt = 0; nt < NT; nt++) {
    bf16x8v b1[KS], b2[KS];
    #pragma unroll
    for (int ks = 0; ks < KS; ks++) {
      size_t boff = (size_t)(nt * KS + ks) * 64 * 8;
      b1[ks] = *reinterpret_cast<const bf16x8v*>(b1p + boff);
      b2[ks] = *reinterpret_cast<const bf16x8v*>(b2p + boff);
    }
    f32x4 acc1 = {}, acc2 = {};
    #pragma unroll
    for (int ks = 0; ks < KS; ks++) {
      acc1 = __builtin_amdgcn_mfma_f32_16x16x32_bf16(a[ks], b1[ks], acc1, 0, 0, 0);
      acc2 = __builtin_amdgcn_mfma_f32_16x16x32_bf16(a[ks], b2[ks], acc2, 0, 0, 0);
    }
    int col = nt * 16 + colb;
    bool cok = (col < H);
    float bias = cok ? tgb[col] : 0.f;
    #pragma unroll
    for (int q = 0; q < 4; q++) {
      int row = rbase + q;
      if (cok && row < NE) {
        hWb[(size_t)row * H + col] = f2b(acc1[q]);
        twb[(size_t)row * H + col] = f2b(sigmoidf(acc2[q] + bias));
      }
    }
  }
}

// ---------------- per-step: CSR build by dst ----------------
__global__ void k_hist(const int* dst, int* deg) {
  int e = blockIdx.x * 256 + threadIdx.x;
  if (e < EC) atomicAdd(&deg[dst[e]], 1);
}

__global__ __launch_bounds__(256) void k_scan1(const int* deg, int* offs, int* bsums) {
  __shared__ int s[256];
  int i = blockIdx.x * 256 + threadIdx.x;
  int v = (i < NE) ? deg[i] : 0;
  s[threadIdx.x] = v;
  __syncthreads();
  for (int o = 1; o < 256; o <<= 1) {
    int add = (threadIdx.x >= o) ? s[threadIdx.x - o] : 0;
    __syncthreads();
    s[threadIdx.x] += add;
    __syncthreads();
  }
  if (i < NE) offs[i] = s[threadIdx.x] - v;  // exclusive
  if (threadIdx.x == 255) bsums[blockIdx.x] = s[255];
}

__global__ __launch_bounds__(256) void k_scan2(int* bsums) {
  __shared__ int s[256];
  int v = (threadIdx.x < NSCAN) ? bsums[threadIdx.x] : 0;
  s[threadIdx.x] = v;
  __syncthreads();
  for (int o = 1; o < 256; o <<= 1) {
    int add = (threadIdx.x >= o) ? s[threadIdx.x - o] : 0;
    __syncthreads();
    s[threadIdx.x] += add;
    __syncthreads();
  }
  if (threadIdx.x < NSCAN) bsums[threadIdx.x] = s[threadIdx.x] - v;  // exclusive
}

__global__ void k_scan3(int* offs, const int* bsums, int* cursor) {
  int i = blockIdx.x * 256 + threadIdx.x;
  if (i < NE) {
    int o = offs[i] + bsums[blockIdx.x];
    offs[i] = o;
    cursor[i] = o;
  }
  if (blockIdx.x == 0 && threadIdx.x == 0) offs[NE] = EC;
}

__global__ void k_scatter(const int* dst, int* cursor, int* eids) {
  int e = blockIdx.x * 256 + threadIdx.x;
  if (e < EC) {
    int pos = atomicAdd(&cursor[dst[e]], 1);
    eids[pos] = e;
  }
}

// ---------------- per-step: aggregate + rrelu + l2norm -> cur (stored in evolve[t] slot) ----------------
__global__ __launch_bounds__(256) void k_aggcur(const int* __restrict__ offs,
                                                const int* __restrict__ eids,
                                                const int* __restrict__ src,
                                                const int* __restrict__ et,
                                                const bf16* __restrict__ hWb,
                                                const float* __restrict__ relW,
                                                float* __restrict__ cur) {
  int wid = threadIdx.x >> 6, lane = threadIdx.x & 63;
  int i = blockIdx.x * 4 + wid;
  if (i >= NE) return;
  int s0 = offs[i], s1 = offs[i + 1];
  float acc[4] = {0.f, 0.f, 0.f, 0.f};
  for (int p = s0; p < s1; p++) {
    int e = eids[p];
    int s = src[e];
    int r = et[e];
    #pragma unroll
    for (int q = 0; q < 4; q++) {
      int d = lane + q * 64;
      if (d < H) acc[q] += b2f(hWb[(size_t)s * H + d]) + relW[r * H + d];
    }
  }
  int deg = s1 - s0;
  float nrm = deg > 0 ? 1.0f / (float)deg : 0.0f;
  float ss = 0.f;
  #pragma unroll
  for (int q = 0; q < 4; q++) {
    float v = acc[q] * nrm;
    v = v >= 0.f ? v : SLOPE * v;
    acc[q] = v;
    ss += v * v;
  }
  ss = wave_sum(ss);
  float sc = 1.0f / fmaxf(sqrtf(ss), 1e-12f);
  #pragma unroll
  for (int q = 0; q < 4; q++) {
    int d = lane + q * 64;
    if (d < H) cur[(size_t)i * H + d] = acc[q] * sc;
  }
}

// ---------------- per-step: time gate + combine + l2norm -> h, evolve (in-place over cur) ----------------
__global__ __launch_bounds__(256) void k_final(const bf16* __restrict__ twb,
                                               float* __restrict__ h,
                                               float* __restrict__ evolve) {
  int wid = threadIdx.x >> 6, lane = threadIdx.x & 63;
  int i = blockIdx.x * 4 + wid;
  if (i >= NE) return;
  float v[4]; float ss = 0.f;
  #pragma unroll
  for (int q = 0; q < 4; q++) {
    int d = lane + q * 64;
    if (d < H) {
      float cur = evolve[(size_t)i * H + d];
      float tw  = b2f(twb[(size_t)i * H + d]);
      float hv  = h[(size_t)i * H + d];
      float val = tw * cur + (1.0f - tw) * hv;
      v[q] = val; ss += val * val;
    } else v[q] = 0.f;
  }
  ss = wave_sum(ss);
  float sc = 1.0f / fmaxf(sqrtf(ss), 1e-12f);
  #pragma unroll
  for (int q = 0; q < 4; q++) {
    int d = lane + q * 64;
    if (d < H) {
      float o = v[q] * sc;
      h[(size_t)i * H + d] = o;
      evolve[(size_t)i * H + d] = o;
    }
  }
}

extern "C" void kernel_launch(void* const* d_in, const int* in_sizes, int n_in,
                              void* d_out, int out_size, void* d_ws, size_t ws_size,
                              hipStream_t stream) {
  const float* de  = (const float*)d_in[0];
  const float* er  = (const float*)d_in[1];
  const float* wih = (const float*)d_in[2];
  const float* whh = (const float*)d_in[3];
  const float* bih = (const float*)d_in[4];
  const float* bhh = (const float*)d_in[5];
  const float* wn  = (const float*)d_in[6];
  const float* tg  = (const float*)d_in[7];
  const float* tgb = (const float*)d_in[8];
  const int* src  = (const int*)d_in[9];
  const int* dst  = (const int*)d_in[10];
  const int* et   = (const int*)d_in[11];
  const int* rte  = (const int*)d_in[12];
  const int* rseg = (const int*)d_in[13];

  char* w = (char*)d_ws;
  auto alloc = [&](size_t bytes) -> char* {
    char* p = w;
    w += (bytes + 255) / 256 * 256;
    return p;
  };
  float* h     = (float*)alloc(sizeof(float) * (size_t)NE * H);   // 40 MB
  bf16*  hWb   = (bf16*) alloc(sizeof(bf16)  * (size_t)NE * H);   // 20 MB
  bf16*  twb   = (bf16*) alloc(sizeof(bf16)  * (size_t)NE * H);   // 20 MB
  float* relW  = (float*)alloc(sizeof(float) * R2C * H);
  float* h0    = (float*)alloc(sizeof(float) * R2C * H);
  float* sums  = (float*)alloc(sizeof(float) * R2C * H);
  unsigned short* bpack = (unsigned short*)alloc(sizeof(unsigned short) * 2 * NT * KS * 64 * 8); // 186 KB
  unsigned short* bgi   = (unsigned short*)alloc(sizeof(unsigned short) * GNT * GKI * 64 * 8);   // 506 KB
  unsigned short* bgh   = (unsigned short*)alloc(sizeof(unsigned short) * GNT * GKH * 64 * 8);   // 272 KB
  unsigned short* xcatb = (unsigned short*)alloc(sizeof(unsigned short) * GR * 416);             // 416 KB
  unsigned short* h0b   = (unsigned short*)alloc(sizeof(unsigned short) * GR * 224);             // 224 KB
  float* gi_ws = (float*)alloc(sizeof(float) * GR * GCS);          // 1.24 MB
  float* gh_ws = (float*)alloc(sizeof(float) * GR * GCS);          // 1.24 MB
  int* segstart= (int*)  alloc(sizeof(int) * (R2C + 1));
  int* deg     = (int*)  alloc(sizeof(int) * NE);
  int* offs    = (int*)  alloc(sizeof(int) * (NE + 1));
  int* cursor  = (int*)  alloc(sizeof(int) * NE);
  int* eids    = (int*)  alloc(sizeof(int) * EC);
  int* bsums   = (int*)  alloc(sizeof(int) * 256);
  (void)ws_size; (void)in_sizes; (void)n_in; (void)out_size;

  float* out    = (float*)d_out;
  float* evolve = out;                       // [TS, NE, H]
  float* h0out  = out + (size_t)TS * NE * H; // [R2C, H]

  const int gRow4  = (NE + 3) / 4;          // 12500
  const int gE     = (EC + 255) / 256;      // 1563
  const int gRel   = (R2C * H + 255) / 256; // 391
  const int gPack  = (2 * NT * KS * 64 + 255) / 256;     // 46
  const int gPackG = (GNT * (GKI + GKH) * 64 + 255) / 256; // 190
  const int gH2b   = (NE * KP / 4 + 255) / 256;          // 10938
  const int gA2b   = (GR * 416 + GR * 224 + 255) / 256;  // 1280
  const int gGemm  = (NE + 63) / 64;                     // 782
  const int gGru   = 8 * GNT;                            // 304
  const int gRelsum= EC / RCH;                           // 3125

  k_init_h<<<gRow4, 256, 0, stream>>>(de, h);
  k_init_h0<<<gRel, 256, 0, stream>>>(er, h0);
  k_relw<<<R2C, 256, 0, stream>>>(er, wn, relW);
  k_packb<<<gPack, 256, 0, stream>>>(wn, tg, bpack);
  k_packgru<<<gPackG, 256, 0, stream>>>(wih, whh, bgi, bgh);

  for (int t = 0; t < TS; t++) {
    const int* src_t  = src  + (size_t)t * EC;
    const int* dst_t  = dst  + (size_t)t * EC;
    const int* et_t   = et   + (size_t)t * EC;
    const int* rte_t  = rte  + (size_t)t * EC;
    const int* rseg_t = rseg + (size_t)t * EC;
    float* evo_t = evolve + (size_t)t * NE * H;
    // bf16 A matrix (and relsums gather source) aliases the evolve[t] slot
    // (22.4 MB < 40 MB); dead before k_aggcur overwrites the slot.
    unsigned short* hb = (unsigned short*)evo_t;

    // bf16 copy of pre-step h first: feeds both relsums gather and MFMA GEMM
    k_h2b<<<gH2b, 256, 0, stream>>>(h, hb);

    // relation-segment means + GRU via MFMA (uses pre-step h, h0)
    k_segbounds<<<1, 512, 0, stream>>>(rseg_t, segstart);
    k_zero_f<<<gRel, 256, 0, stream>>>(sums, R2C * H);
    k_relsums<<<gRelsum, 256, 0, stream>>>(rseg_t, rte_t, hb, sums);
    k_a2b<<<gA2b, 256, 0, stream>>>(er, sums, segstart, h0, xcatb, h0b);
    k_grumm<<<gGru, 256, 0, stream>>>(xcatb, h0b, bgi, bgh, gi_ws, gh_ws);
    k_grutail<<<R2C, 256, 0, stream>>>(gi_ws, gh_ws, bih, bhh,
                                       h0, (t == TS - 1) ? h0out : (float*)nullptr);

    // node GEMMs via MFMA (pre-step h)
    k_mfma_gemm<<<gGemm, 256, 0, stream>>>(hb, bpack, tgb, hWb, twb);

    // CSR build by dst
    k_zero_i<<<NSCAN, 256, 0, stream>>>(deg, NE);
    k_hist<<<gE, 256, 0, stream>>>(dst_t, deg);
    k_scan1<<<NSCAN, 256, 0, stream>>>(deg, offs, bsums);
    k_scan2<<<1, 256, 0, stream>>>(bsums);
    k_scan3<<<NSCAN, 256, 0, stream>>>(offs, bsums, cursor);
    k_scatter<<<gE, 256, 0, stream>>>(dst_t, cursor, eids);

    // aggregate + rrelu + l2norm -> cur (stored in evolve[t] slot of d_out)
    k_aggcur<<<gRow4, 256, 0, stream>>>(offs, eids, src_t, et_t, hWb, relW, evo_t);

    // time gate + combine + l2norm; updates h in place, rewrites evolve[t] with h_new
    k_final<<<gRow4, 256, 0, stream>>>(twb, h, evo_t);
  }
}

// Round 8
// 935.379 us; speedup vs baseline: 5.2335x; 1.2923x over previous
//
#include <hip/hip_runtime.h>
#include <hip/hip_bf16.h>

using bf16 = __hip_bfloat16;

constexpr int NE  = 50000;   // entities
constexpr int H   = 200;     // hidden dim
constexpr int R2C = 500;     // 2*num_rels
constexpr int TS  = 4;       // timesteps
constexpr int EC  = 400000;  // edges per step
constexpr float SLOPE = 0.22916666666666666f;  // rrelu eval slope
constexpr int NSCAN = (NE + 255) / 256;        // 196

// node-GEMM MFMA geometry
constexpr int KP = 224;      // K padded to 7*32
constexpr int KS = 7;        // k-steps of 32
constexpr int NT = 13;       // n-tiles of 16

// GRU-GEMM MFMA geometry (out [512][608])
constexpr int GNT = 38;      // n-tiles (608/16)
constexpr int GKI = 13;      // k-steps for W_ih (416/32)
constexpr int GKH = 7;       // k-steps for W_hh (224/32)
constexpr int GR  = 512;     // padded relation rows
constexpr int GCS = 608;     // padded gate cols (stride)

constexpr int RCH = 128;     // edges per block in k_relsums

#define DEVINL __device__ __forceinline__

typedef __bf16 bf16x8v __attribute__((ext_vector_type(8)));
typedef float  f32x4   __attribute__((ext_vector_type(4)));

DEVINL float b2f(bf16 v) { return __bfloat162float(v); }
DEVINL bf16  f2b(float v) { return __float2bfloat16(v); }
DEVINL unsigned short f2bu(float x) { bf16 b = f2b(x); return *reinterpret_cast<unsigned short*>(&b); }
DEVINL float u2f(unsigned short u) { unsigned int w = (unsigned int)u << 16; float f; __builtin_memcpy(&f, &w, 4); return f; }

DEVINL float wave_sum(float v) {
  #pragma unroll
  for (int o = 32; o > 0; o >>= 1) v += __shfl_xor(v, o, 64);
  return v;
}

DEVINL float sigmoidf(float x) { return 1.0f / (1.0f + expf(-x)); }

// ---------------- init ----------------
__global__ __launch_bounds__(256) void k_init_h(const float* de, float* h) {
  int wid = threadIdx.x >> 6, lane = threadIdx.x & 63;
  int row = blockIdx.x * 4 + wid;
  if (row >= NE) return;
  float v[4]; float ss = 0.f;
  #pragma unroll
  for (int q = 0; q < 4; q++) {
    int d = lane + q * 64;
    v[q] = (d < H) ? de[(size_t)row * H + d] : 0.f;
    ss += v[q] * v[q];
  }
  ss = wave_sum(ss);
  float sc = 1.0f / fmaxf(sqrtf(ss), 1e-12f);
  #pragma unroll
  for (int q = 0; q < 4; q++) {
    int d = lane + q * 64;
    if (d < H) h[(size_t)row * H + d] = v[q] * sc;
  }
}

__global__ __launch_bounds__(256) void k_init_h0(const float* er, float* h0) {
  int i = blockIdx.x * 256 + threadIdx.x;
  if (i < R2C * H) h0[i] = er[i];
}

// relW = emb_rel @ W_n   [R2C, H]
__global__ __launch_bounds__(256) void k_relw(const float* er, const float* wn, float* relW) {
  __shared__ float a[H];
  int r = blockIdx.x;
  for (int d = threadIdx.x; d < H; d += 256) a[d] = er[r * H + d];
  __syncthreads();
  for (int c = threadIdx.x; c < H; c += 256) {
    float s = 0.f;
    for (int k = 0; k < H; k++) s += a[k] * wn[k * H + c];
    relW[r * H + c] = s;
  }
}

// pack Wn and Tg into per-lane MFMA B-fragment order, zero-padded to [KP][NP].
__global__ __launch_bounds__(256) void k_packb(const float* wn, const float* tg,
                                               unsigned short* bpack) {
  int t = blockIdx.x * 256 + threadIdx.x;
  int total = 2 * NT * KS * 64;
  if (t >= total) return;
  int m    = t / (NT * KS * 64);
  int rem  = t % (NT * KS * 64);
  int nt   = rem / (KS * 64);
  int rem2 = rem % (KS * 64);
  int ks   = rem2 / 64, lane = rem2 % 64;
  const float* W = m ? tg : wn;
  int n = nt * 16 + (lane & 15);
  unsigned short out[8];
  #pragma unroll
  for (int j = 0; j < 8; j++) {
    int k = ks * 32 + (lane >> 4) * 8 + j;
    float v = (k < H && n < H) ? W[k * H + n] : 0.f;
    out[j] = f2bu(v);
  }
  unsigned short* dst = bpack + (size_t)t * 8;
  #pragma unroll
  for (int j = 0; j < 8; j++) dst[j] = out[j];
}

// pack W_ih [600,400] and W_hh [600,200] (row-major [n][k]) into B-frag order
// for out = A @ W^T: B[k][n] = W[n][k]. Padded to K=416/224, N=608.
__global__ __launch_bounds__(256) void k_packgru(const float* __restrict__ wih,
                                                 const float* __restrict__ whh,
                                                 unsigned short* __restrict__ bgi,
                                                 unsigned short* __restrict__ bgh) {
  int t = blockIdx.x * 256 + threadIdx.x;
  const int tot_i = GNT * GKI * 64;
  const int tot_h = GNT * GKH * 64;
  if (t < tot_i) {
    int nt = t / (GKI * 64);
    int rem = t % (GKI * 64);
    int ks = rem / 64, lane = rem % 64;
    int n = nt * 16 + (lane & 15);
    unsigned short o[8];
    #pragma unroll
    for (int j = 0; j < 8; j++) {
      int k = ks * 32 + (lane >> 4) * 8 + j;
      o[j] = (n < 3 * H && k < 2 * H) ? f2bu(wih[n * (2 * H) + k]) : (unsigned short)0;
    }
    unsigned short* dstp = bgi + (size_t)t * 8;
    #pragma unroll
    for (int j = 0; j < 8; j++) dstp[j] = o[j];
  } else if (t < tot_i + tot_h) {
    int t2 = t - tot_i;
    int nt = t2 / (GKH * 64);
    int rem = t2 % (GKH * 64);
    int ks = rem / 64, lane = rem % 64;
    int n = nt * 16 + (lane & 15);
    unsigned short o[8];
    #pragma unroll
    for (int j = 0; j < 8; j++) {
      int k = ks * 32 + (lane >> 4) * 8 + j;
      o[j] = (n < 3 * H && k < H) ? f2bu(whh[n * H + k]) : (unsigned short)0;
    }
    unsigned short* dstp = bgh + (size_t)t2 * 8;
    #pragma unroll
    for (int j = 0; j < 8; j++) dstp[j] = o[j];
  }
}

// convert h (f32 [NE][H]) -> hb (bf16 [NE][KP], zero-padded cols 200..223)
__global__ __launch_bounds__(256) void k_h2b(const float* __restrict__ h,
                                             unsigned short* __restrict__ hb) {
  int i = (blockIdx.x * 256 + threadIdx.x) * 4;
  if (i >= NE * KP) return;
  int row = i / KP, col = i % KP;   // col % 4 == 0
  ushort4 o;
  if (col < H) {
    const float4 v = *reinterpret_cast<const float4*>(h + (size_t)row * H + col);
    o.x = f2bu(v.x); o.y = f2bu(v.y); o.z = f2bu(v.z); o.w = f2bu(v.w);
  } else {
    o.x = o.y = o.z = o.w = 0;
  }
  *reinterpret_cast<ushort4*>(hb + i) = o;
}

// build GRU A-matrices: xcatb [512][416] = [emb_rel | seg-mean], h0b [512][224]
__global__ __launch_bounds__(256) void k_a2b(const float* __restrict__ er,
                                             const float* __restrict__ sums,
                                             const int* __restrict__ segstart,
                                             const float* __restrict__ h0,
                                             unsigned short* __restrict__ xcatb,
                                             unsigned short* __restrict__ h0b) {
  int i = blockIdx.x * 256 + threadIdx.x;
  const int n1 = GR * 416;
  if (i < n1) {
    int r = i / 416, c = i % 416;
    float v = 0.f;
    if (r < R2C) {
      if (c < H) v = er[r * H + c];
      else if (c < 2 * H) {
        int cnt = segstart[r + 1] - segstart[r];
        float inv = cnt > 0 ? 1.0f / (float)cnt : 0.0f;
        v = sums[r * H + (c - H)] * inv;
      }
    }
    xcatb[i] = f2bu(v);
  } else {
    int i2 = i - n1;
    if (i2 < GR * 224) {
      int r = i2 / 224, c = i2 % 224;
      float v = (r < R2C && c < H) ? h0[r * H + c] : 0.f;
      h0b[i2] = f2bu(v);
    }
  }
}

// ---------------- generic zero ----------------
__global__ void k_zero_f(float* p, int n) {
  int i = blockIdx.x * 256 + threadIdx.x;
  if (i < n) p[i] = 0.f;
}
__global__ void k_zero_i(int* p, int n) {
  int i = blockIdx.x * 256 + threadIdx.x;
  if (i < n) p[i] = 0;
}

// ---------------- per-step: relation segment bounds (sorted rseg) ----------------
__global__ __launch_bounds__(512) void k_segbounds(const int* rseg, int* segstart) {
  for (int r = threadIdx.x; r <= R2C; r += 512) {
    int lo = 0, hi = EC;
    while (lo < hi) { int m = (lo + hi) >> 1; if (rseg[m] < r) lo = m + 1; else hi = m; }
    segstart[r] = lo;
  }
}

// segment-sum over sorted rseg, gathering bf16 rows of hb.
__global__ __launch_bounds__(256) void k_relsums(const int* __restrict__ rseg,
                                                 const int* __restrict__ rte,
                                                 const unsigned short* __restrict__ hb,
                                                 float* __restrict__ sums) {
  int base = blockIdx.x * RCH;
  int d = threadIdx.x;
  bool act = d < H;
  float a0 = 0.f, a1 = 0.f, a2 = 0.f, a3 = 0.f;
  int prev = rseg[base];
  for (int g = 0; g < RCH; g += 4) {
    int e = base + g;
    int4 sg = *reinterpret_cast<const int4*>(rseg + e);
    int4 rr = *reinterpret_cast<const int4*>(rte + e);
    if (sg.w == prev) {            // sorted => whole group in same segment (uniform branch)
      if (act) {
        a0 += u2f(hb[(size_t)rr.x * KP + d]);
        a1 += u2f(hb[(size_t)rr.y * KP + d]);
        a2 += u2f(hb[(size_t)rr.z * KP + d]);
        a3 += u2f(hb[(size_t)rr.w * KP + d]);
      }
    } else {                       // boundary group (rare): scalar path
      int ss[4] = {sg.x, sg.y, sg.z, sg.w};
      int rr2[4] = {rr.x, rr.y, rr.z, rr.w};
      #pragma unroll
      for (int j = 0; j < 4; j++) {
        if (ss[j] != prev) {
          if (act) atomicAdd(&sums[prev * H + d], a0 + a1 + a2 + a3);
          a0 = a1 = a2 = a3 = 0.f;
          prev = ss[j];
        }
        if (act) a0 += u2f(hb[(size_t)rr2[j] * KP + d]);
      }
    }
  }
  if (act) atomicAdd(&sums[prev * H + d], a0 + a1 + a2 + a3);
}

// ---------------- per-step: GRU GEMMs via MFMA -> gi, gh [512][608] f32 ----------------
__global__ __launch_bounds__(256) void k_grumm(const unsigned short* __restrict__ xcatb,
                                               const unsigned short* __restrict__ h0b,
                                               const unsigned short* __restrict__ bgi,
                                               const unsigned short* __restrict__ bgh,
                                               float* __restrict__ gi_ws,
                                               float* __restrict__ gh_ws) {
  int wid = threadIdx.x >> 6, lane = threadIdx.x & 63;
  int nt   = blockIdx.x % GNT;
  int row0 = (blockIdx.x / GNT) * 64 + wid * 16;
  int arow = row0 + (lane & 15);

  const unsigned short* api = xcatb + (size_t)arow * 416 + (lane >> 4) * 8;
  bf16x8v ai[GKI];
  #pragma unroll
  for (int ks = 0; ks < GKI; ks++)
    ai[ks] = *reinterpret_cast<const bf16x8v*>(api + ks * 32);
  const unsigned short* aph = h0b + (size_t)arow * 224 + (lane >> 4) * 8;
  bf16x8v ah[GKH];
  #pragma unroll
  for (int ks = 0; ks < GKH; ks++)
    ah[ks] = *reinterpret_cast<const bf16x8v*>(aph + ks * 32);

  const unsigned short* bip = bgi + ((size_t)(nt * GKI) * 64 + lane) * 8;
  bf16x8v bi[GKI];
  #pragma unroll
  for (int ks = 0; ks < GKI; ks++)
    bi[ks] = *reinterpret_cast<const bf16x8v*>(bip + (size_t)ks * 64 * 8);
  const unsigned short* bhp = bgh + ((size_t)(nt * GKH) * 64 + lane) * 8;
  bf16x8v bh[GKH];
  #pragma unroll
  for (int ks = 0; ks < GKH; ks++)
    bh[ks] = *reinterpret_cast<const bf16x8v*>(bhp + (size_t)ks * 64 * 8);

  f32x4 a1 = {}, a2 = {};
  #pragma unroll
  for (int ks = 0; ks < GKI; ks++)
    a1 = __builtin_amdgcn_mfma_f32_16x16x32_bf16(ai[ks], bi[ks], a1, 0, 0, 0);
  #pragma unroll
  for (int ks = 0; ks < GKH; ks++)
    a2 = __builtin_amdgcn_mfma_f32_16x16x32_bf16(ah[ks], bh[ks], a2, 0, 0, 0);

  int col = nt * 16 + (lane & 15);
  int rb = row0 + (lane >> 4) * 4;
  #pragma unroll
  for (int q = 0; q < 4; q++) {
    gi_ws[(size_t)(rb + q) * GCS + col] = a1[q];
    gh_ws[(size_t)(rb + q) * GCS + col] = a2[q];
  }
}

// ---------------- per-step: GRU gates + l2norm -> h0 (and h0_out on last step) ----------------
__global__ __launch_bounds__(256) void k_grutail(const float* __restrict__ gi_ws,
                                                 const float* __restrict__ gh_ws,
                                                 const float* __restrict__ b_ih,
                                                 const float* __restrict__ b_hh,
                                                 float* __restrict__ h0,
                                                 float* __restrict__ h0_out) {
  __shared__ float xc[H];
  __shared__ float red[4];
  int r = blockIdx.x;
  int tid = threadIdx.x, wid = tid >> 6, lane = tid & 63;
  float ssp = 0.f;
  for (int d = tid; d < H; d += 256) {
    float gir = gi_ws[(size_t)r * GCS + d]         + b_ih[d];
    float ghr = gh_ws[(size_t)r * GCS + d]         + b_hh[d];
    float giz = gi_ws[(size_t)r * GCS + H + d]     + b_ih[H + d];
    float ghz = gh_ws[(size_t)r * GCS + H + d]     + b_hh[H + d];
    float gin = gi_ws[(size_t)r * GCS + 2 * H + d] + b_ih[2 * H + d];
    float ghn = gh_ws[(size_t)r * GCS + 2 * H + d] + b_hh[2 * H + d];
    float rg = sigmoidf(gir + ghr);
    float z  = sigmoidf(giz + ghz);
    float n  = tanhf(gin + rg * ghn);
    float hv = h0[r * H + d];
    float o  = (1.0f - z) * n + z * hv;
    xc[d] = o;
    ssp += o * o;
  }
  ssp = wave_sum(ssp);
  if (lane == 0) red[wid] = ssp;
  __syncthreads();
  float ss = red[0] + red[1] + red[2] + red[3];
  float sc = 1.0f / fmaxf(sqrtf(ss), 1e-12f);
  for (int d = tid; d < H; d += 256) {
    float o = xc[d] * sc;
    h0[r * H + d] = o;
    if (h0_out) h0_out[r * H + d] = o;
  }
}

// ---------------- per-step: MFMA node GEMMs (hW = h@Wn, tw = sigmoid(h@Tg+b)) ----------------
__global__ __launch_bounds__(256) void k_mfma_gemm(const unsigned short* __restrict__ hb,
                                                   const unsigned short* __restrict__ bpack,
                                                   const float* __restrict__ tgb,
                                                   bf16* __restrict__ hWb,
                                                   bf16* __restrict__ twb) {
  int wid = threadIdx.x >> 6, lane = threadIdx.x & 63;
  int row0 = blockIdx.x * 64 + wid * 16;
  if (row0 >= NE) return;                 // wave-uniform
  int arow = min(row0 + (lane & 15), NE - 1);
  const unsigned short* ap = hb + (size_t)arow * KP + (lane >> 4) * 8;
  bf16x8v a[KS];
  #pragma unroll
  for (int ks = 0; ks < KS; ks++)
    a[ks] = *reinterpret_cast<const bf16x8v*>(ap + ks * 32);

  const unsigned short* b1p = bpack + (size_t)lane * 8;
  const unsigned short* b2p = b1p + (size_t)NT * KS * 64 * 8;
  int colb = lane & 15;
  int rbase = row0 + (lane >> 4) * 4;

  for (int nt = 0; nt < NT; nt++) {
    bf16x8v b1[KS], b2[KS];
    #pragma unroll
    for (int ks = 0; ks < KS; ks++) {
      size_t boff = (size_t)(nt * KS + ks) * 64 * 8;
      b1[ks] = *reinterpret_cast<const bf16x8v*>(b1p + boff);
      b2[ks] = *reinterpret_cast<const bf16x8v*>(b2p + boff);
    }
    f32x4 acc1 = {}, acc2 = {};
    #pragma unroll
    for (int ks = 0; ks < KS; ks++) {
      acc1 = __builtin_amdgcn_mfma_f32_16x16x32_bf16(a[ks], b1[ks], acc1, 0, 0, 0);
      acc2 = __builtin_amdgcn_mfma_f32_16x16x32_bf16(a[ks], b2[ks], acc2, 0, 0, 0);
    }
    int col = nt * 16 + colb;
    bool cok = (col < H);
    float bias = cok ? tgb[col] : 0.f;
    #pragma unroll
    for (int q = 0; q < 4; q++) {
      int row = rbase + q;
      if (cok && row < NE) {
        hWb[(size_t)row * H + col] = f2b(acc1[q]);
        twb[(size_t)row * H + col] = f2b(sigmoidf(acc2[q] + bias));
      }
    }
  }
}

// ---------------- per-step: CSR build by dst ----------------
__global__ void k_hist(const int* dst, int* deg) {
  int e = blockIdx.x * 256 + threadIdx.x;
  if (e < EC) atomicAdd(&deg[dst[e]], 1);
}

__global__ __launch_bounds__(256) void k_scan1(const int* deg, int* offs, int* bsums) {
  __shared__ int s[256];
  int i = blockIdx.x * 256 + threadIdx.x;
  int v = (i < NE) ? deg[i] : 0;
  s[threadIdx.x] = v;
  __syncthreads();
  for (int o = 1; o < 256; o <<= 1) {
    int add = (threadIdx.x >= o) ? s[threadIdx.x - o] : 0;
    __syncthreads();
    s[threadIdx.x] += add;
    __syncthreads();
  }
  if (i < NE) offs[i] = s[threadIdx.x] - v;  // exclusive
  if (threadIdx.x == 255) bsums[blockIdx.x] = s[255];
}

__global__ __launch_bounds__(256) void k_scan2(int* bsums) {
  __shared__ int s[256];
  int v = (threadIdx.x < NSCAN) ? bsums[threadIdx.x] : 0;
  s[threadIdx.x] = v;
  __syncthreads();
  for (int o = 1; o < 256; o <<= 1) {
    int add = (threadIdx.x >= o) ? s[threadIdx.x - o] : 0;
    __syncthreads();
    s[threadIdx.x] += add;
    __syncthreads();
  }
  if (threadIdx.x < NSCAN) bsums[threadIdx.x] = s[threadIdx.x] - v;  // exclusive
}

__global__ void k_scan3(int* offs, const int* bsums, int* cursor) {
  int i = blockIdx.x * 256 + threadIdx.x;
  if (i < NE) {
    int o = offs[i] + bsums[blockIdx.x];
    offs[i] = o;
    cursor[i] = o;
  }
  if (blockIdx.x == 0 && threadIdx.x == 0) offs[NE] = EC;
}

// scatter (src,et) payloads into CSR order -> se[pos]
__global__ void k_scatter(const int* __restrict__ dst, const int* __restrict__ src,
                          const int* __restrict__ et, int* __restrict__ cursor,
                          int2* __restrict__ se) {
  int e = blockIdx.x * 256 + threadIdx.x;
  if (e < EC) {
    int pos = atomicAdd(&cursor[dst[e]], 1);
    se[pos] = make_int2(src[e], et[e]);
  }
}

// ---------------- per-step: aggregate + rrelu + l2norm + time gate + l2norm ----------------
// fused k_aggcur + k_final. Lane d-mapping: d = lane*4 (lanes 0..49 active, H=200=50*4).
__global__ __launch_bounds__(256) void k_aggfin(const int* __restrict__ offs,
                                                const int2* __restrict__ se,
                                                const bf16* __restrict__ hWb,
                                                const float* __restrict__ relW,
                                                const bf16* __restrict__ twb,
                                                float* __restrict__ h,
                                                float* __restrict__ evolve) {
  int wid = threadIdx.x >> 6, lane = threadIdx.x & 63;
  int i = blockIdx.x * 4 + wid;
  if (i >= NE) return;
  int s0 = offs[i], s1 = offs[i + 1];
  int d0 = lane * 4;
  bool act = d0 < H;
  const unsigned short* hw = (const unsigned short*)hWb;
  float a0 = 0.f, a1 = 0.f, a2 = 0.f, a3 = 0.f;

  int p = s0;
  for (; p + 4 <= s1; p += 4) {
    int2 e0 = se[p], e1 = se[p + 1], e2 = se[p + 2], e3 = se[p + 3];
    if (act) {
      ushort4 m0 = *reinterpret_cast<const ushort4*>(hw + (size_t)e0.x * H + d0);
      ushort4 m1 = *reinterpret_cast<const ushort4*>(hw + (size_t)e1.x * H + d0);
      ushort4 m2 = *reinterpret_cast<const ushort4*>(hw + (size_t)e2.x * H + d0);
      ushort4 m3 = *reinterpret_cast<const ushort4*>(hw + (size_t)e3.x * H + d0);
      float4 r0 = *reinterpret_cast<const float4*>(relW + (size_t)e0.y * H + d0);
      float4 r1 = *reinterpret_cast<const float4*>(relW + (size_t)e1.y * H + d0);
      float4 r2 = *reinterpret_cast<const float4*>(relW + (size_t)e2.y * H + d0);
      float4 r3 = *reinterpret_cast<const float4*>(relW + (size_t)e3.y * H + d0);
      a0 += u2f(m0.x) + r0.x + u2f(m1.x) + r1.x + u2f(m2.x) + r2.x + u2f(m3.x) + r3.x;
      a1 += u2f(m0.y) + r0.y + u2f(m1.y) + r1.y + u2f(m2.y) + r2.y + u2f(m3.y) + r3.y;
      a2 += u2f(m0.z) + r0.z + u2f(m1.z) + r1.z + u2f(m2.z) + r2.z + u2f(m3.z) + r3.z;
      a3 += u2f(m0.w) + r0.w + u2f(m1.w) + r1.w + u2f(m2.w) + r2.w + u2f(m3.w) + r3.w;
    }
  }
  for (; p < s1; p++) {
    int2 e0 = se[p];
    if (act) {
      ushort4 m0 = *reinterpret_cast<const ushort4*>(hw + (size_t)e0.x * H + d0);
      float4 r0 = *reinterpret_cast<const float4*>(relW + (size_t)e0.y * H + d0);
      a0 += u2f(m0.x) + r0.x;
      a1 += u2f(m0.y) + r0.y;
      a2 += u2f(m0.z) + r0.z;
      a3 += u2f(m0.w) + r0.w;
    }
  }

  int deg = s1 - s0;
  float nrm = deg > 0 ? 1.0f / (float)deg : 0.0f;
  float c0 = a0 * nrm; c0 = c0 >= 0.f ? c0 : SLOPE * c0;
  float c1 = a1 * nrm; c1 = c1 >= 0.f ? c1 : SLOPE * c1;
  float c2 = a2 * nrm; c2 = c2 >= 0.f ? c2 : SLOPE * c2;
  float c3 = a3 * nrm; c3 = c3 >= 0.f ? c3 : SLOPE * c3;
  float ss = act ? (c0 * c0 + c1 * c1 + c2 * c2 + c3 * c3) : 0.f;
  ss = wave_sum(ss);
  float sc = 1.0f / fmaxf(sqrtf(ss), 1e-12f);
  c0 *= sc; c1 *= sc; c2 *= sc; c3 *= sc;

  // time gate + combine + l2norm
  float v0 = 0.f, v1 = 0.f, v2 = 0.f, v3 = 0.f;
  if (act) {
    ushort4 t4 = *reinterpret_cast<const ushort4*>((const unsigned short*)twb + (size_t)i * H + d0);
    float4 hv = *reinterpret_cast<const float4*>(h + (size_t)i * H + d0);
    float t0 = u2f(t4.x), t1 = u2f(t4.y), t2 = u2f(t4.z), t3 = u2f(t4.w);
    v0 = t0 * c0 + (1.0f - t0) * hv.x;
    v1 = t1 * c1 + (1.0f - t1) * hv.y;
    v2 = t2 * c2 + (1.0f - t2) * hv.z;
    v3 = t3 * c3 + (1.0f - t3) * hv.w;
  }
  float ss2 = v0 * v0 + v1 * v1 + v2 * v2 + v3 * v3;
  ss2 = wave_sum(ss2);
  float sc2 = 1.0f / fmaxf(sqrtf(ss2), 1e-12f);
  if (act) {
    float4 o = make_float4(v0 * sc2, v1 * sc2, v2 * sc2, v3 * sc2);
    *reinterpret_cast<float4*>(h + (size_t)i * H + d0) = o;
    *reinterpret_cast<float4*>(evolve + (size_t)i * H + d0) = o;
  }
}

extern "C" void kernel_launch(void* const* d_in, const int* in_sizes, int n_in,
                              void* d_out, int out_size, void* d_ws, size_t ws_size,
                              hipStream_t stream) {
  const float* de  = (const float*)d_in[0];
  const float* er  = (const float*)d_in[1];
  const float* wih = (const float*)d_in[2];
  const float* whh = (const float*)d_in[3];
  const float* bih = (const float*)d_in[4];
  const float* bhh = (const float*)d_in[5];
  const float* wn  = (const float*)d_in[6];
  const float* tg  = (const float*)d_in[7];
  const float* tgb = (const float*)d_in[8];
  const int* src  = (const int*)d_in[9];
  const int* dst  = (const int*)d_in[10];
  const int* et   = (const int*)d_in[11];
  const int* rte  = (const int*)d_in[12];
  const int* rseg = (const int*)d_in[13];

  char* w = (char*)d_ws;
  auto alloc = [&](size_t bytes) -> char* {
    char* p = w;
    w += (bytes + 255) / 256 * 256;
    return p;
  };
  float* h     = (float*)alloc(sizeof(float) * (size_t)NE * H);   // 40 MB
  bf16*  hWb   = (bf16*) alloc(sizeof(bf16)  * (size_t)NE * H);   // 20 MB
  bf16*  twb   = (bf16*) alloc(sizeof(bf16)  * (size_t)NE * H);   // 20 MB
  float* relW  = (float*)alloc(sizeof(float) * R2C * H);
  float* h0    = (float*)alloc(sizeof(float) * R2C * H);
  float* sums  = (float*)alloc(sizeof(float) * R2C * H);
  unsigned short* bpack = (unsigned short*)alloc(sizeof(unsigned short) * 2 * NT * KS * 64 * 8); // 186 KB
  unsigned short* bgi   = (unsigned short*)alloc(sizeof(unsigned short) * GNT * GKI * 64 * 8);   // 506 KB
  unsigned short* bgh   = (unsigned short*)alloc(sizeof(unsigned short) * GNT * GKH * 64 * 8);   // 272 KB
  unsigned short* xcatb = (unsigned short*)alloc(sizeof(unsigned short) * GR * 416);             // 416 KB
  unsigned short* h0b   = (unsigned short*)alloc(sizeof(unsigned short) * GR * 224);             // 224 KB
  float* gi_ws = (float*)alloc(sizeof(float) * GR * GCS);          // 1.24 MB
  float* gh_ws = (float*)alloc(sizeof(float) * GR * GCS);          // 1.24 MB
  int* segstart= (int*)  alloc(sizeof(int) * (R2C + 1));
  int* deg     = (int*)  alloc(sizeof(int) * NE);
  int* offs    = (int*)  alloc(sizeof(int) * (NE + 1));
  int* cursor  = (int*)  alloc(sizeof(int) * NE);
  int2* sepack = (int2*) alloc(sizeof(int2) * EC);                 // 3.2 MB
  int* bsums   = (int*)  alloc(sizeof(int) * 256);
  (void)ws_size; (void)in_sizes; (void)n_in; (void)out_size;

  float* out    = (float*)d_out;
  float* evolve = out;                       // [TS, NE, H]
  float* h0out  = out + (size_t)TS * NE * H; // [R2C, H]

  const int gRow4  = (NE + 3) / 4;          // 12500
  const int gE     = (EC + 255) / 256;      // 1563
  const int gRel   = (R2C * H + 255) / 256; // 391
  const int gPack  = (2 * NT * KS * 64 + 255) / 256;     // 46
  const int gPackG = (GNT * (GKI + GKH) * 64 + 255) / 256; // 190
  const int gH2b   = (NE * KP / 4 + 255) / 256;          // 10938
  const int gA2b   = (GR * 416 + GR * 224 + 255) / 256;  // 1280
  const int gGemm  = (NE + 63) / 64;                     // 782
  const int gGru   = 8 * GNT;                            // 304
  const int gRelsum= EC / RCH;                           // 3125

  k_init_h<<<gRow4, 256, 0, stream>>>(de, h);
  k_init_h0<<<gRel, 256, 0, stream>>>(er, h0);
  k_relw<<<R2C, 256, 0, stream>>>(er, wn, relW);
  k_packb<<<gPack, 256, 0, stream>>>(wn, tg, bpack);
  k_packgru<<<gPackG, 256, 0, stream>>>(wih, whh, bgi, bgh);

  for (int t = 0; t < TS; t++) {
    const int* src_t  = src  + (size_t)t * EC;
    const int* dst_t  = dst  + (size_t)t * EC;
    const int* et_t   = et   + (size_t)t * EC;
    const int* rte_t  = rte  + (size_t)t * EC;
    const int* rseg_t = rseg + (size_t)t * EC;
    float* evo_t = evolve + (size_t)t * NE * H;
    // bf16 A matrix (and relsums gather source) aliases the evolve[t] slot
    // (22.4 MB < 40 MB); dead before k_aggfin overwrites the slot.
    unsigned short* hb = (unsigned short*)evo_t;

    // bf16 copy of pre-step h first: feeds both relsums gather and MFMA GEMM
    k_h2b<<<gH2b, 256, 0, stream>>>(h, hb);

    // relation-segment means + GRU via MFMA (uses pre-step h, h0)
    k_segbounds<<<1, 512, 0, stream>>>(rseg_t, segstart);
    k_zero_f<<<gRel, 256, 0, stream>>>(sums, R2C * H);
    k_relsums<<<gRelsum, 256, 0, stream>>>(rseg_t, rte_t, hb, sums);
    k_a2b<<<gA2b, 256, 0, stream>>>(er, sums, segstart, h0, xcatb, h0b);
    k_grumm<<<gGru, 256, 0, stream>>>(xcatb, h0b, bgi, bgh, gi_ws, gh_ws);
    k_grutail<<<R2C, 256, 0, stream>>>(gi_ws, gh_ws, bih, bhh,
                                       h0, (t == TS - 1) ? h0out : (float*)nullptr);

    // node GEMMs via MFMA (pre-step h)
    k_mfma_gemm<<<gGemm, 256, 0, stream>>>(hb, bpack, tgb, hWb, twb);

    // CSR build by dst (payload scatter: (src,et) pairs)
    k_zero_i<<<NSCAN, 256, 0, stream>>>(deg, NE);
    k_hist<<<gE, 256, 0, stream>>>(dst_t, deg);
    k_scan1<<<NSCAN, 256, 0, stream>>>(deg, offs, bsums);
    k_scan2<<<1, 256, 0, stream>>>(bsums);
    k_scan3<<<NSCAN, 256, 0, stream>>>(offs, bsums, cursor);
    k_scatter<<<gE, 256, 0, stream>>>(dst_t, src_t, et_t, cursor, sepack);

    // fused aggregate + rrelu + l2norm + time gate + combine + l2norm
    // -> writes h (in place) and evolve[t]
    k_aggfin<<<gRow4, 256, 0, stream>>>(offs, sepack, hWb, relW, twb, h, evo_t);
  }
}

// Round 9
// 836.440 us; speedup vs baseline: 5.8525x; 1.1183x over previous
//
#include <hip/hip_runtime.h>
#include <hip/hip_bf16.h>

using bf16 = __hip_bfloat16;

constexpr int NE  = 50000;   // entities
constexpr int H   = 200;     // hidden dim
constexpr int R2C = 500;     // 2*num_rels
constexpr int TS  = 4;       // timesteps
constexpr int EC  = 400000;  // edges per step
constexpr float SLOPE = 0.22916666666666666f;  // rrelu eval slope
constexpr int NSCAN = (NE + 255) / 256;        // 196

// node-GEMM MFMA geometry
constexpr int KP = 224;      // K padded to 7*32
constexpr int KS = 7;        // k-steps of 32
constexpr int NT = 13;       // n-tiles of 16

// GRU-GEMM MFMA geometry (out [512][608])
constexpr int GNT = 38;      // n-tiles (608/16)
constexpr int GKI = 13;      // k-steps for W_ih (416/32)
constexpr int GKH = 7;       // k-steps for W_hh (224/32)
constexpr int GR  = 512;     // padded relation rows
constexpr int GCS = 608;     // padded gate cols (stride)

constexpr int RCH = 128;     // edges per block in k_relsums

#define DEVINL __device__ __forceinline__

typedef __bf16 bf16x8v __attribute__((ext_vector_type(8)));
typedef float  f32x4   __attribute__((ext_vector_type(4)));

DEVINL float b2f(bf16 v) { return __bfloat162float(v); }
DEVINL bf16  f2b(float v) { return __float2bfloat16(v); }
DEVINL unsigned short f2bu(float x) { bf16 b = f2b(x); return *reinterpret_cast<unsigned short*>(&b); }
DEVINL float u2f(unsigned short u) { unsigned int w = (unsigned int)u << 16; float f; __builtin_memcpy(&f, &w, 4); return f; }

DEVINL float wave_sum(float v) {
  #pragma unroll
  for (int o = 32; o > 0; o >>= 1) v += __shfl_xor(v, o, 64);
  return v;
}

DEVINL float sigmoidf(float x) { return 1.0f / (1.0f + expf(-x)); }

// ---------------- init: l2norm rows of dynamic_emb -> h (f32) AND hb0 (bf16 padded) ----------------
__global__ __launch_bounds__(256) void k_init_h(const float* __restrict__ de,
                                                float* __restrict__ h,
                                                unsigned short* __restrict__ hb0) {
  int wid = threadIdx.x >> 6, lane = threadIdx.x & 63;
  int row = blockIdx.x * 4 + wid;
  if (row >= NE) return;
  int d0 = lane * 4;
  bool act = d0 < H;
  float4 v = make_float4(0.f, 0.f, 0.f, 0.f);
  if (act) v = *reinterpret_cast<const float4*>(de + (size_t)row * H + d0);
  float ss = v.x * v.x + v.y * v.y + v.z * v.z + v.w * v.w;
  ss = wave_sum(ss);
  float sc = 1.0f / fmaxf(sqrtf(ss), 1e-12f);
  if (act) {
    float4 o = make_float4(v.x * sc, v.y * sc, v.z * sc, v.w * sc);
    *reinterpret_cast<float4*>(h + (size_t)row * H + d0) = o;
    ushort4 ob; ob.x = f2bu(o.x); ob.y = f2bu(o.y); ob.z = f2bu(o.z); ob.w = f2bu(o.w);
    *reinterpret_cast<ushort4*>(hb0 + (size_t)row * KP + d0) = ob;
  } else if (d0 < KP) {
    ushort4 z; z.x = z.y = z.z = z.w = 0;
    *reinterpret_cast<ushort4*>(hb0 + (size_t)row * KP + d0) = z;
  }
}

__global__ __launch_bounds__(256) void k_init_h0(const float* er, float* h0) {
  int i = blockIdx.x * 256 + threadIdx.x;
  if (i < R2C * H) h0[i] = er[i];
}

// relW = emb_rel @ W_n   [R2C, H]
__global__ __launch_bounds__(256) void k_relw(const float* er, const float* wn, float* relW) {
  __shared__ float a[H];
  int r = blockIdx.x;
  for (int d = threadIdx.x; d < H; d += 256) a[d] = er[r * H + d];
  __syncthreads();
  for (int c = threadIdx.x; c < H; c += 256) {
    float s = 0.f;
    for (int k = 0; k < H; k++) s += a[k] * wn[k * H + c];
    relW[r * H + c] = s;
  }
}

// pack Wn and Tg into per-lane MFMA B-fragment order, zero-padded to [KP][NP].
__global__ __launch_bounds__(256) void k_packb(const float* wn, const float* tg,
                                               unsigned short* bpack) {
  int t = blockIdx.x * 256 + threadIdx.x;
  int total = 2 * NT * KS * 64;
  if (t >= total) return;
  int m    = t / (NT * KS * 64);
  int rem  = t % (NT * KS * 64);
  int nt   = rem / (KS * 64);
  int rem2 = rem % (KS * 64);
  int ks   = rem2 / 64, lane = rem2 % 64;
  const float* W = m ? tg : wn;
  int n = nt * 16 + (lane & 15);
  unsigned short out[8];
  #pragma unroll
  for (int j = 0; j < 8; j++) {
    int k = ks * 32 + (lane >> 4) * 8 + j;
    float v = (k < H && n < H) ? W[k * H + n] : 0.f;
    out[j] = f2bu(v);
  }
  unsigned short* dst = bpack + (size_t)t * 8;
  #pragma unroll
  for (int j = 0; j < 8; j++) dst[j] = out[j];
}

// pack W_ih [600,400] and W_hh [600,200] (row-major [n][k]) into B-frag order
__global__ __launch_bounds__(256) void k_packgru(const float* __restrict__ wih,
                                                 const float* __restrict__ whh,
                                                 unsigned short* __restrict__ bgi,
                                                 unsigned short* __restrict__ bgh) {
  int t = blockIdx.x * 256 + threadIdx.x;
  const int tot_i = GNT * GKI * 64;
  const int tot_h = GNT * GKH * 64;
  if (t < tot_i) {
    int nt = t / (GKI * 64);
    int rem = t % (GKI * 64);
    int ks = rem / 64, lane = rem % 64;
    int n = nt * 16 + (lane & 15);
    unsigned short o[8];
    #pragma unroll
    for (int j = 0; j < 8; j++) {
      int k = ks * 32 + (lane >> 4) * 8 + j;
      o[j] = (n < 3 * H && k < 2 * H) ? f2bu(wih[n * (2 * H) + k]) : (unsigned short)0;
    }
    unsigned short* dstp = bgi + (size_t)t * 8;
    #pragma unroll
    for (int j = 0; j < 8; j++) dstp[j] = o[j];
  } else if (t < tot_i + tot_h) {
    int t2 = t - tot_i;
    int nt = t2 / (GKH * 64);
    int rem = t2 % (GKH * 64);
    int ks = rem / 64, lane = rem % 64;
    int n = nt * 16 + (lane & 15);
    unsigned short o[8];
    #pragma unroll
    for (int j = 0; j < 8; j++) {
      int k = ks * 32 + (lane >> 4) * 8 + j;
      o[j] = (n < 3 * H && k < H) ? f2bu(whh[n * H + k]) : (unsigned short)0;
    }
    unsigned short* dstp = bgh + (size_t)t2 * 8;
    #pragma unroll
    for (int j = 0; j < 8; j++) dstp[j] = o[j];
  }
}

// build GRU A-matrices: xcatb [512][416] = [emb_rel | seg-mean], h0b [512][224]
__global__ __launch_bounds__(256) void k_a2b(const float* __restrict__ er,
                                             const float* __restrict__ sums,
                                             const int* __restrict__ segstart,
                                             const float* __restrict__ h0,
                                             unsigned short* __restrict__ xcatb,
                                             unsigned short* __restrict__ h0b) {
  int i = blockIdx.x * 256 + threadIdx.x;
  const int n1 = GR * 416;
  if (i < n1) {
    int r = i / 416, c = i % 416;
    float v = 0.f;
    if (r < R2C) {
      if (c < H) v = er[r * H + c];
      else if (c < 2 * H) {
        int cnt = segstart[r + 1] - segstart[r];
        float inv = cnt > 0 ? 1.0f / (float)cnt : 0.0f;
        v = sums[r * H + (c - H)] * inv;
      }
    }
    xcatb[i] = f2bu(v);
  } else {
    int i2 = i - n1;
    if (i2 < GR * 224) {
      int r = i2 / 224, c = i2 % 224;
      float v = (r < R2C && c < H) ? h0[r * H + c] : 0.f;
      h0b[i2] = f2bu(v);
    }
  }
}

// ---------------- generic zero ----------------
__global__ void k_zero_f(float* p, int n) {
  int i = blockIdx.x * 256 + threadIdx.x;
  if (i < n) p[i] = 0.f;
}
__global__ void k_zero_i(int* p, int n) {
  int i = blockIdx.x * 256 + threadIdx.x;
  if (i < n) p[i] = 0;
}

// ---------------- prologue: relation segment bounds for ALL steps ----------------
__global__ __launch_bounds__(512) void k_segbounds4(const int* __restrict__ rseg,
                                                    int* __restrict__ segstart4) {
  const int* rs = rseg + (size_t)blockIdx.x * EC;
  int* out = segstart4 + blockIdx.x * (R2C + 1);
  for (int r = threadIdx.x; r <= R2C; r += 512) {
    int lo = 0, hi = EC;
    while (lo < hi) { int m = (lo + hi) >> 1; if (rs[m] < r) lo = m + 1; else hi = m; }
    out[r] = lo;
  }
}

// ---------------- prologue: CSR build for ALL steps ----------------
__global__ void k_hist4(const int* __restrict__ dst, int* __restrict__ deg4) {
  int e = blockIdx.x * 256 + threadIdx.x;
  if (e < TS * EC) atomicAdd(&deg4[(e / EC) * NE + dst[e]], 1);
}

__global__ __launch_bounds__(256) void k_scan1(const int* __restrict__ deg4,
                                               int* __restrict__ offs4,
                                               int* __restrict__ bsums4) {
  __shared__ int s[256];
  int t = blockIdx.x / NSCAN, blk = blockIdx.x % NSCAN;
  int i = blk * 256 + threadIdx.x;
  int v = (i < NE) ? deg4[t * NE + i] : 0;
  s[threadIdx.x] = v;
  __syncthreads();
  for (int o = 1; o < 256; o <<= 1) {
    int add = (threadIdx.x >= o) ? s[threadIdx.x - o] : 0;
    __syncthreads();
    s[threadIdx.x] += add;
    __syncthreads();
  }
  if (i < NE) offs4[t * (NE + 1) + i] = s[threadIdx.x] - v;  // exclusive
  if (threadIdx.x == 255) bsums4[t * 256 + blk] = s[255];
}

__global__ __launch_bounds__(256) void k_scan2(int* bsums4) {
  __shared__ int s[256];
  int t = blockIdx.x;
  int v = (threadIdx.x < NSCAN) ? bsums4[t * 256 + threadIdx.x] : 0;
  s[threadIdx.x] = v;
  __syncthreads();
  for (int o = 1; o < 256; o <<= 1) {
    int add = (threadIdx.x >= o) ? s[threadIdx.x - o] : 0;
    __syncthreads();
    s[threadIdx.x] += add;
    __syncthreads();
  }
  if (threadIdx.x < NSCAN) bsums4[t * 256 + threadIdx.x] = s[threadIdx.x] - v;  // exclusive
}

__global__ void k_scan3(int* __restrict__ offs4, const int* __restrict__ bsums4,
                        int* __restrict__ cursor4) {
  int t = blockIdx.x / NSCAN, blk = blockIdx.x % NSCAN;
  int i = blk * 256 + threadIdx.x;
  if (i < NE) {
    int o = offs4[t * (NE + 1) + i] + bsums4[t * 256 + blk];
    offs4[t * (NE + 1) + i] = o;
    cursor4[t * NE + i] = o;
  }
  if (blk == 0 && threadIdx.x == 0) offs4[t * (NE + 1) + NE] = EC;
}

// scatter (src,et) payloads into CSR order for all steps
__global__ void k_scatter4(const int* __restrict__ dst, const int* __restrict__ src,
                           const int* __restrict__ et, int* __restrict__ cursor4,
                           int2* __restrict__ se4) {
  int e = blockIdx.x * 256 + threadIdx.x;
  if (e < TS * EC) {
    int t = e / EC;
    int pos = atomicAdd(&cursor4[t * NE + dst[e]], 1);
    se4[(size_t)t * EC + pos] = make_int2(src[e], et[e]);
  }
}

// ---------------- per-step: segment-sum over sorted rseg, gathering bf16 rows of hb ----------------
__global__ __launch_bounds__(256) void k_relsums(const int* __restrict__ rseg,
                                                 const int* __restrict__ rte,
                                                 const unsigned short* __restrict__ hb,
                                                 float* __restrict__ sums) {
  int base = blockIdx.x * RCH;
  int d = threadIdx.x;
  bool act = d < H;
  float a0 = 0.f, a1 = 0.f, a2 = 0.f, a3 = 0.f;
  int prev = rseg[base];
  for (int g = 0; g < RCH; g += 4) {
    int e = base + g;
    int4 sg = *reinterpret_cast<const int4*>(rseg + e);
    int4 rr = *reinterpret_cast<const int4*>(rte + e);
    if (sg.w == prev) {            // sorted => whole group in same segment (uniform branch)
      if (act) {
        a0 += u2f(hb[(size_t)rr.x * KP + d]);
        a1 += u2f(hb[(size_t)rr.y * KP + d]);
        a2 += u2f(hb[(size_t)rr.z * KP + d]);
        a3 += u2f(hb[(size_t)rr.w * KP + d]);
      }
    } else {                       // boundary group (rare): scalar path
      int ss[4] = {sg.x, sg.y, sg.z, sg.w};
      int rr2[4] = {rr.x, rr.y, rr.z, rr.w};
      #pragma unroll
      for (int j = 0; j < 4; j++) {
        if (ss[j] != prev) {
          if (act) atomicAdd(&sums[prev * H + d], a0 + a1 + a2 + a3);
          a0 = a1 = a2 = a3 = 0.f;
          prev = ss[j];
        }
        if (act) a0 += u2f(hb[(size_t)rr2[j] * KP + d]);
      }
    }
  }
  if (act) atomicAdd(&sums[prev * H + d], a0 + a1 + a2 + a3);
}

// ---------------- per-step: GRU GEMMs via MFMA -> gi, gh [512][608] f32 ----------------
__global__ __launch_bounds__(256) void k_grumm(const unsigned short* __restrict__ xcatb,
                                               const unsigned short* __restrict__ h0b,
                                               const unsigned short* __restrict__ bgi,
                                               const unsigned short* __restrict__ bgh,
                                               float* __restrict__ gi_ws,
                                               float* __restrict__ gh_ws) {
  int wid = threadIdx.x >> 6, lane = threadIdx.x & 63;
  int nt   = blockIdx.x % GNT;
  int row0 = (blockIdx.x / GNT) * 64 + wid * 16;
  int arow = row0 + (lane & 15);

  const unsigned short* api = xcatb + (size_t)arow * 416 + (lane >> 4) * 8;
  bf16x8v ai[GKI];
  #pragma unroll
  for (int ks = 0; ks < GKI; ks++)
    ai[ks] = *reinterpret_cast<const bf16x8v*>(api + ks * 32);
  const unsigned short* aph = h0b + (size_t)arow * 224 + (lane >> 4) * 8;
  bf16x8v ah[GKH];
  #pragma unroll
  for (int ks = 0; ks < GKH; ks++)
    ah[ks] = *reinterpret_cast<const bf16x8v*>(aph + ks * 32);

  const unsigned short* bip = bgi + ((size_t)(nt * GKI) * 64 + lane) * 8;
  bf16x8v bi[GKI];
  #pragma unroll
  for (int ks = 0; ks < GKI; ks++)
    bi[ks] = *reinterpret_cast<const bf16x8v*>(bip + (size_t)ks * 64 * 8);
  const unsigned short* bhp = bgh + ((size_t)(nt * GKH) * 64 + lane) * 8;
  bf16x8v bh[GKH];
  #pragma unroll
  for (int ks = 0; ks < GKH; ks++)
    bh[ks] = *reinterpret_cast<const bf16x8v*>(bhp + (size_t)ks * 64 * 8);

  f32x4 a1 = {}, a2 = {};
  #pragma unroll
  for (int ks = 0; ks < GKI; ks++)
    a1 = __builtin_amdgcn_mfma_f32_16x16x32_bf16(ai[ks], bi[ks], a1, 0, 0, 0);
  #pragma unroll
  for (int ks = 0; ks < GKH; ks++)
    a2 = __builtin_amdgcn_mfma_f32_16x16x32_bf16(ah[ks], bh[ks], a2, 0, 0, 0);

  int col = nt * 16 + (lane & 15);
  int rb = row0 + (lane >> 4) * 4;
  #pragma unroll
  for (int q = 0; q < 4; q++) {
    gi_ws[(size_t)(rb + q) * GCS + col] = a1[q];
    gh_ws[(size_t)(rb + q) * GCS + col] = a2[q];
  }
}

// ---------------- per-step: GRU gates + l2norm -> h0 (and h0_out on last step) ----------------
__global__ __launch_bounds__(256) void k_grutail(const float* __restrict__ gi_ws,
                                                 const float* __restrict__ gh_ws,
                                                 const float* __restrict__ b_ih,
                                                 const float* __restrict__ b_hh,
                                                 float* __restrict__ h0,
                                                 float* __restrict__ h0_out) {
  __shared__ float xc[H];
  __shared__ float red[4];
  int r = blockIdx.x;
  int tid = threadIdx.x, wid = tid >> 6, lane = tid & 63;
  float ssp = 0.f;
  for (int d = tid; d < H; d += 256) {
    float gir = gi_ws[(size_t)r * GCS + d]         + b_ih[d];
    float ghr = gh_ws[(size_t)r * GCS + d]         + b_hh[d];
    float giz = gi_ws[(size_t)r * GCS + H + d]     + b_ih[H + d];
    float ghz = gh_ws[(size_t)r * GCS + H + d]     + b_hh[H + d];
    float gin = gi_ws[(size_t)r * GCS + 2 * H + d] + b_ih[2 * H + d];
    float ghn = gh_ws[(size_t)r * GCS + 2 * H + d] + b_hh[2 * H + d];
    float rg = sigmoidf(gir + ghr);
    float z  = sigmoidf(giz + ghz);
    float n  = tanhf(gin + rg * ghn);
    float hv = h0[r * H + d];
    float o  = (1.0f - z) * n + z * hv;
    xc[d] = o;
    ssp += o * o;
  }
  ssp = wave_sum(ssp);
  if (lane == 0) red[wid] = ssp;
  __syncthreads();
  float ss = red[0] + red[1] + red[2] + red[3];
  float sc = 1.0f / fmaxf(sqrtf(ss), 1e-12f);
  for (int d = tid; d < H; d += 256) {
    float o = xc[d] * sc;
    h0[r * H + d] = o;
    if (h0_out) h0_out[r * H + d] = o;
  }
}

// ---------------- per-step: MFMA node GEMMs (hW = h@Wn, tw = sigmoid(h@Tg+b)) ----------------
__global__ __launch_bounds__(256) void k_mfma_gemm(const unsigned short* __restrict__ hb,
                                                   const unsigned short* __restrict__ bpack,
                                                   const float* __restrict__ tgb,
                                                   bf16* __restrict__ hWb,
                                                   bf16* __restrict__ twb) {
  int wid = threadIdx.x >> 6, lane = threadIdx.x & 63;
  int row0 = blockIdx.x * 64 + wid * 16;
  if (row0 >= NE) return;                 // wave-uniform
  int arow = min(row0 + (lane & 15), NE - 1);
  const unsigned short* ap = hb + (size_t)arow * KP + (lane >> 4) * 8;
  bf16x8v a[KS];
  #pragma unroll
  for (int ks = 0; ks < KS; ks++)
    a[ks] = *reinterpret_cast<const bf16x8v*>(ap + ks * 32);

  const unsigned short* b1p = bpack + (size_t)lane * 8;
  const unsigned short* b2p = b1p + (size_t)NT * KS * 64 * 8;
  int colb = lane & 15;
  int rbase = row0 + (lane >> 4) * 4;

  for (int nt = 0; nt < NT; nt++) {
    bf16x8v b1[KS], b2[KS];
    #pragma unroll
    for (int ks = 0; ks < KS; ks++) {
      size_t boff = (size_t)(nt * KS + ks) * 64 * 8;
      b1[ks] = *reinterpret_cast<const bf16x8v*>(b1p + boff);
      b2[ks] = *reinterpret_cast<const bf16x8v*>(b2p + boff);
    }
    f32x4 acc1 = {}, acc2 = {};
    #pragma unroll
    for (int ks = 0; ks < KS; ks++) {
      acc1 = __builtin_amdgcn_mfma_f32_16x16x32_bf16(a[ks], b1[ks], acc1, 0, 0, 0);
      acc2 = __builtin_amdgcn_mfma_f32_16x16x32_bf16(a[ks], b2[ks], acc2, 0, 0, 0);
    }
    int col = nt * 16 + colb;
    bool cok = (col < H);
    float bias = cok ? tgb[col] : 0.f;
    #pragma unroll
    for (int q = 0; q < 4; q++) {
      int row = rbase + q;
      if (cok && row < NE) {
        hWb[(size_t)row * H + col] = f2b(acc1[q]);
        twb[(size_t)row * H + col] = f2b(sigmoidf(acc2[q] + bias));
      }
    }
  }
}

// ---------------- per-step: aggregate + rrelu + l2norm + time gate + l2norm ----------------
// fused; also emits next step's bf16 hb (padded) when hbnext != null.
__global__ __launch_bounds__(256) void k_aggfin(const int* __restrict__ offs,
                                                const int2* __restrict__ se,
                                                const bf16* __restrict__ hWb,
                                                const float* __restrict__ relW,
                                                const bf16* __restrict__ twb,
                                                float* __restrict__ h,
                                                float* __restrict__ evolve,
                                                unsigned short* __restrict__ hbnext) {
  int wid = threadIdx.x >> 6, lane = threadIdx.x & 63;
  int i = blockIdx.x * 4 + wid;
  if (i >= NE) return;
  int s0 = offs[i], s1 = offs[i + 1];
  int d0 = lane * 4;
  bool act = d0 < H;
  const unsigned short* hw = (const unsigned short*)hWb;
  float a0 = 0.f, a1 = 0.f, a2 = 0.f, a3 = 0.f;

  int p = s0;
  for (; p + 4 <= s1; p += 4) {
    int2 e0 = se[p], e1 = se[p + 1], e2 = se[p + 2], e3 = se[p + 3];
    if (act) {
      ushort4 m0 = *reinterpret_cast<const ushort4*>(hw + (size_t)e0.x * H + d0);
      ushort4 m1 = *reinterpret_cast<const ushort4*>(hw + (size_t)e1.x * H + d0);
      ushort4 m2 = *reinterpret_cast<const ushort4*>(hw + (size_t)e2.x * H + d0);
      ushort4 m3 = *reinterpret_cast<const ushort4*>(hw + (size_t)e3.x * H + d0);
      float4 r0 = *reinterpret_cast<const float4*>(relW + (size_t)e0.y * H + d0);
      float4 r1 = *reinterpret_cast<const float4*>(relW + (size_t)e1.y * H + d0);
      float4 r2 = *reinterpret_cast<const float4*>(relW + (size_t)e2.y * H + d0);
      float4 r3 = *reinterpret_cast<const float4*>(relW + (size_t)e3.y * H + d0);
      a0 += u2f(m0.x) + r0.x + u2f(m1.x) + r1.x + u2f(m2.x) + r2.x + u2f(m3.x) + r3.x;
      a1 += u2f(m0.y) + r0.y + u2f(m1.y) + r1.y + u2f(m2.y) + r2.y + u2f(m3.y) + r3.y;
      a2 += u2f(m0.z) + r0.z + u2f(m1.z) + r1.z + u2f(m2.z) + r2.z + u2f(m3.z) + r3.z;
      a3 += u2f(m0.w) + r0.w + u2f(m1.w) + r1.w + u2f(m2.w) + r2.w + u2f(m3.w) + r3.w;
    }
  }
  for (; p < s1; p++) {
    int2 e0 = se[p];
    if (act) {
      ushort4 m0 = *reinterpret_cast<const ushort4*>(hw + (size_t)e0.x * H + d0);
      float4 r0 = *reinterpret_cast<const float4*>(relW + (size_t)e0.y * H + d0);
      a0 += u2f(m0.x) + r0.x;
      a1 += u2f(m0.y) + r0.y;
      a2 += u2f(m0.z) + r0.z;
      a3 += u2f(m0.w) + r0.w;
    }
  }

  int deg = s1 - s0;
  float nrm = deg > 0 ? 1.0f / (float)deg : 0.0f;
  float c0 = a0 * nrm; c0 = c0 >= 0.f ? c0 : SLOPE * c0;
  float c1 = a1 * nrm; c1 = c1 >= 0.f ? c1 : SLOPE * c1;
  float c2 = a2 * nrm; c2 = c2 >= 0.f ? c2 : SLOPE * c2;
  float c3 = a3 * nrm; c3 = c3 >= 0.f ? c3 : SLOPE * c3;
  float ss = act ? (c0 * c0 + c1 * c1 + c2 * c2 + c3 * c3) : 0.f;
  ss = wave_sum(ss);
  float sc = 1.0f / fmaxf(sqrtf(ss), 1e-12f);
  c0 *= sc; c1 *= sc; c2 *= sc; c3 *= sc;

  // time gate + combine + l2norm
  float v0 = 0.f, v1 = 0.f, v2 = 0.f, v3 = 0.f;
  if (act) {
    ushort4 t4 = *reinterpret_cast<const ushort4*>((const unsigned short*)twb + (size_t)i * H + d0);
    float4 hv = *reinterpret_cast<const float4*>(h + (size_t)i * H + d0);
    float t0 = u2f(t4.x), t1 = u2f(t4.y), t2 = u2f(t4.z), t3 = u2f(t4.w);
    v0 = t0 * c0 + (1.0f - t0) * hv.x;
    v1 = t1 * c1 + (1.0f - t1) * hv.y;
    v2 = t2 * c2 + (1.0f - t2) * hv.z;
    v3 = t3 * c3 + (1.0f - t3) * hv.w;
  }
  float ss2 = v0 * v0 + v1 * v1 + v2 * v2 + v3 * v3;
  ss2 = wave_sum(ss2);
  float sc2 = 1.0f / fmaxf(sqrtf(ss2), 1e-12f);
  if (act) {
    float4 o = make_float4(v0 * sc2, v1 * sc2, v2 * sc2, v3 * sc2);
    *reinterpret_cast<float4*>(h + (size_t)i * H + d0) = o;
    *reinterpret_cast<float4*>(evolve + (size_t)i * H + d0) = o;
    if (hbnext) {
      ushort4 ob; ob.x = f2bu(o.x); ob.y = f2bu(o.y); ob.z = f2bu(o.z); ob.w = f2bu(o.w);
      *reinterpret_cast<ushort4*>(hbnext + (size_t)i * KP + d0) = ob;
    }
  } else if (d0 < KP && hbnext) {
    ushort4 z; z.x = z.y = z.z = z.w = 0;
    *reinterpret_cast<ushort4*>(hbnext + (size_t)i * KP + d0) = z;
  }
}

extern "C" void kernel_launch(void* const* d_in, const int* in_sizes, int n_in,
                              void* d_out, int out_size, void* d_ws, size_t ws_size,
                              hipStream_t stream) {
  const float* de  = (const float*)d_in[0];
  const float* er  = (const float*)d_in[1];
  const float* wih = (const float*)d_in[2];
  const float* whh = (const float*)d_in[3];
  const float* bih = (const float*)d_in[4];
  const float* bhh = (const float*)d_in[5];
  const float* wn  = (const float*)d_in[6];
  const float* tg  = (const float*)d_in[7];
  const float* tgb = (const float*)d_in[8];
  const int* src  = (const int*)d_in[9];
  const int* dst  = (const int*)d_in[10];
  const int* et   = (const int*)d_in[11];
  const int* rte  = (const int*)d_in[12];
  const int* rseg = (const int*)d_in[13];

  char* w = (char*)d_ws;
  auto alloc = [&](size_t bytes) -> char* {
    char* p = w;
    w += (bytes + 255) / 256 * 256;
    return p;
  };
  float* h     = (float*)alloc(sizeof(float) * (size_t)NE * H);   // 40 MB
  bf16*  hWb   = (bf16*) alloc(sizeof(bf16)  * (size_t)NE * H);   // 20 MB
  bf16*  twb   = (bf16*) alloc(sizeof(bf16)  * (size_t)NE * H);   // 20 MB
  float* relW  = (float*)alloc(sizeof(float) * R2C * H);
  float* h0    = (float*)alloc(sizeof(float) * R2C * H);
  float* sums  = (float*)alloc(sizeof(float) * R2C * H);
  unsigned short* bpack = (unsigned short*)alloc(sizeof(unsigned short) * 2 * NT * KS * 64 * 8); // 186 KB
  unsigned short* bgi   = (unsigned short*)alloc(sizeof(unsigned short) * GNT * GKI * 64 * 8);   // 506 KB
  unsigned short* bgh   = (unsigned short*)alloc(sizeof(unsigned short) * GNT * GKH * 64 * 8);   // 272 KB
  unsigned short* xcatb = (unsigned short*)alloc(sizeof(unsigned short) * GR * 416);             // 416 KB
  unsigned short* h0b   = (unsigned short*)alloc(sizeof(unsigned short) * GR * 224);             // 224 KB
  float* gi_ws = (float*)alloc(sizeof(float) * GR * GCS);          // 1.24 MB
  float* gh_ws = (float*)alloc(sizeof(float) * GR * GCS);          // 1.24 MB
  int* segstart4 = (int*)alloc(sizeof(int) * TS * (R2C + 1));
  int* deg4    = (int*) alloc(sizeof(int) * TS * NE);              // 800 KB
  int* offs4   = (int*) alloc(sizeof(int) * TS * (NE + 1));        // 800 KB
  int* cursor4 = (int*) alloc(sizeof(int) * TS * NE);              // 800 KB
  int2* se4    = (int2*)alloc(sizeof(int2) * (size_t)TS * EC);     // 12.8 MB
  int* bsums4  = (int*) alloc(sizeof(int) * TS * 256);
  (void)ws_size; (void)in_sizes; (void)n_in; (void)out_size;

  float* out    = (float*)d_out;
  float* evolve = out;                       // [TS, NE, H]
  float* h0out  = out + (size_t)TS * NE * H; // [R2C, H]

  const int gRow4  = (NE + 3) / 4;          // 12500
  const int gRel   = (R2C * H + 255) / 256; // 391
  const int gPack  = (2 * NT * KS * 64 + 255) / 256;       // 46
  const int gPackG = (GNT * (GKI + GKH) * 64 + 255) / 256; // 190
  const int gA2b   = (GR * 416 + GR * 224 + 255) / 256;    // 1280
  const int gGemm  = (NE + 63) / 64;                       // 782
  const int gGru   = 8 * GNT;                              // 304
  const int gRelsum= EC / RCH;                             // 3125
  const int gE4    = (TS * EC + 255) / 256;                // 6250
  const int gZ4    = (TS * NE + 255) / 256;                // 782

  // ---- prologue: init + weight packs + all-step CSR / segment bounds ----
  k_init_h<<<gRow4, 256, 0, stream>>>(de, h, (unsigned short*)evolve);  // hb0 in evolve[0] slot
  k_init_h0<<<gRel, 256, 0, stream>>>(er, h0);
  k_relw<<<R2C, 256, 0, stream>>>(er, wn, relW);
  k_packb<<<gPack, 256, 0, stream>>>(wn, tg, bpack);
  k_packgru<<<gPackG, 256, 0, stream>>>(wih, whh, bgi, bgh);
  k_segbounds4<<<TS, 512, 0, stream>>>(rseg, segstart4);
  k_zero_i<<<gZ4, 256, 0, stream>>>(deg4, TS * NE);
  k_hist4<<<gE4, 256, 0, stream>>>(dst, deg4);
  k_scan1<<<TS * NSCAN, 256, 0, stream>>>(deg4, offs4, bsums4);
  k_scan2<<<TS, 256, 0, stream>>>(bsums4);
  k_scan3<<<TS * NSCAN, 256, 0, stream>>>(offs4, bsums4, cursor4);
  k_scatter4<<<gE4, 256, 0, stream>>>(dst, src, et, cursor4, se4);

  for (int t = 0; t < TS; t++) {
    const int* rseg_t = rseg + (size_t)t * EC;
    const int* rte_t  = rte  + (size_t)t * EC;
    float* evo_t = evolve + (size_t)t * NE * H;
    // hb(t) lives in the evolve[t] slot (written by k_init_h for t=0, else by
    // the previous step's k_aggfin); it is dead before k_aggfin overwrites it.
    unsigned short* hb = (unsigned short*)evo_t;
    unsigned short* hbnext = (t < TS - 1) ? (unsigned short*)(evolve + (size_t)(t + 1) * NE * H)
                                          : (unsigned short*)nullptr;

    // relation-segment means + GRU via MFMA (uses pre-step h, h0)
    k_zero_f<<<gRel, 256, 0, stream>>>(sums, R2C * H);
    k_relsums<<<gRelsum, 256, 0, stream>>>(rseg_t, rte_t, hb, sums);
    k_a2b<<<gA2b, 256, 0, stream>>>(er, sums, segstart4 + t * (R2C + 1), h0, xcatb, h0b);
    k_grumm<<<gGru, 256, 0, stream>>>(xcatb, h0b, bgi, bgh, gi_ws, gh_ws);
    k_grutail<<<R2C, 256, 0, stream>>>(gi_ws, gh_ws, bih, bhh,
                                       h0, (t == TS - 1) ? h0out : (float*)nullptr);

    // node GEMMs via MFMA (pre-step h)
    k_mfma_gemm<<<gGemm, 256, 0, stream>>>(hb, bpack, tgb, hWb, twb);

    // fused aggregate + rrelu + l2norm + time gate + combine + l2norm
    // -> writes h (in place), evolve[t], and next step's hb
    k_aggfin<<<gRow4, 256, 0, stream>>>(offs4 + t * (NE + 1), se4 + (size_t)t * EC,
                                        hWb, relW, twb, h, evo_t, hbnext);
  }
}

// Round 10
// 774.080 us; speedup vs baseline: 6.3240x; 1.0806x over previous
//
#include <hip/hip_runtime.h>
#include <hip/hip_bf16.h>

using bf16 = __hip_bfloat16;

constexpr int NE  = 50000;   // entities
constexpr int H   = 200;     // hidden dim
constexpr int R2C = 500;     // 2*num_rels
constexpr int TS  = 4;       // timesteps
constexpr int EC  = 400000;  // edges per step
constexpr float SLOPE = 0.22916666666666666f;  // rrelu eval slope
constexpr int NSCAN = (NE + 255) / 256;        // 196

// node-GEMM MFMA geometry
constexpr int KP = 224;      // K padded to 7*32
constexpr int KS = 7;        // k-steps of 32
constexpr int NT = 13;       // n-tiles of 16

// GRU-GEMM MFMA geometry (out [512][608])
constexpr int GNT = 38;      // n-tiles (608/16)
constexpr int GKI = 13;      // k-steps for W_ih (416/32)
constexpr int GKH = 7;       // k-steps for W_hh (224/32)
constexpr int GR  = 512;     // padded relation rows
constexpr int GCS = 608;     // padded gate cols (stride)

constexpr int RCH = 64;      // edges per block in k_relsums

#define DEVINL __device__ __forceinline__

typedef __bf16 bf16x8v __attribute__((ext_vector_type(8)));
typedef float  f32x4   __attribute__((ext_vector_type(4)));

DEVINL float b2f(bf16 v) { return __bfloat162float(v); }
DEVINL bf16  f2b(float v) { return __float2bfloat16(v); }
DEVINL unsigned short f2bu(float x) { bf16 b = f2b(x); return *reinterpret_cast<unsigned short*>(&b); }
DEVINL float u2f(unsigned short u) { unsigned int w = (unsigned int)u << 16; float f; __builtin_memcpy(&f, &w, 4); return f; }

DEVINL float wave_sum(float v) {
  #pragma unroll
  for (int o = 32; o > 0; o >>= 1) v += __shfl_xor(v, o, 64);
  return v;
}

DEVINL float sigmoidf(float x) { return 1.0f / (1.0f + expf(-x)); }

// ---------------- init: l2norm rows of dynamic_emb -> h (f32) AND hb0 (bf16 padded) ----------------
__global__ __launch_bounds__(256) void k_init_h(const float* __restrict__ de,
                                                float* __restrict__ h,
                                                unsigned short* __restrict__ hb0) {
  int wid = threadIdx.x >> 6, lane = threadIdx.x & 63;
  int row = blockIdx.x * 4 + wid;
  if (row >= NE) return;
  int d0 = lane * 4;
  bool act = d0 < H;
  float4 v = make_float4(0.f, 0.f, 0.f, 0.f);
  if (act) v = *reinterpret_cast<const float4*>(de + (size_t)row * H + d0);
  float ss = v.x * v.x + v.y * v.y + v.z * v.z + v.w * v.w;
  ss = wave_sum(ss);
  float sc = 1.0f / fmaxf(sqrtf(ss), 1e-12f);
  if (act) {
    float4 o = make_float4(v.x * sc, v.y * sc, v.z * sc, v.w * sc);
    *reinterpret_cast<float4*>(h + (size_t)row * H + d0) = o;
    ushort4 ob; ob.x = f2bu(o.x); ob.y = f2bu(o.y); ob.z = f2bu(o.z); ob.w = f2bu(o.w);
    *reinterpret_cast<ushort4*>(hb0 + (size_t)row * KP + d0) = ob;
  } else if (d0 < KP) {
    ushort4 z; z.x = z.y = z.z = z.w = 0;
    *reinterpret_cast<ushort4*>(hb0 + (size_t)row * KP + d0) = z;
  }
}

__global__ __launch_bounds__(256) void k_init_h0(const float* er, float* h0) {
  int i = blockIdx.x * 256 + threadIdx.x;
  if (i < R2C * H) h0[i] = er[i];
}

// relW = emb_rel @ W_n   [R2C, H]
__global__ __launch_bounds__(256) void k_relw(const float* er, const float* wn, float* relW) {
  __shared__ float a[H];
  int r = blockIdx.x;
  for (int d = threadIdx.x; d < H; d += 256) a[d] = er[r * H + d];
  __syncthreads();
  for (int c = threadIdx.x; c < H; c += 256) {
    float s = 0.f;
    for (int k = 0; k < H; k++) s += a[k] * wn[k * H + c];
    relW[r * H + c] = s;
  }
}

// pack Wn and Tg into per-lane MFMA B-fragment order, zero-padded to [KP][NP].
__global__ __launch_bounds__(256) void k_packb(const float* wn, const float* tg,
                                               unsigned short* bpack) {
  int t = blockIdx.x * 256 + threadIdx.x;
  int total = 2 * NT * KS * 64;
  if (t >= total) return;
  int m    = t / (NT * KS * 64);
  int rem  = t % (NT * KS * 64);
  int nt   = rem / (KS * 64);
  int rem2 = rem % (KS * 64);
  int ks   = rem2 / 64, lane = rem2 % 64;
  const float* W = m ? tg : wn;
  int n = nt * 16 + (lane & 15);
  unsigned short out[8];
  #pragma unroll
  for (int j = 0; j < 8; j++) {
    int k = ks * 32 + (lane >> 4) * 8 + j;
    float v = (k < H && n < H) ? W[k * H + n] : 0.f;
    out[j] = f2bu(v);
  }
  unsigned short* dst = bpack + (size_t)t * 8;
  #pragma unroll
  for (int j = 0; j < 8; j++) dst[j] = out[j];
}

// pack W_ih [600,400] and W_hh [600,200] (row-major [n][k]) into B-frag order
__global__ __launch_bounds__(256) void k_packgru(const float* __restrict__ wih,
                                                 const float* __restrict__ whh,
                                                 unsigned short* __restrict__ bgi,
                                                 unsigned short* __restrict__ bgh) {
  int t = blockIdx.x * 256 + threadIdx.x;
  const int tot_i = GNT * GKI * 64;
  const int tot_h = GNT * GKH * 64;
  if (t < tot_i) {
    int nt = t / (GKI * 64);
    int rem = t % (GKI * 64);
    int ks = rem / 64, lane = rem % 64;
    int n = nt * 16 + (lane & 15);
    unsigned short o[8];
    #pragma unroll
    for (int j = 0; j < 8; j++) {
      int k = ks * 32 + (lane >> 4) * 8 + j;
      o[j] = (n < 3 * H && k < 2 * H) ? f2bu(wih[n * (2 * H) + k]) : (unsigned short)0;
    }
    unsigned short* dstp = bgi + (size_t)t * 8;
    #pragma unroll
    for (int j = 0; j < 8; j++) dstp[j] = o[j];
  } else if (t < tot_i + tot_h) {
    int t2 = t - tot_i;
    int nt = t2 / (GKH * 64);
    int rem = t2 % (GKH * 64);
    int ks = rem / 64, lane = rem % 64;
    int n = nt * 16 + (lane & 15);
    unsigned short o[8];
    #pragma unroll
    for (int j = 0; j < 8; j++) {
      int k = ks * 32 + (lane >> 4) * 8 + j;
      o[j] = (n < 3 * H && k < H) ? f2bu(whh[n * H + k]) : (unsigned short)0;
    }
    unsigned short* dstp = bgh + (size_t)t2 * 8;
    #pragma unroll
    for (int j = 0; j < 8; j++) dstp[j] = o[j];
  }
}

// build GRU A-matrices: xcatb [512][416] = [emb_rel | seg-mean], h0b [512][224]
__global__ __launch_bounds__(256) void k_a2b(const float* __restrict__ er,
                                             const float* __restrict__ sums,
                                             const int* __restrict__ segstart,
                                             const float* __restrict__ h0,
                                             unsigned short* __restrict__ xcatb,
                                             unsigned short* __restrict__ h0b) {
  int i = blockIdx.x * 256 + threadIdx.x;
  const int n1 = GR * 416;
  if (i < n1) {
    int r = i / 416, c = i % 416;
    float v = 0.f;
    if (r < R2C) {
      if (c < H) v = er[r * H + c];
      else if (c < 2 * H) {
        int cnt = segstart[r + 1] - segstart[r];
        float inv = cnt > 0 ? 1.0f / (float)cnt : 0.0f;
        v = sums[r * H + (c - H)] * inv;
      }
    }
    xcatb[i] = f2bu(v);
  } else {
    int i2 = i - n1;
    if (i2 < GR * 224) {
      int r = i2 / 224, c = i2 % 224;
      float v = (r < R2C && c < H) ? h0[r * H + c] : 0.f;
      h0b[i2] = f2bu(v);
    }
  }
}

// ---------------- generic zero ----------------
__global__ void k_zero_f(float* p, int n) {
  int i = blockIdx.x * 256 + threadIdx.x;
  if (i < n) p[i] = 0.f;
}
__global__ void k_zero_i(int* p, int n) {
  int i = blockIdx.x * 256 + threadIdx.x;
  if (i < n) p[i] = 0;
}

// ---------------- prologue: relation segment bounds for ALL steps ----------------
__global__ __launch_bounds__(512) void k_segbounds4(const int* __restrict__ rseg,
                                                    int* __restrict__ segstart4) {
  const int* rs = rseg + (size_t)blockIdx.x * EC;
  int* out = segstart4 + blockIdx.x * (R2C + 1);
  for (int r = threadIdx.x; r <= R2C; r += 512) {
    int lo = 0, hi = EC;
    while (lo < hi) { int m = (lo + hi) >> 1; if (rs[m] < r) lo = m + 1; else hi = m; }
    out[r] = lo;
  }
}

// ---------------- prologue: CSR build for ALL steps (ILP-4) ----------------
__global__ void k_hist4(const int* __restrict__ dst, int* __restrict__ deg4) {
  int base = (blockIdx.x * 256 + threadIdx.x) * 4;
  if (base + 3 < TS * EC) {
    int4 d4 = *reinterpret_cast<const int4*>(dst + base);
    int t = base / EC;   // EC%4==0, base%4==0 -> whole quad in one step
    atomicAdd(&deg4[t * NE + d4.x], 1);
    atomicAdd(&deg4[t * NE + d4.y], 1);
    atomicAdd(&deg4[t * NE + d4.z], 1);
    atomicAdd(&deg4[t * NE + d4.w], 1);
  }
}

__global__ __launch_bounds__(256) void k_scan1(const int* __restrict__ deg4,
                                               int* __restrict__ offs4,
                                               int* __restrict__ bsums4) {
  __shared__ int s[256];
  int t = blockIdx.x / NSCAN, blk = blockIdx.x % NSCAN;
  int i = blk * 256 + threadIdx.x;
  int v = (i < NE) ? deg4[t * NE + i] : 0;
  s[threadIdx.x] = v;
  __syncthreads();
  for (int o = 1; o < 256; o <<= 1) {
    int add = (threadIdx.x >= o) ? s[threadIdx.x - o] : 0;
    __syncthreads();
    s[threadIdx.x] += add;
    __syncthreads();
  }
  if (i < NE) offs4[t * (NE + 1) + i] = s[threadIdx.x] - v;  // exclusive
  if (threadIdx.x == 255) bsums4[t * 256 + blk] = s[255];
}

__global__ __launch_bounds__(256) void k_scan2(int* bsums4) {
  __shared__ int s[256];
  int t = blockIdx.x;
  int v = (threadIdx.x < NSCAN) ? bsums4[t * 256 + threadIdx.x] : 0;
  s[threadIdx.x] = v;
  __syncthreads();
  for (int o = 1; o < 256; o <<= 1) {
    int add = (threadIdx.x >= o) ? s[threadIdx.x - o] : 0;
    __syncthreads();
    s[threadIdx.x] += add;
    __syncthreads();
  }
  if (threadIdx.x < NSCAN) bsums4[t * 256 + threadIdx.x] = s[threadIdx.x] - v;  // exclusive
}

__global__ void k_scan3(int* __restrict__ offs4, const int* __restrict__ bsums4,
                        int* __restrict__ cursor4) {
  int t = blockIdx.x / NSCAN, blk = blockIdx.x % NSCAN;
  int i = blk * 256 + threadIdx.x;
  if (i < NE) {
    int o = offs4[t * (NE + 1) + i] + bsums4[t * 256 + blk];
    offs4[t * (NE + 1) + i] = o;
    cursor4[t * NE + i] = o;
  }
  if (blk == 0 && threadIdx.x == 0) offs4[t * (NE + 1) + NE] = EC;
}

// scatter packed (et<<16)|src payloads into CSR order for all steps (ILP-4)
__global__ void k_scatter4(const int* __restrict__ dst, const int* __restrict__ src,
                           const int* __restrict__ et, int* __restrict__ cursor4,
                           unsigned int* __restrict__ se4) {
  int base = (blockIdx.x * 256 + threadIdx.x) * 4;
  if (base + 3 < TS * EC) {
    int4 d4 = *reinterpret_cast<const int4*>(dst + base);
    int4 s4 = *reinterpret_cast<const int4*>(src + base);
    int4 e4 = *reinterpret_cast<const int4*>(et + base);
    int t = base / EC;
    int* cur = cursor4 + t * NE;
    unsigned int* se = se4 + (size_t)t * EC;
    int p0 = atomicAdd(&cur[d4.x], 1);
    int p1 = atomicAdd(&cur[d4.y], 1);
    int p2 = atomicAdd(&cur[d4.z], 1);
    int p3 = atomicAdd(&cur[d4.w], 1);
    se[p0] = (unsigned int)s4.x | ((unsigned int)e4.x << 16);
    se[p1] = (unsigned int)s4.y | ((unsigned int)e4.y << 16);
    se[p2] = (unsigned int)s4.z | ((unsigned int)e4.z << 16);
    se[p3] = (unsigned int)s4.w | ((unsigned int)e4.w << 16);
  }
}

// ---------------- per-step: segment-sum over sorted rseg (ILP-8, bf16 gather) ----------------
__global__ __launch_bounds__(256) void k_relsums(const int* __restrict__ rseg,
                                                 const int* __restrict__ rte,
                                                 const unsigned short* __restrict__ hb,
                                                 float* __restrict__ sums) {
  int base = blockIdx.x * RCH;
  int d = threadIdx.x;
  bool act = d < H;
  float a0 = 0.f, a1 = 0.f, a2 = 0.f, a3 = 0.f;
  int prev = rseg[base];
  for (int g = 0; g < RCH; g += 8) {
    int e = base + g;
    int4 sgA = *reinterpret_cast<const int4*>(rseg + e);
    int4 sgB = *reinterpret_cast<const int4*>(rseg + e + 4);
    int4 rrA = *reinterpret_cast<const int4*>(rte + e);
    int4 rrB = *reinterpret_cast<const int4*>(rte + e + 4);
    if (sgB.w == prev) {           // sorted => whole group of 8 in same segment
      if (act) {
        float v0 = u2f(hb[(size_t)rrA.x * KP + d]);
        float v1 = u2f(hb[(size_t)rrA.y * KP + d]);
        float v2 = u2f(hb[(size_t)rrA.z * KP + d]);
        float v3 = u2f(hb[(size_t)rrA.w * KP + d]);
        float v4 = u2f(hb[(size_t)rrB.x * KP + d]);
        float v5 = u2f(hb[(size_t)rrB.y * KP + d]);
        float v6 = u2f(hb[(size_t)rrB.z * KP + d]);
        float v7 = u2f(hb[(size_t)rrB.w * KP + d]);
        a0 += v0; a1 += v1; a2 += v2; a3 += v3;   // same mod-4 association as before
        a0 += v4; a1 += v5; a2 += v6; a3 += v7;
      }
    } else {                       // boundary group (rare): scalar path
      int ss[8] = {sgA.x, sgA.y, sgA.z, sgA.w, sgB.x, sgB.y, sgB.z, sgB.w};
      int rr[8] = {rrA.x, rrA.y, rrA.z, rrA.w, rrB.x, rrB.y, rrB.z, rrB.w};
      #pragma unroll
      for (int j = 0; j < 8; j++) {
        if (ss[j] != prev) {
          if (act) atomicAdd(&sums[prev * H + d], a0 + a1 + a2 + a3);
          a0 = a1 = a2 = a3 = 0.f;
          prev = ss[j];
        }
        if (act) a0 += u2f(hb[(size_t)rr[j] * KP + d]);
      }
    }
  }
  if (act) atomicAdd(&sums[prev * H + d], a0 + a1 + a2 + a3);
}

// ---------------- per-step: GRU GEMMs via MFMA -> gi, gh [512][608] f32 ----------------
__global__ __launch_bounds__(256) void k_grumm(const unsigned short* __restrict__ xcatb,
                                               const unsigned short* __restrict__ h0b,
                                               const unsigned short* __restrict__ bgi,
                                               const unsigned short* __restrict__ bgh,
                                               float* __restrict__ gi_ws,
                                               float* __restrict__ gh_ws) {
  int wid = threadIdx.x >> 6, lane = threadIdx.x & 63;
  int nt   = blockIdx.x % GNT;
  int row0 = (blockIdx.x / GNT) * 64 + wid * 16;
  int arow = row0 + (lane & 15);

  const unsigned short* api = xcatb + (size_t)arow * 416 + (lane >> 4) * 8;
  bf16x8v ai[GKI];
  #pragma unroll
  for (int ks = 0; ks < GKI; ks++)
    ai[ks] = *reinterpret_cast<const bf16x8v*>(api + ks * 32);
  const unsigned short* aph = h0b + (size_t)arow * 224 + (lane >> 4) * 8;
  bf16x8v ah[GKH];
  #pragma unroll
  for (int ks = 0; ks < GKH; ks++)
    ah[ks] = *reinterpret_cast<const bf16x8v*>(aph + ks * 32);

  const unsigned short* bip = bgi + ((size_t)(nt * GKI) * 64 + lane) * 8;
  bf16x8v bi[GKI];
  #pragma unroll
  for (int ks = 0; ks < GKI; ks++)
    bi[ks] = *reinterpret_cast<const bf16x8v*>(bip + (size_t)ks * 64 * 8);
  const unsigned short* bhp = bgh + ((size_t)(nt * GKH) * 64 + lane) * 8;
  bf16x8v bh[GKH];
  #pragma unroll
  for (int ks = 0; ks < GKH; ks++)
    bh[ks] = *reinterpret_cast<const bf16x8v*>(bhp + (size_t)ks * 64 * 8);

  f32x4 a1 = {}, a2 = {};
  #pragma unroll
  for (int ks = 0; ks < GKI; ks++)
    a1 = __builtin_amdgcn_mfma_f32_16x16x32_bf16(ai[ks], bi[ks], a1, 0, 0, 0);
  #pragma unroll
  for (int ks = 0; ks < GKH; ks++)
    a2 = __builtin_amdgcn_mfma_f32_16x16x32_bf16(ah[ks], bh[ks], a2, 0, 0, 0);

  int col = nt * 16 + (lane & 15);
  int rb = row0 + (lane >> 4) * 4;
  #pragma unroll
  for (int q = 0; q < 4; q++) {
    gi_ws[(size_t)(rb + q) * GCS + col] = a1[q];
    gh_ws[(size_t)(rb + q) * GCS + col] = a2[q];
  }
}

// ---------------- per-step: GRU gates + l2norm -> h0 (and h0_out on last step) ----------------
__global__ __launch_bounds__(256) void k_grutail(const float* __restrict__ gi_ws,
                                                 const float* __restrict__ gh_ws,
                                                 const float* __restrict__ b_ih,
                                                 const float* __restrict__ b_hh,
                                                 float* __restrict__ h0,
                                                 float* __restrict__ h0_out) {
  __shared__ float xc[H];
  __shared__ float red[4];
  int r = blockIdx.x;
  int tid = threadIdx.x, wid = tid >> 6, lane = tid & 63;
  float ssp = 0.f;
  for (int d = tid; d < H; d += 256) {
    float gir = gi_ws[(size_t)r * GCS + d]         + b_ih[d];
    float ghr = gh_ws[(size_t)r * GCS + d]         + b_hh[d];
    float giz = gi_ws[(size_t)r * GCS + H + d]     + b_ih[H + d];
    float ghz = gh_ws[(size_t)r * GCS + H + d]     + b_hh[H + d];
    float gin = gi_ws[(size_t)r * GCS + 2 * H + d] + b_ih[2 * H + d];
    float ghn = gh_ws[(size_t)r * GCS + 2 * H + d] + b_hh[2 * H + d];
    float rg = sigmoidf(gir + ghr);
    float z  = sigmoidf(giz + ghz);
    float n  = tanhf(gin + rg * ghn);
    float hv = h0[r * H + d];
    float o  = (1.0f - z) * n + z * hv;
    xc[d] = o;
    ssp += o * o;
  }
  ssp = wave_sum(ssp);
  if (lane == 0) red[wid] = ssp;
  __syncthreads();
  float ss = red[0] + red[1] + red[2] + red[3];
  float sc = 1.0f / fmaxf(sqrtf(ss), 1e-12f);
  for (int d = tid; d < H; d += 256) {
    float o = xc[d] * sc;
    h0[r * H + d] = o;
    if (h0_out) h0_out[r * H + d] = o;
  }
}

// ---------------- per-step: MFMA node GEMMs (hW = h@Wn, tw = sigmoid(h@Tg+b)) ----------------
__global__ __launch_bounds__(256) void k_mfma_gemm(const unsigned short* __restrict__ hb,
                                                   const unsigned short* __restrict__ bpack,
                                                   const float* __restrict__ tgb,
                                                   bf16* __restrict__ hWb,
                                                   bf16* __restrict__ twb) {
  int wid = threadIdx.x >> 6, lane = threadIdx.x & 63;
  int row0 = blockIdx.x * 64 + wid * 16;
  if (row0 >= NE) return;                 // wave-uniform
  int arow = min(row0 + (lane & 15), NE - 1);
  const unsigned short* ap = hb + (size_t)arow * KP + (lane >> 4) * 8;
  bf16x8v a[KS];
  #pragma unroll
  for (int ks = 0; ks < KS; ks++)
    a[ks] = *reinterpret_cast<const bf16x8v*>(ap + ks * 32);

  const unsigned short* b1p = bpack + (size_t)lane * 8;
  const unsigned short* b2p = b1p + (size_t)NT * KS * 64 * 8;
  int colb = lane & 15;
  int rbase = row0 + (lane >> 4) * 4;

  for (int nt = 0; nt < NT; nt++) {
    bf16x8v b1[KS], b2[KS];
    #pragma unroll
    for (int ks = 0; ks < KS; ks++) {
      size_t boff = (size_t)(nt * KS + ks) * 64 * 8;
      b1[ks] = *reinterpret_cast<const bf16x8v*>(b1p + boff);
      b2[ks] = *reinterpret_cast<const bf16x8v*>(b2p + boff);
    }
    f32x4 acc1 = {}, acc2 = {};
    #pragma unroll
    for (int ks = 0; ks < KS; ks++) {
      acc1 = __builtin_amdgcn_mfma_f32_16x16x32_bf16(a[ks], b1[ks], acc1, 0, 0, 0);
      acc2 = __builtin_amdgcn_mfma_f32_16x16x32_bf16(a[ks], b2[ks], acc2, 0, 0, 0);
    }
    int col = nt * 16 + colb;
    bool cok = (col < H);
    float bias = cok ? tgb[col] : 0.f;
    #pragma unroll
    for (int q = 0; q < 4; q++) {
      int row = rbase + q;
      if (cok && row < NE) {
        hWb[(size_t)row * H + col] = f2b(acc1[q]);
        twb[(size_t)row * H + col] = f2b(sigmoidf(acc2[q] + bias));
      }
    }
  }
}

// ---------------- per-step: aggregate + rrelu + l2norm + time gate + l2norm ----------------
// fused; also emits next step's bf16 hb (padded) when hbnext != null.
__global__ __launch_bounds__(256) void k_aggfin(const int* __restrict__ offs,
                                                const unsigned int* __restrict__ se,
                                                const bf16* __restrict__ hWb,
                                                const float* __restrict__ relW,
                                                const bf16* __restrict__ twb,
                                                float* __restrict__ h,
                                                float* __restrict__ evolve,
                                                unsigned short* __restrict__ hbnext) {
  int wid = threadIdx.x >> 6, lane = threadIdx.x & 63;
  int i = blockIdx.x * 4 + wid;
  if (i >= NE) return;
  int s0 = offs[i], s1 = offs[i + 1];
  int d0 = lane * 4;
  bool act = d0 < H;
  const unsigned short* hw = (const unsigned short*)hWb;
  float a0 = 0.f, a1 = 0.f, a2 = 0.f, a3 = 0.f;

  int p = s0;
  for (; p + 4 <= s1; p += 4) {
    unsigned int e0 = se[p], e1 = se[p + 1], e2 = se[p + 2], e3 = se[p + 3];
    if (act) {
      ushort4 m0 = *reinterpret_cast<const ushort4*>(hw + (size_t)(e0 & 0xFFFFu) * H + d0);
      ushort4 m1 = *reinterpret_cast<const ushort4*>(hw + (size_t)(e1 & 0xFFFFu) * H + d0);
      ushort4 m2 = *reinterpret_cast<const ushort4*>(hw + (size_t)(e2 & 0xFFFFu) * H + d0);
      ushort4 m3 = *reinterpret_cast<const ushort4*>(hw + (size_t)(e3 & 0xFFFFu) * H + d0);
      float4 r0 = *reinterpret_cast<const float4*>(relW + (size_t)(e0 >> 16) * H + d0);
      float4 r1 = *reinterpret_cast<const float4*>(relW + (size_t)(e1 >> 16) * H + d0);
      float4 r2 = *reinterpret_cast<const float4*>(relW + (size_t)(e2 >> 16) * H + d0);
      float4 r3 = *reinterpret_cast<const float4*>(relW + (size_t)(e3 >> 16) * H + d0);
      a0 += u2f(m0.x) + r0.x + u2f(m1.x) + r1.x + u2f(m2.x) + r2.x + u2f(m3.x) + r3.x;
      a1 += u2f(m0.y) + r0.y + u2f(m1.y) + r1.y + u2f(m2.y) + r2.y + u2f(m3.y) + r3.y;
      a2 += u2f(m0.z) + r0.z + u2f(m1.z) + r1.z + u2f(m2.z) + r2.z + u2f(m3.z) + r3.z;
      a3 += u2f(m0.w) + r0.w + u2f(m1.w) + r1.w + u2f(m2.w) + r2.w + u2f(m3.w) + r3.w;
    }
  }
  for (; p < s1; p++) {
    unsigned int e0 = se[p];
    if (act) {
      ushort4 m0 = *reinterpret_cast<const ushort4*>(hw + (size_t)(e0 & 0xFFFFu) * H + d0);
      float4 r0 = *reinterpret_cast<const float4*>(relW + (size_t)(e0 >> 16) * H + d0);
      a0 += u2f(m0.x) + r0.x;
      a1 += u2f(m0.y) + r0.y;
      a2 += u2f(m0.z) + r0.z;
      a3 += u2f(m0.w) + r0.w;
    }
  }

  int deg = s1 - s0;
  float nrm = deg > 0 ? 1.0f / (float)deg : 0.0f;
  float c0 = a0 * nrm; c0 = c0 >= 0.f ? c0 : SLOPE * c0;
  float c1 = a1 * nrm; c1 = c1 >= 0.f ? c1 : SLOPE * c1;
  float c2 = a2 * nrm; c2 = c2 >= 0.f ? c2 : SLOPE * c2;
  float c3 = a3 * nrm; c3 = c3 >= 0.f ? c3 : SLOPE * c3;
  float ss = act ? (c0 * c0 + c1 * c1 + c2 * c2 + c3 * c3) : 0.f;
  ss = wave_sum(ss);
  float sc = 1.0f / fmaxf(sqrtf(ss), 1e-12f);
  c0 *= sc; c1 *= sc; c2 *= sc; c3 *= sc;

  // time gate + combine + l2norm
  float v0 = 0.f, v1 = 0.f, v2 = 0.f, v3 = 0.f;
  if (act) {
    ushort4 t4 = *reinterpret_cast<const ushort4*>((const unsigned short*)twb + (size_t)i * H + d0);
    float4 hv = *reinterpret_cast<const float4*>(h + (size_t)i * H + d0);
    float t0 = u2f(t4.x), t1 = u2f(t4.y), t2 = u2f(t4.z), t3 = u2f(t4.w);
    v0 = t0 * c0 + (1.0f - t0) * hv.x;
    v1 = t1 * c1 + (1.0f - t1) * hv.y;
    v2 = t2 * c2 + (1.0f - t2) * hv.z;
    v3 = t3 * c3 + (1.0f - t3) * hv.w;
  }
  float ss2 = v0 * v0 + v1 * v1 + v2 * v2 + v3 * v3;
  ss2 = wave_sum(ss2);
  float sc2 = 1.0f / fmaxf(sqrtf(ss2), 1e-12f);
  if (act) {
    float4 o = make_float4(v0 * sc2, v1 * sc2, v2 * sc2, v3 * sc2);
    *reinterpret_cast<float4*>(h + (size_t)i * H + d0) = o;
    *reinterpret_cast<float4*>(evolve + (size_t)i * H + d0) = o;
    if (hbnext) {
      ushort4 ob; ob.x = f2bu(o.x); ob.y = f2bu(o.y); ob.z = f2bu(o.z); ob.w = f2bu(o.w);
      *reinterpret_cast<ushort4*>(hbnext + (size_t)i * KP + d0) = ob;
    }
  } else if (d0 < KP && hbnext) {
    ushort4 z; z.x = z.y = z.z = z.w = 0;
    *reinterpret_cast<ushort4*>(hbnext + (size_t)i * KP + d0) = z;
  }
}

extern "C" void kernel_launch(void* const* d_in, const int* in_sizes, int n_in,
                              void* d_out, int out_size, void* d_ws, size_t ws_size,
                              hipStream_t stream) {
  const float* de  = (const float*)d_in[0];
  const float* er  = (const float*)d_in[1];
  const float* wih = (const float*)d_in[2];
  const float* whh = (const float*)d_in[3];
  const float* bih = (const float*)d_in[4];
  const float* bhh = (const float*)d_in[5];
  const float* wn  = (const float*)d_in[6];
  const float* tg  = (const float*)d_in[7];
  const float* tgb = (const float*)d_in[8];
  const int* src  = (const int*)d_in[9];
  const int* dst  = (const int*)d_in[10];
  const int* et   = (const int*)d_in[11];
  const int* rte  = (const int*)d_in[12];
  const int* rseg = (const int*)d_in[13];

  char* w = (char*)d_ws;
  auto alloc = [&](size_t bytes) -> char* {
    char* p = w;
    w += (bytes + 255) / 256 * 256;
    return p;
  };
  float* h     = (float*)alloc(sizeof(float) * (size_t)NE * H);   // 40 MB
  bf16*  hWb   = (bf16*) alloc(sizeof(bf16)  * (size_t)NE * H);   // 20 MB
  bf16*  twb   = (bf16*) alloc(sizeof(bf16)  * (size_t)NE * H);   // 20 MB
  float* relW  = (float*)alloc(sizeof(float) * R2C * H);
  float* h0    = (float*)alloc(sizeof(float) * R2C * H);
  float* sums  = (float*)alloc(sizeof(float) * R2C * H);
  unsigned short* bpack = (unsigned short*)alloc(sizeof(unsigned short) * 2 * NT * KS * 64 * 8); // 186 KB
  unsigned short* bgi   = (unsigned short*)alloc(sizeof(unsigned short) * GNT * GKI * 64 * 8);   // 506 KB
  unsigned short* bgh   = (unsigned short*)alloc(sizeof(unsigned short) * GNT * GKH * 64 * 8);   // 272 KB
  unsigned short* xcatb = (unsigned short*)alloc(sizeof(unsigned short) * GR * 416);             // 416 KB
  unsigned short* h0b   = (unsigned short*)alloc(sizeof(unsigned short) * GR * 224);             // 224 KB
  float* gi_ws = (float*)alloc(sizeof(float) * GR * GCS);          // 1.24 MB
  float* gh_ws = (float*)alloc(sizeof(float) * GR * GCS);          // 1.24 MB
  int* segstart4 = (int*)alloc(sizeof(int) * TS * (R2C + 1));
  int* deg4    = (int*) alloc(sizeof(int) * TS * NE);              // 800 KB
  int* offs4   = (int*) alloc(sizeof(int) * TS * (NE + 1));        // 800 KB
  int* cursor4 = (int*) alloc(sizeof(int) * TS * NE);              // 800 KB
  unsigned int* se4 = (unsigned int*)alloc(sizeof(unsigned int) * (size_t)TS * EC); // 6.4 MB
  int* bsums4  = (int*) alloc(sizeof(int) * TS * 256);
  (void)ws_size; (void)in_sizes; (void)n_in; (void)out_size;

  float* out    = (float*)d_out;
  float* evolve = out;                       // [TS, NE, H]
  float* h0out  = out + (size_t)TS * NE * H; // [R2C, H]

  const int gRow4  = (NE + 3) / 4;          // 12500
  const int gRel   = (R2C * H + 255) / 256; // 391
  const int gPack  = (2 * NT * KS * 64 + 255) / 256;       // 46
  const int gPackG = (GNT * (GKI + GKH) * 64 + 255) / 256; // 190
  const int gA2b   = (GR * 416 + GR * 224 + 255) / 256;    // 1280
  const int gGemm  = (NE + 63) / 64;                       // 782
  const int gGru   = 8 * GNT;                              // 304
  const int gRelsum= EC / RCH;                             // 6250
  const int gE4i   = (TS * EC / 4 + 255) / 256;            // 1563
  const int gZ4    = (TS * NE + 255) / 256;                // 782

  // ---- prologue: init + weight packs + all-step CSR / segment bounds ----
  k_init_h<<<gRow4, 256, 0, stream>>>(de, h, (unsigned short*)evolve);  // hb0 in evolve[0] slot
  k_init_h0<<<gRel, 256, 0, stream>>>(er, h0);
  k_relw<<<R2C, 256, 0, stream>>>(er, wn, relW);
  k_packb<<<gPack, 256, 0, stream>>>(wn, tg, bpack);
  k_packgru<<<gPackG, 256, 0, stream>>>(wih, whh, bgi, bgh);
  k_segbounds4<<<TS, 512, 0, stream>>>(rseg, segstart4);
  k_zero_i<<<gZ4, 256, 0, stream>>>(deg4, TS * NE);
  k_hist4<<<gE4i, 256, 0, stream>>>(dst, deg4);
  k_scan1<<<TS * NSCAN, 256, 0, stream>>>(deg4, offs4, bsums4);
  k_scan2<<<TS, 256, 0, stream>>>(bsums4);
  k_scan3<<<TS * NSCAN, 256, 0, stream>>>(offs4, bsums4, cursor4);
  k_scatter4<<<gE4i, 256, 0, stream>>>(dst, src, et, cursor4, se4);

  for (int t = 0; t < TS; t++) {
    const int* rseg_t = rseg + (size_t)t * EC;
    const int* rte_t  = rte  + (size_t)t * EC;
    float* evo_t = evolve + (size_t)t * NE * H;
    // hb(t) lives in the evolve[t] slot (written by k_init_h for t=0, else by
    // the previous step's k_aggfin); it is dead before k_aggfin overwrites it.
    unsigned short* hb = (unsigned short*)evo_t;
    unsigned short* hbnext = (t < TS - 1) ? (unsigned short*)(evolve + (size_t)(t + 1) * NE * H)
                                          : (unsigned short*)nullptr;

    // relation-segment means + GRU via MFMA (uses pre-step h, h0)
    k_zero_f<<<gRel, 256, 0, stream>>>(sums, R2C * H);
    k_relsums<<<gRelsum, 256, 0, stream>>>(rseg_t, rte_t, hb, sums);
    k_a2b<<<gA2b, 256, 0, stream>>>(er, sums, segstart4 + t * (R2C + 1), h0, xcatb, h0b);
    k_grumm<<<gGru, 256, 0, stream>>>(xcatb, h0b, bgi, bgh, gi_ws, gh_ws);
    k_grutail<<<R2C, 256, 0, stream>>>(gi_ws, gh_ws, bih, bhh,
                                       h0, (t == TS - 1) ? h0out : (float*)nullptr);

    // node GEMMs via MFMA (pre-step h)
    k_mfma_gemm<<<gGemm, 256, 0, stream>>>(hb, bpack, tgb, hWb, twb);

    // fused aggregate + rrelu + l2norm + time gate + combine + l2norm
    // -> writes h (in place), evolve[t], and next step's hb
    k_aggfin<<<gRow4, 256, 0, stream>>>(offs4 + t * (NE + 1), se4 + (size_t)t * EC,
                                        hWb, relW, twb, h, evo_t, hbnext);
  }
}

// Round 11
// 728.789 us; speedup vs baseline: 6.7170x; 1.0621x over previous
//
#include <hip/hip_runtime.h>
#include <hip/hip_bf16.h>

using bf16 = __hip_bfloat16;

constexpr int NE  = 50000;   // entities
constexpr int H   = 200;     // hidden dim
constexpr int R2C = 500;     // 2*num_rels
constexpr int TS  = 4;       // timesteps
constexpr int EC  = 400000;  // edges per step
constexpr float SLOPE = 0.22916666666666666f;  // rrelu eval slope
constexpr int NSCAN = (NE + 255) / 256;        // 196

// node-GEMM MFMA geometry
constexpr int KP = 224;      // K padded to 7*32
constexpr int KS = 7;        // k-steps of 32
constexpr int NT = 13;       // n-tiles of 16

// GRU-GEMM MFMA geometry (out [512][608])
constexpr int GNT = 38;      // n-tiles (608/16)
constexpr int GKI = 13;      // k-steps for W_ih (416/32)
constexpr int GKH = 7;       // k-steps for W_hh (224/32)
constexpr int GR  = 512;     // padded relation rows
constexpr int GCS = 608;     // padded gate cols (stride)

constexpr int RCH = 64;      // edges per block in k_relsums
constexpr int NRNG = 8;      // dst ranges (≈ XCD count); NE/NRNG = 6250
constexpr int DRNG = NE / NRNG;              // 6250
constexpr int SCHK = 1024;   // edges per scatter chunk
constexpr int NCHK = (EC + SCHK - 1) / SCHK; // 391

#define DEVINL __device__ __forceinline__

typedef __bf16 bf16x8v __attribute__((ext_vector_type(8)));
typedef float  f32x4   __attribute__((ext_vector_type(4)));

DEVINL float b2f(bf16 v) { return __bfloat162float(v); }
DEVINL bf16  f2b(float v) { return __float2bfloat16(v); }
DEVINL unsigned short f2bu(float x) { bf16 b = f2b(x); return *reinterpret_cast<unsigned short*>(&b); }
DEVINL float u2f(unsigned short u) { unsigned int w = (unsigned int)u << 16; float f; __builtin_memcpy(&f, &w, 4); return f; }

DEVINL float wave_sum(float v) {
  #pragma unroll
  for (int o = 32; o > 0; o >>= 1) v += __shfl_xor(v, o, 64);
  return v;
}

DEVINL float sigmoidf(float x) { return 1.0f / (1.0f + expf(-x)); }

// ---------------- init: l2norm rows of dynamic_emb -> h (f32) AND hb0 (bf16 padded) ----------------
__global__ __launch_bounds__(256) void k_init_h(const float* __restrict__ de,
                                                float* __restrict__ h,
                                                unsigned short* __restrict__ hb0) {
  int wid = threadIdx.x >> 6, lane = threadIdx.x & 63;
  int row = blockIdx.x * 4 + wid;
  if (row >= NE) return;
  int d0 = lane * 4;
  bool act = d0 < H;
  float4 v = make_float4(0.f, 0.f, 0.f, 0.f);
  if (act) v = *reinterpret_cast<const float4*>(de + (size_t)row * H + d0);
  float ss = v.x * v.x + v.y * v.y + v.z * v.z + v.w * v.w;
  ss = wave_sum(ss);
  float sc = 1.0f / fmaxf(sqrtf(ss), 1e-12f);
  if (act) {
    float4 o = make_float4(v.x * sc, v.y * sc, v.z * sc, v.w * sc);
    *reinterpret_cast<float4*>(h + (size_t)row * H + d0) = o;
    ushort4 ob; ob.x = f2bu(o.x); ob.y = f2bu(o.y); ob.z = f2bu(o.z); ob.w = f2bu(o.w);
    *reinterpret_cast<ushort4*>(hb0 + (size_t)row * KP + d0) = ob;
  } else if (d0 < KP) {
    ushort4 z; z.x = z.y = z.z = z.w = 0;
    *reinterpret_cast<ushort4*>(hb0 + (size_t)row * KP + d0) = z;
  }
}

__global__ __launch_bounds__(256) void k_init_h0(const float* er, float* h0) {
  int i = blockIdx.x * 256 + threadIdx.x;
  if (i < R2C * H) h0[i] = er[i];
}

// relW = emb_rel @ W_n   [R2C, H]
__global__ __launch_bounds__(256) void k_relw(const float* er, const float* wn, float* relW) {
  __shared__ float a[H];
  int r = blockIdx.x;
  for (int d = threadIdx.x; d < H; d += 256) a[d] = er[r * H + d];
  __syncthreads();
  for (int c = threadIdx.x; c < H; c += 256) {
    float s = 0.f;
    for (int k = 0; k < H; k++) s += a[k] * wn[k * H + c];
    relW[r * H + c] = s;
  }
}

// pack Wn and Tg into per-lane MFMA B-fragment order, zero-padded to [KP][NP].
__global__ __launch_bounds__(256) void k_packb(const float* wn, const float* tg,
                                               unsigned short* bpack) {
  int t = blockIdx.x * 256 + threadIdx.x;
  int total = 2 * NT * KS * 64;
  if (t >= total) return;
  int m    = t / (NT * KS * 64);
  int rem  = t % (NT * KS * 64);
  int nt   = rem / (KS * 64);
  int rem2 = rem % (KS * 64);
  int ks   = rem2 / 64, lane = rem2 % 64;
  const float* W = m ? tg : wn;
  int n = nt * 16 + (lane & 15);
  unsigned short out[8];
  #pragma unroll
  for (int j = 0; j < 8; j++) {
    int k = ks * 32 + (lane >> 4) * 8 + j;
    float v = (k < H && n < H) ? W[k * H + n] : 0.f;
    out[j] = f2bu(v);
  }
  unsigned short* dst = bpack + (size_t)t * 8;
  #pragma unroll
  for (int j = 0; j < 8; j++) dst[j] = out[j];
}

// pack W_ih [600,400] and W_hh [600,200] (row-major [n][k]) into B-frag order
__global__ __launch_bounds__(256) void k_packgru(const float* __restrict__ wih,
                                                 const float* __restrict__ whh,
                                                 unsigned short* __restrict__ bgi,
                                                 unsigned short* __restrict__ bgh) {
  int t = blockIdx.x * 256 + threadIdx.x;
  const int tot_i = GNT * GKI * 64;
  const int tot_h = GNT * GKH * 64;
  if (t < tot_i) {
    int nt = t / (GKI * 64);
    int rem = t % (GKI * 64);
    int ks = rem / 64, lane = rem % 64;
    int n = nt * 16 + (lane & 15);
    unsigned short o[8];
    #pragma unroll
    for (int j = 0; j < 8; j++) {
      int k = ks * 32 + (lane >> 4) * 8 + j;
      o[j] = (n < 3 * H && k < 2 * H) ? f2bu(wih[n * (2 * H) + k]) : (unsigned short)0;
    }
    unsigned short* dstp = bgi + (size_t)t * 8;
    #pragma unroll
    for (int j = 0; j < 8; j++) dstp[j] = o[j];
  } else if (t < tot_i + tot_h) {
    int t2 = t - tot_i;
    int nt = t2 / (GKH * 64);
    int rem = t2 % (GKH * 64);
    int ks = rem / 64, lane = rem % 64;
    int n = nt * 16 + (lane & 15);
    unsigned short o[8];
    #pragma unroll
    for (int j = 0; j < 8; j++) {
      int k = ks * 32 + (lane >> 4) * 8 + j;
      o[j] = (n < 3 * H && k < H) ? f2bu(whh[n * H + k]) : (unsigned short)0;
    }
    unsigned short* dstp = bgh + (size_t)t2 * 8;
    #pragma unroll
    for (int j = 0; j < 8; j++) dstp[j] = o[j];
  }
}

// build GRU A-matrices: xcatb [512][416] = [emb_rel | seg-mean], h0b [512][224]
__global__ __launch_bounds__(256) void k_a2b(const float* __restrict__ er,
                                             const float* __restrict__ sums,
                                             const int* __restrict__ segstart,
                                             const float* __restrict__ h0,
                                             unsigned short* __restrict__ xcatb,
                                             unsigned short* __restrict__ h0b) {
  int i = blockIdx.x * 256 + threadIdx.x;
  const int n1 = GR * 416;
  if (i < n1) {
    int r = i / 416, c = i % 416;
    float v = 0.f;
    if (r < R2C) {
      if (c < H) v = er[r * H + c];
      else if (c < 2 * H) {
        int cnt = segstart[r + 1] - segstart[r];
        float inv = cnt > 0 ? 1.0f / (float)cnt : 0.0f;
        v = sums[r * H + (c - H)] * inv;
      }
    }
    xcatb[i] = f2bu(v);
  } else {
    int i2 = i - n1;
    if (i2 < GR * 224) {
      int r = i2 / 224, c = i2 % 224;
      float v = (r < R2C && c < H) ? h0[r * H + c] : 0.f;
      h0b[i2] = f2bu(v);
    }
  }
}

// ---------------- generic zero ----------------
__global__ void k_zero_f(float* p, int n) {
  int i = blockIdx.x * 256 + threadIdx.x;
  if (i < n) p[i] = 0.f;
}
__global__ void k_zero_i(int* p, int n) {
  int i = blockIdx.x * 256 + threadIdx.x;
  if (i < n) p[i] = 0;
}

// ---------------- prologue: relation segment bounds for ALL steps ----------------
__global__ __launch_bounds__(512) void k_segbounds4(const int* __restrict__ rseg,
                                                    int* __restrict__ segstart4) {
  const int* rs = rseg + (size_t)blockIdx.x * EC;
  int* out = segstart4 + blockIdx.x * (R2C + 1);
  for (int r = threadIdx.x; r <= R2C; r += 512) {
    int lo = 0, hi = EC;
    while (lo < hi) { int m = (lo + hi) >> 1; if (rs[m] < r) lo = m + 1; else hi = m; }
    out[r] = lo;
  }
}

// ---------------- prologue: CSR build for ALL steps (ILP-4) ----------------
__global__ void k_hist4(const int* __restrict__ dst, int* __restrict__ deg4) {
  int base = (blockIdx.x * 256 + threadIdx.x) * 4;
  if (base + 3 < TS * EC) {
    int4 d4 = *reinterpret_cast<const int4*>(dst + base);
    int t = base / EC;   // EC%4==0, base%4==0 -> whole quad in one step
    atomicAdd(&deg4[t * NE + d4.x], 1);
    atomicAdd(&deg4[t * NE + d4.y], 1);
    atomicAdd(&deg4[t * NE + d4.z], 1);
    atomicAdd(&deg4[t * NE + d4.w], 1);
  }
}

__global__ __launch_bounds__(256) void k_scan1(const int* __restrict__ deg4,
                                               int* __restrict__ offs4,
                                               int* __restrict__ bsums4) {
  __shared__ int s[256];
  int t = blockIdx.x / NSCAN, blk = blockIdx.x % NSCAN;
  int i = blk * 256 + threadIdx.x;
  int v = (i < NE) ? deg4[t * NE + i] : 0;
  s[threadIdx.x] = v;
  __syncthreads();
  for (int o = 1; o < 256; o <<= 1) {
    int add = (threadIdx.x >= o) ? s[threadIdx.x - o] : 0;
    __syncthreads();
    s[threadIdx.x] += add;
    __syncthreads();
  }
  if (i < NE) offs4[t * (NE + 1) + i] = s[threadIdx.x] - v;  // exclusive
  if (threadIdx.x == 255) bsums4[t * 256 + blk] = s[255];
}

__global__ __launch_bounds__(256) void k_scan2(int* bsums4) {
  __shared__ int s[256];
  int t = blockIdx.x;
  int v = (threadIdx.x < NSCAN) ? bsums4[t * 256 + threadIdx.x] : 0;
  s[threadIdx.x] = v;
  __syncthreads();
  for (int o = 1; o < 256; o <<= 1) {
    int add = (threadIdx.x >= o) ? s[threadIdx.x - o] : 0;
    __syncthreads();
    s[threadIdx.x] += add;
    __syncthreads();
  }
  if (threadIdx.x < NSCAN) bsums4[t * 256 + threadIdx.x] = s[threadIdx.x] - v;  // exclusive
}

__global__ void k_scan3(int* __restrict__ offs4, const int* __restrict__ bsums4,
                        int* __restrict__ cursor4) {
  int t = blockIdx.x / NSCAN, blk = blockIdx.x % NSCAN;
  int i = blk * 256 + threadIdx.x;
  if (i < NE) {
    int o = offs4[t * (NE + 1) + i] + bsums4[t * 256 + blk];
    offs4[t * (NE + 1) + i] = o;
    cursor4[t * NE + i] = o;
  }
  if (blk == 0 && threadIdx.x == 0) offs4[t * (NE + 1) + NE] = EC;
}

// dst-range-partitioned scatter: blockIdx&7 selects dst range [r*6250,(r+1)*6250)
// so all writes to a given se/cursor line come from one XCD (round-robin
// dispatch heuristic) -> L2 assembles full lines, ~1x writeback instead of ~15x.
__global__ void k_scatter8(const int* __restrict__ dst, const int* __restrict__ src,
                           const int* __restrict__ et, int* __restrict__ cursor4,
                           unsigned int* __restrict__ se4) {
  int r = blockIdx.x & (NRNG - 1);
  int rest = blockIdx.x >> 3;
  int t = rest % TS;
  int chunk = rest / TS;
  int li = chunk * SCHK + threadIdx.x * 4;
  if (li >= EC) return;                     // EC%4==0 so full quad when li<EC
  int base = t * EC + li;
  int4 d4 = *reinterpret_cast<const int4*>(dst + base);
  int4 s4 = *reinterpret_cast<const int4*>(src + base);
  int4 e4 = *reinterpret_cast<const int4*>(et + base);
  int* cur = cursor4 + t * NE;
  unsigned int* se = se4 + (size_t)t * EC;
  if ((unsigned)d4.x / DRNG == (unsigned)r) {
    int p = atomicAdd(&cur[d4.x], 1);
    se[p] = (unsigned int)s4.x | ((unsigned int)e4.x << 16);
  }
  if ((unsigned)d4.y / DRNG == (unsigned)r) {
    int p = atomicAdd(&cur[d4.y], 1);
    se[p] = (unsigned int)s4.y | ((unsigned int)e4.y << 16);
  }
  if ((unsigned)d4.z / DRNG == (unsigned)r) {
    int p = atomicAdd(&cur[d4.z], 1);
    se[p] = (unsigned int)s4.z | ((unsigned int)e4.z << 16);
  }
  if ((unsigned)d4.w / DRNG == (unsigned)r) {
    int p = atomicAdd(&cur[d4.w], 1);
    se[p] = (unsigned int)s4.w | ((unsigned int)e4.w << 16);
  }
}

// ---------------- per-step: segment-sum over sorted rseg (ILP-8, bf16 gather) ----------------
__global__ __launch_bounds__(256) void k_relsums(const int* __restrict__ rseg,
                                                 const int* __restrict__ rte,
                                                 const unsigned short* __restrict__ hb,
                                                 float* __restrict__ sums) {
  int base = blockIdx.x * RCH;
  int d = threadIdx.x;
  bool act = d < H;
  float a0 = 0.f, a1 = 0.f, a2 = 0.f, a3 = 0.f;
  int prev = rseg[base];
  for (int g = 0; g < RCH; g += 8) {
    int e = base + g;
    int4 sgA = *reinterpret_cast<const int4*>(rseg + e);
    int4 sgB = *reinterpret_cast<const int4*>(rseg + e + 4);
    int4 rrA = *reinterpret_cast<const int4*>(rte + e);
    int4 rrB = *reinterpret_cast<const int4*>(rte + e + 4);
    if (sgB.w == prev) {           // sorted => whole group of 8 in same segment
      if (act) {
        float v0 = u2f(hb[(size_t)rrA.x * KP + d]);
        float v1 = u2f(hb[(size_t)rrA.y * KP + d]);
        float v2 = u2f(hb[(size_t)rrA.z * KP + d]);
        float v3 = u2f(hb[(size_t)rrA.w * KP + d]);
        float v4 = u2f(hb[(size_t)rrB.x * KP + d]);
        float v5 = u2f(hb[(size_t)rrB.y * KP + d]);
        float v6 = u2f(hb[(size_t)rrB.z * KP + d]);
        float v7 = u2f(hb[(size_t)rrB.w * KP + d]);
        a0 += v0; a1 += v1; a2 += v2; a3 += v3;   // same mod-4 association as before
        a0 += v4; a1 += v5; a2 += v6; a3 += v7;
      }
    } else {                       // boundary group (rare): scalar path
      int ss[8] = {sgA.x, sgA.y, sgA.z, sgA.w, sgB.x, sgB.y, sgB.z, sgB.w};
      int rr[8] = {rrA.x, rrA.y, rrA.z, rrA.w, rrB.x, rrB.y, rrB.z, rrB.w};
      #pragma unroll
      for (int j = 0; j < 8; j++) {
        if (ss[j] != prev) {
          if (act) atomicAdd(&sums[prev * H + d], a0 + a1 + a2 + a3);
          a0 = a1 = a2 = a3 = 0.f;
          prev = ss[j];
        }
        if (act) a0 += u2f(hb[(size_t)rr[j] * KP + d]);
      }
    }
  }
  if (act) atomicAdd(&sums[prev * H + d], a0 + a1 + a2 + a3);
}

// ---------------- per-step: GRU GEMMs via MFMA -> gi, gh [512][608] f32 ----------------
__global__ __launch_bounds__(256) void k_grumm(const unsigned short* __restrict__ xcatb,
                                               const unsigned short* __restrict__ h0b,
                                               const unsigned short* __restrict__ bgi,
                                               const unsigned short* __restrict__ bgh,
                                               float* __restrict__ gi_ws,
                                               float* __restrict__ gh_ws) {
  int wid = threadIdx.x >> 6, lane = threadIdx.x & 63;
  int nt   = blockIdx.x % GNT;
  int row0 = (blockIdx.x / GNT) * 64 + wid * 16;
  int arow = row0 + (lane & 15);

  const unsigned short* api = xcatb + (size_t)arow * 416 + (lane >> 4) * 8;
  bf16x8v ai[GKI];
  #pragma unroll
  for (int ks = 0; ks < GKI; ks++)
    ai[ks] = *reinterpret_cast<const bf16x8v*>(api + ks * 32);
  const unsigned short* aph = h0b + (size_t)arow * 224 + (lane >> 4) * 8;
  bf16x8v ah[GKH];
  #pragma unroll
  for (int ks = 0; ks < GKH; ks++)
    ah[ks] = *reinterpret_cast<const bf16x8v*>(aph + ks * 32);

  const unsigned short* bip = bgi + ((size_t)(nt * GKI) * 64 + lane) * 8;
  bf16x8v bi[GKI];
  #pragma unroll
  for (int ks = 0; ks < GKI; ks++)
    bi[ks] = *reinterpret_cast<const bf16x8v*>(bip + (size_t)ks * 64 * 8);
  const unsigned short* bhp = bgh + ((size_t)(nt * GKH) * 64 + lane) * 8;
  bf16x8v bh[GKH];
  #pragma unroll
  for (int ks = 0; ks < GKH; ks++)
    bh[ks] = *reinterpret_cast<const bf16x8v*>(bhp + (size_t)ks * 64 * 8);

  f32x4 a1 = {}, a2 = {};
  #pragma unroll
  for (int ks = 0; ks < GKI; ks++)
    a1 = __builtin_amdgcn_mfma_f32_16x16x32_bf16(ai[ks], bi[ks], a1, 0, 0, 0);
  #pragma unroll
  for (int ks = 0; ks < GKH; ks++)
    a2 = __builtin_amdgcn_mfma_f32_16x16x32_bf16(ah[ks], bh[ks], a2, 0, 0, 0);

  int col = nt * 16 + (lane & 15);
  int rb = row0 + (lane >> 4) * 4;
  #pragma unroll
  for (int q = 0; q < 4; q++) {
    gi_ws[(size_t)(rb + q) * GCS + col] = a1[q];
    gh_ws[(size_t)(rb + q) * GCS + col] = a2[q];
  }
}

// ---------------- per-step: GRU gates + l2norm -> h0 (and h0_out on last step) ----------------
__global__ __launch_bounds__(256) void k_grutail(const float* __restrict__ gi_ws,
                                                 const float* __restrict__ gh_ws,
                                                 const float* __restrict__ b_ih,
                                                 const float* __restrict__ b_hh,
                                                 float* __restrict__ h0,
                                                 float* __restrict__ h0_out) {
  __shared__ float xc[H];
  __shared__ float red[4];
  int r = blockIdx.x;
  int tid = threadIdx.x, wid = tid >> 6, lane = tid & 63;
  float ssp = 0.f;
  for (int d = tid; d < H; d += 256) {
    float gir = gi_ws[(size_t)r * GCS + d]         + b_ih[d];
    float ghr = gh_ws[(size_t)r * GCS + d]         + b_hh[d];
    float giz = gi_ws[(size_t)r * GCS + H + d]     + b_ih[H + d];
    float ghz = gh_ws[(size_t)r * GCS + H + d]     + b_hh[H + d];
    float gin = gi_ws[(size_t)r * GCS + 2 * H + d] + b_ih[2 * H + d];
    float ghn = gh_ws[(size_t)r * GCS + 2 * H + d] + b_hh[2 * H + d];
    float rg = sigmoidf(gir + ghr);
    float z  = sigmoidf(giz + ghz);
    float n  = tanhf(gin + rg * ghn);
    float hv = h0[r * H + d];
    float o  = (1.0f - z) * n + z * hv;
    xc[d] = o;
    ssp += o * o;
  }
  ssp = wave_sum(ssp);
  if (lane == 0) red[wid] = ssp;
  __syncthreads();
  float ss = red[0] + red[1] + red[2] + red[3];
  float sc = 1.0f / fmaxf(sqrtf(ss), 1e-12f);
  for (int d = tid; d < H; d += 256) {
    float o = xc[d] * sc;
    h0[r * H + d] = o;
    if (h0_out) h0_out[r * H + d] = o;
  }
}

// ---------------- per-step: MFMA node GEMMs (hW = h@Wn, tw = sigmoid(h@Tg+b)) ----------------
__global__ __launch_bounds__(256) void k_mfma_gemm(const unsigned short* __restrict__ hb,
                                                   const unsigned short* __restrict__ bpack,
                                                   const float* __restrict__ tgb,
                                                   bf16* __restrict__ hWb,
                                                   bf16* __restrict__ twb) {
  int wid = threadIdx.x >> 6, lane = threadIdx.x & 63;
  int row0 = blockIdx.x * 64 + wid * 16;
  if (row0 >= NE) return;                 // wave-uniform
  int arow = min(row0 + (lane & 15), NE - 1);
  const unsigned short* ap = hb + (size_t)arow * KP + (lane >> 4) * 8;
  bf16x8v a[KS];
  #pragma unroll
  for (int ks = 0; ks < KS; ks++)
    a[ks] = *reinterpret_cast<const bf16x8v*>(ap + ks * 32);

  const unsigned short* b1p = bpack + (size_t)lane * 8;
  const unsigned short* b2p = b1p + (size_t)NT * KS * 64 * 8;
  int colb = lane & 15;
  int rbase = row0 + (lane >> 4) * 4;

  for (int nt = 0; nt < NT; nt++) {
    bf16x8v b1[KS], b2[KS];
    #pragma unroll
    for (int ks = 0; ks < KS; ks++) {
      size_t boff = (size_t)(nt * KS + ks) * 64 * 8;
      b1[ks] = *reinterpret_cast<const bf16x8v*>(b1p + boff);
      b2[ks] = *reinterpret_cast<const bf16x8v*>(b2p + boff);
    }
    f32x4 acc1 = {}, acc2 = {};
    #pragma unroll
    for (int ks = 0; ks < KS; ks++) {
      acc1 = __builtin_amdgcn_mfma_f32_16x16x32_bf16(a[ks], b1[ks], acc1, 0, 0, 0);
      acc2 = __builtin_amdgcn_mfma_f32_16x16x32_bf16(a[ks], b2[ks], acc2, 0, 0, 0);
    }
    int col = nt * 16 + colb;
    bool cok = (col < H);
    float bias = cok ? tgb[col] : 0.f;
    #pragma unroll
    for (int q = 0; q < 4; q++) {
      int row = rbase + q;
      if (cok && row < NE) {
        hWb[(size_t)row * H + col] = f2b(acc1[q]);
        twb[(size_t)row * H + col] = f2b(sigmoidf(acc2[q] + bias));
      }
    }
  }
}

// ---------------- per-step: aggregate + rrelu + l2norm + time gate + l2norm ----------------
// fused; also emits next step's bf16 hb (padded) when hbnext != null.
__global__ __launch_bounds__(256) void k_aggfin(const int* __restrict__ offs,
                                                const unsigned int* __restrict__ se,
                                                const bf16* __restrict__ hWb,
                                                const float* __restrict__ relW,
                                                const bf16* __restrict__ twb,
                                                float* __restrict__ h,
                                                float* __restrict__ evolve,
                                                unsigned short* __restrict__ hbnext) {
  int wid = threadIdx.x >> 6, lane = threadIdx.x & 63;
  int i = blockIdx.x * 4 + wid;
  if (i >= NE) return;
  int s0 = offs[i], s1 = offs[i + 1];
  int d0 = lane * 4;
  bool act = d0 < H;
  const unsigned short* hw = (const unsigned short*)hWb;
  float a0 = 0.f, a1 = 0.f, a2 = 0.f, a3 = 0.f;

  int p = s0;
  for (; p + 4 <= s1; p += 4) {
    unsigned int e0 = se[p], e1 = se[p + 1], e2 = se[p + 2], e3 = se[p + 3];
    if (act) {
      ushort4 m0 = *reinterpret_cast<const ushort4*>(hw + (size_t)(e0 & 0xFFFFu) * H + d0);
      ushort4 m1 = *reinterpret_cast<const ushort4*>(hw + (size_t)(e1 & 0xFFFFu) * H + d0);
      ushort4 m2 = *reinterpret_cast<const ushort4*>(hw + (size_t)(e2 & 0xFFFFu) * H + d0);
      ushort4 m3 = *reinterpret_cast<const ushort4*>(hw + (size_t)(e3 & 0xFFFFu) * H + d0);
      float4 r0 = *reinterpret_cast<const float4*>(relW + (size_t)(e0 >> 16) * H + d0);
      float4 r1 = *reinterpret_cast<const float4*>(relW + (size_t)(e1 >> 16) * H + d0);
      float4 r2 = *reinterpret_cast<const float4*>(relW + (size_t)(e2 >> 16) * H + d0);
      float4 r3 = *reinterpret_cast<const float4*>(relW + (size_t)(e3 >> 16) * H + d0);
      a0 += u2f(m0.x) + r0.x + u2f(m1.x) + r1.x + u2f(m2.x) + r2.x + u2f(m3.x) + r3.x;
      a1 += u2f(m0.y) + r0.y + u2f(m1.y) + r1.y + u2f(m2.y) + r2.y + u2f(m3.y) + r3.y;
      a2 += u2f(m0.z) + r0.z + u2f(m1.z) + r1.z + u2f(m2.z) + r2.z + u2f(m3.z) + r3.z;
      a3 += u2f(m0.w) + r0.w + u2f(m1.w) + r1.w + u2f(m2.w) + r2.w + u2f(m3.w) + r3.w;
    }
  }
  for (; p < s1; p++) {
    unsigned int e0 = se[p];
    if (act) {
      ushort4 m0 = *reinterpret_cast<const ushort4*>(hw + (size_t)(e0 & 0xFFFFu) * H + d0);
      float4 r0 = *reinterpret_cast<const float4*>(relW + (size_t)(e0 >> 16) * H + d0);
      a0 += u2f(m0.x) + r0.x;
      a1 += u2f(m0.y) + r0.y;
      a2 += u2f(m0.z) + r0.z;
      a3 += u2f(m0.w) + r0.w;
    }
  }

  int deg = s1 - s0;
  float nrm = deg > 0 ? 1.0f / (float)deg : 0.0f;
  float c0 = a0 * nrm; c0 = c0 >= 0.f ? c0 : SLOPE * c0;
  float c1 = a1 * nrm; c1 = c1 >= 0.f ? c1 : SLOPE * c1;
  float c2 = a2 * nrm; c2 = c2 >= 0.f ? c2 : SLOPE * c2;
  float c3 = a3 * nrm; c3 = c3 >= 0.f ? c3 : SLOPE * c3;
  float ss = act ? (c0 * c0 + c1 * c1 + c2 * c2 + c3 * c3) : 0.f;
  ss = wave_sum(ss);
  float sc = 1.0f / fmaxf(sqrtf(ss), 1e-12f);
  c0 *= sc; c1 *= sc; c2 *= sc; c3 *= sc;

  // time gate + combine + l2norm
  float v0 = 0.f, v1 = 0.f, v2 = 0.f, v3 = 0.f;
  if (act) {
    ushort4 t4 = *reinterpret_cast<const ushort4*>((const unsigned short*)twb + (size_t)i * H + d0);
    float4 hv = *reinterpret_cast<const float4*>(h + (size_t)i * H + d0);
    float t0 = u2f(t4.x), t1 = u2f(t4.y), t2 = u2f(t4.z), t3 = u2f(t4.w);
    v0 = t0 * c0 + (1.0f - t0) * hv.x;
    v1 = t1 * c1 + (1.0f - t1) * hv.y;
    v2 = t2 * c2 + (1.0f - t2) * hv.z;
    v3 = t3 * c3 + (1.0f - t3) * hv.w;
  }
  float ss2 = v0 * v0 + v1 * v1 + v2 * v2 + v3 * v3;
  ss2 = wave_sum(ss2);
  float sc2 = 1.0f / fmaxf(sqrtf(ss2), 1e-12f);
  if (act) {
    float4 o = make_float4(v0 * sc2, v1 * sc2, v2 * sc2, v3 * sc2);
    *reinterpret_cast<float4*>(h + (size_t)i * H + d0) = o;
    *reinterpret_cast<float4*>(evolve + (size_t)i * H + d0) = o;
    if (hbnext) {
      ushort4 ob; ob.x = f2bu(o.x); ob.y = f2bu(o.y); ob.z = f2bu(o.z); ob.w = f2bu(o.w);
      *reinterpret_cast<ushort4*>(hbnext + (size_t)i * KP + d0) = ob;
    }
  } else if (d0 < KP && hbnext) {
    ushort4 z; z.x = z.y = z.z = z.w = 0;
    *reinterpret_cast<ushort4*>(hbnext + (size_t)i * KP + d0) = z;
  }
}

extern "C" void kernel_launch(void* const* d_in, const int* in_sizes, int n_in,
                              void* d_out, int out_size, void* d_ws, size_t ws_size,
                              hipStream_t stream) {
  const float* de  = (const float*)d_in[0];
  const float* er  = (const float*)d_in[1];
  const float* wih = (const float*)d_in[2];
  const float* whh = (const float*)d_in[3];
  const float* bih = (const float*)d_in[4];
  const float* bhh = (const float*)d_in[5];
  const float* wn  = (const float*)d_in[6];
  const float* tg  = (const float*)d_in[7];
  const float* tgb = (const float*)d_in[8];
  const int* src  = (const int*)d_in[9];
  const int* dst  = (const int*)d_in[10];
  const int* et   = (const int*)d_in[11];
  const int* rte  = (const int*)d_in[12];
  const int* rseg = (const int*)d_in[13];

  char* w = (char*)d_ws;
  auto alloc = [&](size_t bytes) -> char* {
    char* p = w;
    w += (bytes + 255) / 256 * 256;
    return p;
  };
  float* h     = (float*)alloc(sizeof(float) * (size_t)NE * H);   // 40 MB
  bf16*  hWb   = (bf16*) alloc(sizeof(bf16)  * (size_t)NE * H);   // 20 MB
  bf16*  twb   = (bf16*) alloc(sizeof(bf16)  * (size_t)NE * H);   // 20 MB
  float* relW  = (float*)alloc(sizeof(float) * R2C * H);
  float* h0    = (float*)alloc(sizeof(float) * R2C * H);
  float* sums4 = (float*)alloc(sizeof(float) * TS * R2C * H);     // 1.6 MB
  unsigned short* bpack = (unsigned short*)alloc(sizeof(unsigned short) * 2 * NT * KS * 64 * 8); // 186 KB
  unsigned short* bgi   = (unsigned short*)alloc(sizeof(unsigned short) * GNT * GKI * 64 * 8);   // 506 KB
  unsigned short* bgh   = (unsigned short*)alloc(sizeof(unsigned short) * GNT * GKH * 64 * 8);   // 272 KB
  unsigned short* xcatb = (unsigned short*)alloc(sizeof(unsigned short) * GR * 416);             // 416 KB
  unsigned short* h0b   = (unsigned short*)alloc(sizeof(unsigned short) * GR * 224);             // 224 KB
  float* gi_ws = (float*)alloc(sizeof(float) * GR * GCS);          // 1.24 MB
  float* gh_ws = (float*)alloc(sizeof(float) * GR * GCS);          // 1.24 MB
  int* segstart4 = (int*)alloc(sizeof(int) * TS * (R2C + 1));
  int* deg4    = (int*) alloc(sizeof(int) * TS * NE);              // 800 KB
  int* offs4   = (int*) alloc(sizeof(int) * TS * (NE + 1));        // 800 KB
  int* cursor4 = (int*) alloc(sizeof(int) * TS * NE);              // 800 KB
  unsigned int* se4 = (unsigned int*)alloc(sizeof(unsigned int) * (size_t)TS * EC); // 6.4 MB
  int* bsums4  = (int*) alloc(sizeof(int) * TS * 256);
  (void)ws_size; (void)in_sizes; (void)n_in; (void)out_size;

  float* out    = (float*)d_out;
  float* evolve = out;                       // [TS, NE, H]
  float* h0out  = out + (size_t)TS * NE * H; // [R2C, H]

  const int gRow4  = (NE + 3) / 4;          // 12500
  const int gRel   = (R2C * H + 255) / 256; // 391
  const int gPack  = (2 * NT * KS * 64 + 255) / 256;       // 46
  const int gPackG = (GNT * (GKI + GKH) * 64 + 255) / 256; // 190
  const int gA2b   = (GR * 416 + GR * 224 + 255) / 256;    // 1280
  const int gGemm  = (NE + 63) / 64;                       // 782
  const int gGru   = 8 * GNT;                              // 304
  const int gRelsum= EC / RCH;                             // 6250
  const int gE4i   = (TS * EC / 4 + 255) / 256;            // 1563
  const int gZ4    = (TS * NE + 255) / 256;                // 782
  const int gZs    = (TS * R2C * H + 255) / 256;           // 1563
  const int gScat  = NCHK * TS * NRNG;                     // 12512

  // ---- prologue: init + weight packs + all-step CSR / segment bounds ----
  k_init_h<<<gRow4, 256, 0, stream>>>(de, h, (unsigned short*)evolve);  // hb0 in evolve[0] slot
  k_init_h0<<<gRel, 256, 0, stream>>>(er, h0);
  k_relw<<<R2C, 256, 0, stream>>>(er, wn, relW);
  k_packb<<<gPack, 256, 0, stream>>>(wn, tg, bpack);
  k_packgru<<<gPackG, 256, 0, stream>>>(wih, whh, bgi, bgh);
  k_segbounds4<<<TS, 512, 0, stream>>>(rseg, segstart4);
  k_zero_f<<<gZs, 256, 0, stream>>>(sums4, TS * R2C * H);
  k_zero_i<<<gZ4, 256, 0, stream>>>(deg4, TS * NE);
  k_hist4<<<gE4i, 256, 0, stream>>>(dst, deg4);
  k_scan1<<<TS * NSCAN, 256, 0, stream>>>(deg4, offs4, bsums4);
  k_scan2<<<TS, 256, 0, stream>>>(bsums4);
  k_scan3<<<TS * NSCAN, 256, 0, stream>>>(offs4, bsums4, cursor4);
  k_scatter8<<<gScat, 256, 0, stream>>>(dst, src, et, cursor4, se4);

  for (int t = 0; t < TS; t++) {
    const int* rseg_t = rseg + (size_t)t * EC;
    const int* rte_t  = rte  + (size_t)t * EC;
    float* sums_t = sums4 + (size_t)t * R2C * H;
    float* evo_t = evolve + (size_t)t * NE * H;
    // hb(t) lives in the evolve[t] slot (written by k_init_h for t=0, else by
    // the previous step's k_aggfin); it is dead before k_aggfin overwrites it.
    unsigned short* hb = (unsigned short*)evo_t;
    unsigned short* hbnext = (t < TS - 1) ? (unsigned short*)(evolve + (size_t)(t + 1) * NE * H)
                                          : (unsigned short*)nullptr;

    // relation-segment means + GRU via MFMA (uses pre-step h, h0)
    k_relsums<<<gRelsum, 256, 0, stream>>>(rseg_t, rte_t, hb, sums_t);
    k_a2b<<<gA2b, 256, 0, stream>>>(er, sums_t, segstart4 + t * (R2C + 1), h0, xcatb, h0b);
    k_grumm<<<gGru, 256, 0, stream>>>(xcatb, h0b, bgi, bgh, gi_ws, gh_ws);
    k_grutail<<<R2C, 256, 0, stream>>>(gi_ws, gh_ws, bih, bhh,
                                       h0, (t == TS - 1) ? h0out : (float*)nullptr);

    // node GEMMs via MFMA (pre-step h)
    k_mfma_gemm<<<gGemm, 256, 0, stream>>>(hb, bpack, tgb, hWb, twb);

    // fused aggregate + rrelu + l2norm + time gate + combine + l2norm
    // -> writes h (in place), evolve[t], and next step's hb
    k_aggfin<<<gRow4, 256, 0, stream>>>(offs4 + t * (NE + 1), se4 + (size_t)t * EC,
                                        hWb, relW, twb, h, evo_t, hbnext);
  }
}